// Round 3
// baseline (1704.990 us; speedup 1.0000x reference)
//
#include <hip/hip_runtime.h>
#include <cstdint>
#include <cstddef>

#define DD 64
constexpr float BN_EPS  = 1e-5f;
constexpr float DEG_EPS = 1e-6f;

__device__ __forceinline__ float fatomic_add(float* p, float v) {
    return unsafeAtomicAdd(p, v);   // hardware global_atomic_add_f32
}

// ---------------- node linears: o = h @ W^T + b, one matrix per blockIdx.y ----
__global__ __launch_bounds__(256) void k_node_linear(
    const float* __restrict__ h, int N,
    const float* __restrict__ w0, const float* __restrict__ b0, float* __restrict__ o0,
    const float* __restrict__ w1, const float* __restrict__ b1, float* __restrict__ o1,
    const float* __restrict__ w2, const float* __restrict__ b2, float* __restrict__ o2,
    const float* __restrict__ w3, const float* __restrict__ b3, float* __restrict__ o3,
    const float* __restrict__ w4, const float* __restrict__ b4, float* __restrict__ o4)
{
    const float* w; const float* b; float* o;
    switch (blockIdx.y) {
        case 0:  w = w0; b = b0; o = o0; break;
        case 1:  w = w1; b = b1; o = o1; break;
        case 2:  w = w2; b = b2; o = o2; break;
        case 3:  w = w3; b = b3; o = o3; break;
        default: w = w4; b = b4; o = o4; break;
    }
    int n = blockIdx.x * 256 + threadIdx.x;
    if (n >= N) return;
    float hr[DD];
    const float4* h4 = reinterpret_cast<const float4*>(h + (size_t)n * DD);
    #pragma unroll
    for (int j = 0; j < 16; ++j) {
        float4 v = h4[j];
        hr[4*j+0] = v.x; hr[4*j+1] = v.y; hr[4*j+2] = v.z; hr[4*j+3] = v.w;
    }
    float4* op = reinterpret_cast<float4*>(o + (size_t)n * DD);
    for (int d4 = 0; d4 < 16; ++d4) {
        float acc[4];
        #pragma unroll
        for (int j = 0; j < 4; ++j) acc[j] = b[d4*4 + j];
        #pragma unroll
        for (int k4 = 0; k4 < 16; ++k4) {
            #pragma unroll
            for (int j = 0; j < 4; ++j) {
                float4 wv = reinterpret_cast<const float4*>(w + (size_t)(d4*4 + j) * DD)[k4];
                acc[j] += hr[4*k4+0]*wv.x + hr[4*k4+1]*wv.y
                        + hr[4*k4+2]*wv.z + hr[4*k4+3]*wv.w;
            }
        }
        float4 ov = {acc[0], acc[1], acc[2], acc[3]};
        op[d4] = ov;
    }
}

// ---------------- edge gate pre-BN: g = B3e + B1h[src] + B2h[dst] + b3 -------
__global__ __launch_bounds__(256) void k_edge_g(
    const float* __restrict__ e, const int* __restrict__ src, const int* __restrict__ dst,
    const float* __restrict__ B1h, const float* __restrict__ B2h,
    const float* __restrict__ w, const float* __restrict__ b,
    float* __restrict__ g, int E)
{
    int ee = blockIdx.x * 256 + threadIdx.x;
    if (ee >= E) return;
    float er[DD];
    const float4* e4 = reinterpret_cast<const float4*>(e + (size_t)ee * DD);
    #pragma unroll
    for (int j = 0; j < 16; ++j) {
        float4 v = e4[j];
        er[4*j+0] = v.x; er[4*j+1] = v.y; er[4*j+2] = v.z; er[4*j+3] = v.w;
    }
    int s = src[ee], t = dst[ee];
    const float4* p1 = reinterpret_cast<const float4*>(B1h + (size_t)s * DD);
    const float4* p2 = reinterpret_cast<const float4*>(B2h + (size_t)t * DD);
    float4* go = reinterpret_cast<float4*>(g + (size_t)ee * DD);
    for (int d4 = 0; d4 < 16; ++d4) {
        float acc[4];
        #pragma unroll
        for (int j = 0; j < 4; ++j) acc[j] = b[d4*4 + j];
        #pragma unroll
        for (int k4 = 0; k4 < 16; ++k4) {
            #pragma unroll
            for (int j = 0; j < 4; ++j) {
                float4 wv = reinterpret_cast<const float4*>(w + (size_t)(d4*4 + j) * DD)[k4];
                acc[j] += er[4*k4+0]*wv.x + er[4*k4+1]*wv.y
                        + er[4*k4+2]*wv.z + er[4*k4+3]*wv.w;
            }
        }
        float4 g1 = p1[d4], g2 = p2[d4];
        float4 ov = {acc[0] + g1.x + g2.x, acc[1] + g1.y + g2.y,
                     acc[2] + g1.z + g2.z, acc[3] + g1.w + g2.w};
        go[d4] = ov;
    }
}

// ---------------- per-column sum / sumsq over a [rows,64] buffer -------------
__global__ __launch_bounds__(256) void k_col_stats(
    const float* __restrict__ x, long long total, float* __restrict__ sums /*[128]*/)
{
    int tid = threadIdx.x;
    long long idx = (long long)blockIdx.x * 256 + tid;
    long long stride = (long long)gridDim.x * 256;   // %64 == 0 -> d fixed per thread
    float ps = 0.f, pq = 0.f;
    for (; idx < total; idx += stride) {
        float v = x[idx];
        ps += v; pq += v * v;
    }
    __shared__ float red[256];
    red[tid] = ps; __syncthreads();
    if (tid < 64) fatomic_add(&sums[tid],      red[tid] + red[tid+64] + red[tid+128] + red[tid+192]);
    __syncthreads();
    red[tid] = pq; __syncthreads();
    if (tid < 64) fatomic_add(&sums[64 + tid], red[tid] + red[tid+64] + red[tid+128] + red[tid+192]);
}

// ---------------- fold stats into scale/shift --------------------------------
__global__ void k_bn_final(const float* __restrict__ sums, float inv_cnt,
                           const float* __restrict__ gamma, const float* __restrict__ beta,
                           float* __restrict__ scale, float* __restrict__ shift)
{
    int d = threadIdx.x;
    if (d >= DD) return;
    float mean = sums[d] * inv_cnt;
    float var  = fmaxf(sums[64 + d] * inv_cnt - mean * mean, 0.f);
    float rs   = rsqrtf(var + BN_EPS);
    float sc   = gamma[d] * rs;
    scale[d] = sc;
    shift[d] = beta[d] - mean * sc;
}

// ---------------- CSR build: count, scan, place ------------------------------
__global__ __launch_bounds__(256) void k_count(
    const int* __restrict__ src, const int* __restrict__ dst,
    int* __restrict__ cnt_f, int* __restrict__ cnt_b, int E)
{
    int ee = blockIdx.x * 256 + threadIdx.x;
    if (ee >= E) return;
    atomicAdd(&cnt_f[dst[ee]], 1);
    atomicAdd(&cnt_b[src[ee]], 1);
}

// single-block exclusive scan; cnt and cur may alias (in-place ok).
__global__ __launch_bounds__(1024) void k_scan(
    const int* cnt, int* row, int* cur, int n, int total)
{
    __shared__ int tmp[1024];
    int tid = threadIdx.x;
    int carry = 0;
    for (int base = 0; base < n; base += 1024) {
        int i = base + tid;
        int v = (i < n) ? cnt[i] : 0;
        tmp[tid] = v; __syncthreads();
        for (int off = 1; off < 1024; off <<= 1) {
            int t = (tid >= off) ? tmp[tid - off] : 0;
            __syncthreads();
            tmp[tid] += t;
            __syncthreads();
        }
        int excl = carry + tmp[tid] - v;
        if (i < n) { row[i] = excl; cur[i] = excl; }
        carry += tmp[1023];
        __syncthreads();
    }
    if (tid == 0) row[n] = total;
}

__global__ __launch_bounds__(256) void k_place(
    const int* __restrict__ src, const int* __restrict__ dst,
    int* __restrict__ cur_f, int* __restrict__ cur_b,
    int* __restrict__ perm_f, int* __restrict__ perm_b, int E)
{
    int ee = blockIdx.x * 256 + threadIdx.x;
    if (ee >= E) return;
    int pf = atomicAdd(&cur_f[dst[ee]], 1);
    perm_f[pf] = ee;
    int pb = atomicAdd(&cur_b[src[ee]], 1);
    perm_b[pb] = ee;
}

// ---------------- sigma = sigmoid(relu(bn(g)) + e), in place over g ----------
// g lives in the out-e region; read g, write sigma to the same slot (same thread).
__global__ __launch_bounds__(256) void k_edge_sigma(
    float* g, const float* __restrict__ e,
    const float* __restrict__ scale, const float* __restrict__ shift,
    long long total)
{
    long long idx = (long long)blockIdx.x * 256 + threadIdx.x;
    if (idx >= total) return;
    int d = (int)(idx & (DD - 1));
    float x = g[idx] * scale[d] + shift[d];
    x = fmaxf(x, 0.f) + e[idx];
    g[idx] = 1.f / (1.f + __expf(-x));
}

// ---------------- gather: one wave per node, lane = d ------------------------
__global__ __launch_bounds__(256) void k_gather(
    const float* __restrict__ sigma, const int* __restrict__ perm,
    const int* __restrict__ row, const int* __restrict__ other_idx,
    const float* __restrict__ Ah, float* __restrict__ agg, int N)
{
    int wid  = (blockIdx.x * 256 + threadIdx.x) >> 6;
    int lane = threadIdx.x & 63;
    if (wid >= N) return;
    int beg = row[wid], end = row[wid + 1];
    float num = 0.f, den = 0.f;
    for (int k = beg; k < end; ++k) {
        int eid = perm[k];                          // broadcast (uniform in wave)
        int o   = other_idx[eid];                   // broadcast
        float s = sigma[(size_t)eid * DD + lane];   // 256B coalesced row
        float a = Ah[(size_t)o * DD + lane];        // 256B coalesced row
        num += s * a;
        den += s;
    }
    agg[(size_t)wid * DD + lane] = num / (den + DEG_EPS);
}

// ---------------- h_pre = A1h + agg_f + agg_b, + column stats ----------------
__global__ __launch_bounds__(256) void k_node_pre(
    const float* __restrict__ A1h,
    const float* __restrict__ agg_f, const float* __restrict__ agg_b,
    float* __restrict__ hpre, float* __restrict__ sums, long long total)
{
    int tid = threadIdx.x;
    long long idx = (long long)blockIdx.x * 256 + tid;
    long long stride = (long long)gridDim.x * 256;
    float ps = 0.f, pq = 0.f;
    for (; idx < total; idx += stride) {
        float v = A1h[idx] + agg_f[idx] + agg_b[idx];
        hpre[idx] = v;
        ps += v; pq += v * v;
    }
    __shared__ float red[256];
    red[tid] = ps; __syncthreads();
    if (tid < 64) fatomic_add(&sums[tid],      red[tid] + red[tid+64] + red[tid+128] + red[tid+192]);
    __syncthreads();
    red[tid] = pq; __syncthreads();
    if (tid < 64) fatomic_add(&sums[64 + tid], red[tid] + red[tid+64] + red[tid+128] + red[tid+192]);
}

// ---------------- finish h: BN affine + relu + residual (in place) -----------
__global__ __launch_bounds__(256) void k_node_out(
    const float* __restrict__ h,
    const float* __restrict__ scale, const float* __restrict__ shift,
    float* __restrict__ out, long long total)
{
    long long idx = (long long)blockIdx.x * 256 + threadIdx.x;
    long long stride = (long long)gridDim.x * 256;
    for (; idx < total; idx += stride) {
        int d = (int)(idx & (DD - 1));
        float v = out[idx] * scale[d] + shift[d];
        out[idx] = fmaxf(v, 0.f) + h[idx];
    }
}

extern "C" void kernel_launch(void* const* d_in, const int* in_sizes, int n_in,
                              void* d_out, int out_size, void* d_ws, size_t ws_size,
                              hipStream_t stream)
{
    const float* h    = (const float*)d_in[0];
    const float* e    = (const float*)d_in[1];
    const int*   src  = (const int*)d_in[2];
    const int*   dst  = (const int*)d_in[3];
    const float* A1w  = (const float*)d_in[4];
    const float* A1b  = (const float*)d_in[5];
    const float* A2w  = (const float*)d_in[6];
    const float* A2b  = (const float*)d_in[7];
    const float* A3w  = (const float*)d_in[8];
    const float* A3b  = (const float*)d_in[9];
    const float* B1w  = (const float*)d_in[10];
    const float* B1b  = (const float*)d_in[11];
    const float* B2w  = (const float*)d_in[12];
    const float* B2b  = (const float*)d_in[13];
    const float* B3w  = (const float*)d_in[14];
    const float* B3b  = (const float*)d_in[15];
    const float* bnhg = (const float*)d_in[16];
    const float* bnhb = (const float*)d_in[17];
    const float* bneg = (const float*)d_in[18];
    const float* bneb = (const float*)d_in[19];

    const int N = in_sizes[0] / DD;
    const int E = in_sizes[1] / DD;
    const size_t ND = (size_t)N * DD;
    const size_t ED = (size_t)E * DD;

    float* ws    = (float*)d_ws;
    float* A1h   = ws + 0 * ND;
    float* A2h   = ws + 1 * ND;
    float* A3h   = ws + 2 * ND;
    float* B1h   = ws + 3 * ND;
    float* B2h   = ws + 4 * ND;
    float* agg_f = ws + 5 * ND;
    float* agg_b = ws + 6 * ND;
    float* stats = ws + 7 * ND;   // 512 floats:
    // [0:64] e_sum [64:128] e_sq [128:192] e_scale [192:256] e_shift
    // [256:320] h_sum [320:384] h_sq [384:448] h_scale [448:512] h_shift
    int* ibase  = (int*)(stats + 512);
    int* cur_f  = ibase;                 // N  (doubles as count buffer)
    int* cur_b  = ibase + N;             // N
    int* row_f  = ibase + 2 * N;         // N+1
    int* row_b  = ibase + 3 * N + 1;     // N+1
    int* perm_f = ibase + 4 * N + 2;     // E
    int* perm_b = ibase + 4 * N + 2 + E; // E

    float* out  = (float*)d_out;
    float* gbuf = out + ND;   // out e-region: holds g, then sigma, finally e

    // zero stats + count buffers
    hipMemsetAsync(stats, 0, 512 * sizeof(float) + 2 * (size_t)N * sizeof(int), stream);

    dim3 blk(256);
    int nb_n = (N + 255) / 256;
    int nb_e = (E + 255) / 256;
    int nb_ed = (int)((ED + 255) / 256);

    k_node_linear<<<dim3(nb_n, 5), blk, 0, stream>>>(h, N,
        A1w, A1b, A1h,  A2w, A2b, A2h,  A3w, A3b, A3h,
        B1w, B1b, B1h,  B2w, B2b, B2h);

    // CSR build (independent of the float pipeline)
    k_count<<<nb_e, blk, 0, stream>>>(src, dst, cur_f, cur_b, E);
    k_scan<<<1, 1024, 0, stream>>>(cur_f, row_f, cur_f, N, E);
    k_scan<<<1, 1024, 0, stream>>>(cur_b, row_b, cur_b, N, E);
    k_place<<<nb_e, blk, 0, stream>>>(src, dst, cur_f, cur_b, perm_f, perm_b, E);

    k_edge_g<<<nb_e, blk, 0, stream>>>(e, src, dst, B1h, B2h, B3w, B3b, gbuf, E);

    k_col_stats<<<2048, blk, 0, stream>>>(gbuf, (long long)ED, stats);
    k_bn_final<<<1, 64, 0, stream>>>(stats, 1.0f / (float)E, bneg, bneb,
                                     stats + 128, stats + 192);

    k_edge_sigma<<<nb_ed, blk, 0, stream>>>(gbuf, e, stats + 128, stats + 192,
                                            (long long)ED);

    int nb_g = (int)(((size_t)N * DD + 255) / 256);
    k_gather<<<nb_g, blk, 0, stream>>>(gbuf, perm_f, row_f, src, A2h, agg_f, N);
    k_gather<<<nb_g, blk, 0, stream>>>(gbuf, perm_b, row_b, dst, A3h, agg_b, N);

    k_node_pre<<<1024, blk, 0, stream>>>(A1h, agg_f, agg_b,
        out, stats + 256, (long long)ND);
    k_bn_final<<<1, 64, 0, stream>>>(stats + 256, 1.0f / (float)N, bnhg, bnhb,
                                     stats + 384, stats + 448);
    k_node_out<<<1024, blk, 0, stream>>>(h, stats + 384, stats + 448,
                                         out, (long long)ND);

    // e passthrough (overwrites sigma scratch in the out e-region)
    hipMemcpyAsync(gbuf, e, ED * sizeof(float), hipMemcpyDeviceToDevice, stream);
}

// Round 4
// 1443.438 us; speedup vs baseline: 1.1812x; 1.1812x over previous
//
#include <hip/hip_runtime.h>
#include <cstdint>
#include <cstddef>

#define DD 64
constexpr float BN_EPS  = 1e-5f;
constexpr float DEG_EPS = 1e-6f;

__device__ __forceinline__ float fatomic_add(float* p, float v) {
    return unsafeAtomicAdd(p, v);   // hardware global_atomic_add_f32
}

// ---------------- node linears: o = h @ W^T + b, one matrix per blockIdx.y ----
__global__ __launch_bounds__(256) void k_node_linear(
    const float* __restrict__ h, int N,
    const float* __restrict__ w0, const float* __restrict__ b0, float* __restrict__ o0,
    const float* __restrict__ w1, const float* __restrict__ b1, float* __restrict__ o1,
    const float* __restrict__ w2, const float* __restrict__ b2, float* __restrict__ o2,
    const float* __restrict__ w3, const float* __restrict__ b3, float* __restrict__ o3,
    const float* __restrict__ w4, const float* __restrict__ b4, float* __restrict__ o4)
{
    const float* w; const float* b; float* o;
    switch (blockIdx.y) {
        case 0:  w = w0; b = b0; o = o0; break;
        case 1:  w = w1; b = b1; o = o1; break;
        case 2:  w = w2; b = b2; o = o2; break;
        case 3:  w = w3; b = b3; o = o3; break;
        default: w = w4; b = b4; o = o4; break;
    }
    int n = blockIdx.x * 256 + threadIdx.x;
    if (n >= N) return;
    float hr[DD];
    const float4* h4 = reinterpret_cast<const float4*>(h + (size_t)n * DD);
    #pragma unroll
    for (int j = 0; j < 16; ++j) {
        float4 v = h4[j];
        hr[4*j+0] = v.x; hr[4*j+1] = v.y; hr[4*j+2] = v.z; hr[4*j+3] = v.w;
    }
    float4* op = reinterpret_cast<float4*>(o + (size_t)n * DD);
    for (int d4 = 0; d4 < 16; ++d4) {
        float acc[4];
        #pragma unroll
        for (int j = 0; j < 4; ++j) acc[j] = b[d4*4 + j];
        #pragma unroll
        for (int k4 = 0; k4 < 16; ++k4) {
            #pragma unroll
            for (int j = 0; j < 4; ++j) {
                float4 wv = reinterpret_cast<const float4*>(w + (size_t)(d4*4 + j) * DD)[k4];
                acc[j] += hr[4*k4+0]*wv.x + hr[4*k4+1]*wv.y
                        + hr[4*k4+2]*wv.z + hr[4*k4+3]*wv.w;
            }
        }
        float4 ov = {acc[0], acc[1], acc[2], acc[3]};
        op[d4] = ov;
    }
}

// ---------------- edge matmul only: g0 = B3 e + b3 (coalesced) ---------------
__global__ __launch_bounds__(256) void k_edge_mm(
    const float* __restrict__ e,
    const float* __restrict__ w, const float* __restrict__ b,
    float* __restrict__ g, int E)
{
    int ee = blockIdx.x * 256 + threadIdx.x;
    if (ee >= E) return;
    float er[DD];
    const float4* e4 = reinterpret_cast<const float4*>(e + (size_t)ee * DD);
    #pragma unroll
    for (int j = 0; j < 16; ++j) {
        float4 v = e4[j];
        er[4*j+0] = v.x; er[4*j+1] = v.y; er[4*j+2] = v.z; er[4*j+3] = v.w;
    }
    float4* go = reinterpret_cast<float4*>(g + (size_t)ee * DD);
    for (int d4 = 0; d4 < 16; ++d4) {
        float acc[4];
        #pragma unroll
        for (int j = 0; j < 4; ++j) acc[j] = b[d4*4 + j];   // uniform -> s_load
        #pragma unroll
        for (int k4 = 0; k4 < 16; ++k4) {
            #pragma unroll
            for (int j = 0; j < 4; ++j) {
                float4 wv = reinterpret_cast<const float4*>(w + (size_t)(d4*4 + j) * DD)[k4];
                acc[j] += er[4*k4+0]*wv.x + er[4*k4+1]*wv.y
                        + er[4*k4+2]*wv.z + er[4*k4+3]*wv.w;
            }
        }
        float4 ov = {acc[0], acc[1], acc[2], acc[3]};
        go[d4] = ov;
    }
}

// ---------------- (edge,d) wave layout: g += B1h[src]row + B2h[dst]row -------
// One edge per wave-iteration; every global access is a full 256B wave line.
// Also fuses the BN-e column stats (lane == column d).
__global__ __launch_bounds__(256) void k_edge_rows(
    float* g,   // in: g0, out: g (in-place, same thread)
    const int* __restrict__ src, const int* __restrict__ dst,
    const float* __restrict__ B1h, const float* __restrict__ B2h,
    float* __restrict__ sums, int E)
{
    int tid  = threadIdx.x;
    int lane = tid & 63;
    int wid  = (blockIdx.x * 256 + tid) >> 6;
    int nw   = (gridDim.x * 256) >> 6;
    float ps = 0.f, pq = 0.f;
    for (int ee = wid; ee < E; ee += nw) {
        int s = src[ee], t = dst[ee];
        size_t ro = (size_t)ee * DD + lane;
        float v = g[ro] + B1h[(size_t)s * DD + lane] + B2h[(size_t)t * DD + lane];
        g[ro] = v;
        ps += v; pq += v * v;
    }
    __shared__ float red[256];
    red[tid] = ps; __syncthreads();
    if (tid < 64) fatomic_add(&sums[tid],      red[tid] + red[tid+64] + red[tid+128] + red[tid+192]);
    __syncthreads();
    red[tid] = pq; __syncthreads();
    if (tid < 64) fatomic_add(&sums[64 + tid], red[tid] + red[tid+64] + red[tid+128] + red[tid+192]);
}

// ---------------- fold stats into scale/shift --------------------------------
__global__ void k_bn_final(const float* __restrict__ sums, float inv_cnt,
                           const float* __restrict__ gamma, const float* __restrict__ beta,
                           float* __restrict__ scale, float* __restrict__ shift)
{
    int d = threadIdx.x;
    if (d >= DD) return;
    float mean = sums[d] * inv_cnt;
    float var  = fmaxf(sums[64 + d] * inv_cnt - mean * mean, 0.f);
    float rs   = rsqrtf(var + BN_EPS);
    float sc   = gamma[d] * rs;
    scale[d] = sc;
    shift[d] = beta[d] - mean * sc;
}

// ---------------- CSR build: count, scan, place ------------------------------
__global__ __launch_bounds__(256) void k_count(
    const int* __restrict__ src, const int* __restrict__ dst,
    int* __restrict__ cnt_f, int* __restrict__ cnt_b, int E)
{
    int ee = blockIdx.x * 256 + threadIdx.x;
    if (ee >= E) return;
    atomicAdd(&cnt_f[dst[ee]], 1);
    atomicAdd(&cnt_b[src[ee]], 1);
}

// single-block exclusive scan; cnt and cur may alias (in-place ok).
__global__ __launch_bounds__(1024) void k_scan(
    const int* cnt, int* row, int* cur, int n, int total)
{
    __shared__ int tmp[1024];
    int tid = threadIdx.x;
    int carry = 0;
    for (int base = 0; base < n; base += 1024) {
        int i = base + tid;
        int v = (i < n) ? cnt[i] : 0;
        tmp[tid] = v; __syncthreads();
        for (int off = 1; off < 1024; off <<= 1) {
            int t = (tid >= off) ? tmp[tid - off] : 0;
            __syncthreads();
            tmp[tid] += t;
            __syncthreads();
        }
        int excl = carry + tmp[tid] - v;
        if (i < n) { row[i] = excl; cur[i] = excl; }
        carry += tmp[1023];
        __syncthreads();
    }
    if (tid == 0) row[n] = total;
}

__global__ __launch_bounds__(256) void k_place(
    const int* __restrict__ src, const int* __restrict__ dst,
    int* __restrict__ cur_f, int* __restrict__ cur_b,
    int* __restrict__ perm_f, int* __restrict__ perm_b, int E)
{
    int ee = blockIdx.x * 256 + threadIdx.x;
    if (ee >= E) return;
    int pf = atomicAdd(&cur_f[dst[ee]], 1);
    perm_f[pf] = ee;
    int pb = atomicAdd(&cur_b[src[ee]], 1);
    perm_b[pb] = ee;
}

// ---------------- sigma = sigmoid(relu(bn(g)) + e), float4-vectorized --------
// sig may alias g (in-place: read-then-write, same thread). If ecopy != null,
// writes e there (fused passthrough; may alias g after the read).
__global__ __launch_bounds__(256) void k_edge_sigma(
    const float4* g, const float4* __restrict__ e,
    float4* sig, float4* ecopy,
    const float* __restrict__ scale, const float* __restrict__ shift,
    long long total4)
{
    long long idx = (long long)blockIdx.x * 256 + threadIdx.x;
    if (idx >= total4) return;
    int q = (int)(idx & 15);            // float4-slot within the 64-col row
    float4 sc = reinterpret_cast<const float4*>(scale)[q];
    float4 sh = reinterpret_cast<const float4*>(shift)[q];
    float4 gv = g[idx];
    float4 ev = e[idx];
    float4 o;
    o.x = 1.f / (1.f + __expf(-(fmaxf(gv.x * sc.x + sh.x, 0.f) + ev.x)));
    o.y = 1.f / (1.f + __expf(-(fmaxf(gv.y * sc.y + sh.y, 0.f) + ev.y)));
    o.z = 1.f / (1.f + __expf(-(fmaxf(gv.z * sc.z + sh.z, 0.f) + ev.z)));
    o.w = 1.f / (1.f + __expf(-(fmaxf(gv.w * sc.w + sh.w, 0.f) + ev.w)));
    sig[idx] = o;
    if (ecopy) ecopy[idx] = ev;
}

// ---------------- gather: one wave per node, lane = d ------------------------
__global__ __launch_bounds__(256) void k_gather(
    const float* __restrict__ sigma, const int* __restrict__ perm,
    const int* __restrict__ row, const int* __restrict__ other_idx,
    const float* __restrict__ Ah, float* __restrict__ agg, int N)
{
    int wid  = (blockIdx.x * 256 + threadIdx.x) >> 6;
    int lane = threadIdx.x & 63;
    if (wid >= N) return;
    int beg = row[wid], end = row[wid + 1];
    float num = 0.f, den = 0.f;
    for (int k = beg; k < end; ++k) {
        int eid = perm[k];                          // uniform in wave
        int o   = other_idx[eid];                   // uniform in wave
        float s = sigma[(size_t)eid * DD + lane];   // 256B coalesced row
        float a = Ah[(size_t)o * DD + lane];        // 256B coalesced row
        num += s * a;
        den += s;
    }
    agg[(size_t)wid * DD + lane] = num / (den + DEG_EPS);
}

// ---------------- h_pre = A1h + agg_f + agg_b, + column stats ----------------
__global__ __launch_bounds__(256) void k_node_pre(
    const float* __restrict__ A1h,
    const float* __restrict__ agg_f, const float* __restrict__ agg_b,
    float* __restrict__ hpre, float* __restrict__ sums, long long total)
{
    int tid = threadIdx.x;
    long long idx = (long long)blockIdx.x * 256 + tid;
    long long stride = (long long)gridDim.x * 256;
    float ps = 0.f, pq = 0.f;
    for (; idx < total; idx += stride) {
        float v = A1h[idx] + agg_f[idx] + agg_b[idx];
        hpre[idx] = v;
        ps += v; pq += v * v;
    }
    __shared__ float red[256];
    red[tid] = ps; __syncthreads();
    if (tid < 64) fatomic_add(&sums[tid],      red[tid] + red[tid+64] + red[tid+128] + red[tid+192]);
    __syncthreads();
    red[tid] = pq; __syncthreads();
    if (tid < 64) fatomic_add(&sums[64 + tid], red[tid] + red[tid+64] + red[tid+128] + red[tid+192]);
}

// ---------------- finish h: BN affine + relu + residual (in place) -----------
__global__ __launch_bounds__(256) void k_node_out(
    const float* __restrict__ h,
    const float* __restrict__ scale, const float* __restrict__ shift,
    float* __restrict__ out, long long total)
{
    long long idx = (long long)blockIdx.x * 256 + threadIdx.x;
    long long stride = (long long)gridDim.x * 256;
    for (; idx < total; idx += stride) {
        int d = (int)(idx & (DD - 1));
        float v = out[idx] * scale[d] + shift[d];
        out[idx] = fmaxf(v, 0.f) + h[idx];
    }
}

extern "C" void kernel_launch(void* const* d_in, const int* in_sizes, int n_in,
                              void* d_out, int out_size, void* d_ws, size_t ws_size,
                              hipStream_t stream)
{
    const float* h    = (const float*)d_in[0];
    const float* e    = (const float*)d_in[1];
    const int*   src  = (const int*)d_in[2];
    const int*   dst  = (const int*)d_in[3];
    const float* A1w  = (const float*)d_in[4];
    const float* A1b  = (const float*)d_in[5];
    const float* A2w  = (const float*)d_in[6];
    const float* A2b  = (const float*)d_in[7];
    const float* A3w  = (const float*)d_in[8];
    const float* A3b  = (const float*)d_in[9];
    const float* B1w  = (const float*)d_in[10];
    const float* B1b  = (const float*)d_in[11];
    const float* B2w  = (const float*)d_in[12];
    const float* B2b  = (const float*)d_in[13];
    const float* B3w  = (const float*)d_in[14];
    const float* B3b  = (const float*)d_in[15];
    const float* bnhg = (const float*)d_in[16];
    const float* bnhb = (const float*)d_in[17];
    const float* bneg = (const float*)d_in[18];
    const float* bneb = (const float*)d_in[19];

    const int N = in_sizes[0] / DD;
    const int E = in_sizes[1] / DD;
    const size_t ND = (size_t)N * DD;
    const size_t ED = (size_t)E * DD;

    float* ws    = (float*)d_ws;
    float* A1h   = ws + 0 * ND;
    float* A2h   = ws + 1 * ND;
    float* A3h   = ws + 2 * ND;
    float* B1h   = ws + 3 * ND;
    float* B2h   = ws + 4 * ND;
    float* agg_f = ws + 5 * ND;
    float* agg_b = ws + 6 * ND;
    float* stats = ws + 7 * ND;   // 512 floats (e/h: sum,sq,scale,shift)

    // optional sigma buffer in ws (enables fused e-passthrough, no memcpy)
    const size_t int_count = 4 * (size_t)N + 2 + 2 * (size_t)E;
    const size_t need_big  = (7 * ND + 512 + ED) * sizeof(float) + int_count * sizeof(int);
    const bool   ws_big    = ws_size >= need_big;

    float* sig_ws = stats + 512;                       // ED floats (only if ws_big)
    int*   ibase  = (int*)(ws_big ? (sig_ws + ED) : (stats + 512));
    int* cur_f  = ibase;                 // N (count -> cursor)
    int* cur_b  = ibase + N;             // N
    int* row_f  = ibase + 2 * N;         // N+1
    int* row_b  = ibase + 3 * N + 1;     // N+1
    int* perm_f = ibase + 4 * N + 2;     // E
    int* perm_b = ibase + 4 * N + 2 + E; // E

    float* out  = (float*)d_out;
    float* gbuf = out + ND;   // out e-region: g0 -> g -> (sigma | e)

    hipMemsetAsync(stats, 0, 512 * sizeof(float), stream);
    hipMemsetAsync(cur_f, 0, 2 * (size_t)N * sizeof(int), stream);

    dim3 blk(256);
    int nb_n = (N + 255) / 256;
    int nb_e = (E + 255) / 256;

    k_node_linear<<<dim3(nb_n, 5), blk, 0, stream>>>(h, N,
        A1w, A1b, A1h,  A2w, A2b, A2h,  A3w, A3b, A3h,
        B1w, B1b, B1h,  B2w, B2b, B2h);

    // CSR build
    k_count<<<nb_e, blk, 0, stream>>>(src, dst, cur_f, cur_b, E);
    k_scan<<<1, 1024, 0, stream>>>(cur_f, row_f, cur_f, N, E);
    k_scan<<<1, 1024, 0, stream>>>(cur_b, row_b, cur_b, N, E);
    k_place<<<nb_e, blk, 0, stream>>>(src, dst, cur_f, cur_b, perm_f, perm_b, E);

    // edge gate: matmul (coalesced) then row-adds (wave-per-edge) + stats
    k_edge_mm<<<nb_e, blk, 0, stream>>>(e, B3w, B3b, gbuf, E);
    k_edge_rows<<<2048, blk, 0, stream>>>(gbuf, src, dst, B1h, B2h, stats, E);
    k_bn_final<<<1, 64, 0, stream>>>(stats, 1.0f / (float)E, bneg, bneb,
                                     stats + 128, stats + 192);

    long long total4 = (long long)(ED / 4);
    int nb_s = (int)((total4 + 255) / 256);
    float* sigma = ws_big ? sig_ws : gbuf;
    k_edge_sigma<<<nb_s, blk, 0, stream>>>(
        (const float4*)gbuf, (const float4*)e,
        (float4*)sigma, ws_big ? (float4*)gbuf : nullptr,
        stats + 128, stats + 192, total4);

    int nb_g = (int)(((size_t)N * DD + 255) / 256);
    k_gather<<<nb_g, blk, 0, stream>>>(sigma, perm_f, row_f, src, A2h, agg_f, N);
    k_gather<<<nb_g, blk, 0, stream>>>(sigma, perm_b, row_b, dst, A3h, agg_b, N);

    k_node_pre<<<1024, blk, 0, stream>>>(A1h, agg_f, agg_b,
        out, stats + 256, (long long)ND);
    k_bn_final<<<1, 64, 0, stream>>>(stats + 256, 1.0f / (float)N, bnhg, bnhb,
                                     stats + 384, stats + 448);
    k_node_out<<<1024, blk, 0, stream>>>(h, stats + 384, stats + 448,
                                         out, (long long)ND);

    if (!ws_big) {
        // e passthrough (overwrites sigma scratch in the out e-region)
        hipMemcpyAsync(gbuf, e, ED * sizeof(float), hipMemcpyDeviceToDevice, stream);
    }
}

// Round 6
// 1106.657 us; speedup vs baseline: 1.5407x; 1.3043x over previous
//
#include <hip/hip_runtime.h>
#include <cstdint>
#include <cstddef>

#define DD 64
#define TILE 64
#define LSTR 65   // padded LDS row stride (floats): (r*65+c)%32 == (r+c)%32 -> <=2-way
constexpr float BN_EPS  = 1e-5f;
constexpr float DEG_EPS = 1e-6f;

__device__ __forceinline__ float fatomic_add(float* p, float v) {
    return unsafeAtomicAdd(p, v);   // hardware global_atomic_add_f32
}

// =============== tiled linear: o = x @ W^T + b, LDS-staged both ways =========
// grid.x = row-chunks of 64, grid.y = which of 5 matrices
__global__ __launch_bounds__(256) void k_tile_linear(
    const float* __restrict__ x, int R,
    const float* __restrict__ w0, const float* __restrict__ b0, float* __restrict__ o0,
    const float* __restrict__ w1, const float* __restrict__ b1, float* __restrict__ o1,
    const float* __restrict__ w2, const float* __restrict__ b2, float* __restrict__ o2,
    const float* __restrict__ w3, const float* __restrict__ b3, float* __restrict__ o3,
    const float* __restrict__ w4, const float* __restrict__ b4, float* __restrict__ o4)
{
    const float* w; const float* b; float* o;
    switch (blockIdx.y) {
        case 0:  w = w0; b = b0; o = o0; break;
        case 1:  w = w1; b = b1; o = o1; break;
        case 2:  w = w2; b = b2; o = o2; break;
        case 3:  w = w3; b = b3; o = o3; break;
        default: w = w4; b = b4; o = o4; break;
    }
    __shared__ float ldsE[TILE * LSTR];
    __shared__ float ldsG[TILE * LSTR];
    int tid  = threadIdx.x;
    int lane = tid & 63;
    int base = blockIdx.x * TILE;
    int rem  = R - base; if (rem > TILE) rem = TILE;
    int qu   = __builtin_amdgcn_readfirstlane(tid >> 6);   // wave id 0..3, SGPR

    // phase 1: stage x rows -> ldsE (coalesced 1KB/wave-instr global reads)
    const float4* x4 = reinterpret_cast<const float4*>(x + (size_t)base * DD);
    #pragma unroll
    for (int j = 0; j < 4; ++j) {
        int f4 = j * 256 + tid;          // float4 index in tile
        int r  = f4 >> 4, c = f4 & 15;
        if (r < rem) {
            float4 v = x4[f4];
            ldsE[r * LSTR + c * 4 + 0] = v.x;
            ldsE[r * LSTR + c * 4 + 1] = v.y;
            ldsE[r * LSTR + c * 4 + 2] = v.z;
            ldsE[r * LSTR + c * 4 + 3] = v.w;
        }
    }
    __syncthreads();

    // phase 2: GEMV, thread = (row=lane, d-quarter=qu); W via uniform s_load
    {
        float acc[16];
        #pragma unroll
        for (int i = 0; i < 16; ++i) acc[i] = b[qu * 16 + i];
        #pragma unroll 4
        for (int k = 0; k < 64; ++k) {
            float ev = ldsE[lane * LSTR + k];
            const float* wq = w + (size_t)(qu * 16) * DD + k;
            #pragma unroll
            for (int i = 0; i < 16; ++i)
                acc[i] = fmaf(ev, wq[(size_t)i * DD], acc[i]);
        }
        #pragma unroll
        for (int i = 0; i < 16; ++i)
            ldsG[lane * LSTR + qu * 16 + i] = acc[i];
    }
    __syncthreads();

    // phase 3: linear write-out (coalesced 1KB/wave-instr global stores)
    float4* op4 = reinterpret_cast<float4*>(o + (size_t)base * DD);
    #pragma unroll
    for (int j = 0; j < 4; ++j) {
        int f4 = j * 256 + tid;
        int r  = f4 >> 4, c = f4 & 15;
        if (r < rem) {
            float4 v;
            v.x = ldsG[r * LSTR + c * 4 + 0];
            v.y = ldsG[r * LSTR + c * 4 + 1];
            v.z = ldsG[r * LSTR + c * 4 + 2];
            v.w = ldsG[r * LSTR + c * 4 + 3];
            op4[f4] = v;
        }
    }
}

// =============== fused edge gate: g = B3 e + b3 + B1h[src] + B2h[dst] ========
// Block per 64-edge tile. Phase 1: stage e. Phase 2: GEMV (uniform W s_loads).
// Phase 3: lane=d row adds (coalesced 256B lines) + BN-e column stats + g write.
__global__ __launch_bounds__(256) void k_edge_fused(
    const float* __restrict__ e,
    const int* __restrict__ src, const int* __restrict__ dst,
    const float* __restrict__ B1h, const float* __restrict__ B2h,
    const float* __restrict__ w, const float* __restrict__ b,
    float* __restrict__ g, float* __restrict__ sums, int E)
{
    __shared__ float ldsE[TILE * LSTR];
    __shared__ float ldsG[TILE * LSTR];
    __shared__ float red[256];
    int tid  = threadIdx.x;
    int lane = tid & 63;
    int base = blockIdx.x * TILE;
    int rem  = E - base; if (rem > TILE) rem = TILE;
    int qu   = __builtin_amdgcn_readfirstlane(tid >> 6);

    // phase 1: stage e tile
    const float4* e4 = reinterpret_cast<const float4*>(e + (size_t)base * DD);
    #pragma unroll
    for (int j = 0; j < 4; ++j) {
        int f4 = j * 256 + tid;
        int r  = f4 >> 4, c = f4 & 15;
        if (r < rem) {
            float4 v = e4[f4];
            ldsE[r * LSTR + c * 4 + 0] = v.x;
            ldsE[r * LSTR + c * 4 + 1] = v.y;
            ldsE[r * LSTR + c * 4 + 2] = v.z;
            ldsE[r * LSTR + c * 4 + 3] = v.w;
        }
    }
    __syncthreads();

    // phase 2: GEMV B3 * e_row + b3
    {
        float acc[16];
        #pragma unroll
        for (int i = 0; i < 16; ++i) acc[i] = b[qu * 16 + i];
        #pragma unroll 4
        for (int k = 0; k < 64; ++k) {
            float ev = ldsE[lane * LSTR + k];
            const float* wq = w + (size_t)(qu * 16) * DD + k;
            #pragma unroll
            for (int i = 0; i < 16; ++i)
                acc[i] = fmaf(ev, wq[(size_t)i * DD], acc[i]);
        }
        #pragma unroll
        for (int i = 0; i < 16; ++i)
            ldsG[lane * LSTR + qu * 16 + i] = acc[i];
    }
    __syncthreads();

    // phase 3: wave-per-edge row adds + stats + coalesced g write (lane = col d)
    float ps = 0.f, pq = 0.f;
    #pragma unroll 4
    for (int it = 0; it < 16; ++it) {
        int el = qu * 16 + it;               // wave-uniform
        if (el < rem) {
            int ee = base + el;
            int s = src[ee], t = dst[ee];
            float v = ldsG[el * LSTR + lane]
                    + B1h[(size_t)s * DD + lane]
                    + B2h[(size_t)t * DD + lane];
            g[(size_t)ee * DD + lane] = v;
            ps += v; pq += v * v;
        }
    }
    red[tid] = ps; __syncthreads();
    if (tid < 64) fatomic_add(&sums[tid],      red[tid] + red[tid+64] + red[tid+128] + red[tid+192]);
    __syncthreads();
    red[tid] = pq; __syncthreads();
    if (tid < 64) fatomic_add(&sums[64 + tid], red[tid] + red[tid+64] + red[tid+128] + red[tid+192]);
}

// ---------------- fold stats into scale/shift --------------------------------
__global__ void k_bn_final(const float* __restrict__ sums, float inv_cnt,
                           const float* __restrict__ gamma, const float* __restrict__ beta,
                           float* __restrict__ scale, float* __restrict__ shift)
{
    int d = threadIdx.x;
    if (d >= DD) return;
    float mean = sums[d] * inv_cnt;
    float var  = fmaxf(sums[64 + d] * inv_cnt - mean * mean, 0.f);
    float rs   = rsqrtf(var + BN_EPS);
    float sc   = gamma[d] * rs;
    scale[d] = sc;
    shift[d] = beta[d] - mean * sc;
}

// ---------------- CSR build: count, single merged scan (2N), place -----------
__global__ __launch_bounds__(256) void k_count(
    const int* __restrict__ src, const int* __restrict__ dst,
    int* __restrict__ cnt2, int N, int E)
{
    int ee = blockIdx.x * 256 + threadIdx.x;
    if (ee >= E) return;
    atomicAdd(&cnt2[dst[ee]], 1);        // fwd counts at [0,N)
    atomicAdd(&cnt2[N + src[ee]], 1);    // bwd counts at [N,2N)
}

// exclusive scan over n entries; writes row (n+1 entries) and cur (n entries).
// cnt and cur may alias.
__global__ __launch_bounds__(1024) void k_scan(
    const int* cnt, int* row, int* cur, int n, int total)
{
    __shared__ int tmp[1024];
    int tid = threadIdx.x;
    int carry = 0;
    for (int basei = 0; basei < n; basei += 1024) {
        int i = basei + tid;
        int v = (i < n) ? cnt[i] : 0;
        tmp[tid] = v; __syncthreads();
        for (int off = 1; off < 1024; off <<= 1) {
            int t = (tid >= off) ? tmp[tid - off] : 0;
            __syncthreads();
            tmp[tid] += t;
            __syncthreads();
        }
        int excl = carry + tmp[tid] - v;
        if (i < n) { row[i] = excl; cur[i] = excl; }
        carry += tmp[1023];
        __syncthreads();
    }
    if (tid == 0) row[n] = total;
}

__global__ __launch_bounds__(256) void k_place(
    const int* __restrict__ src, const int* __restrict__ dst,
    int* __restrict__ cur2, int* __restrict__ perm2, int N, int E)
{
    int ee = blockIdx.x * 256 + threadIdx.x;
    if (ee >= E) return;
    int pf = atomicAdd(&cur2[dst[ee]], 1);
    perm2[pf] = ee;
    int pb = atomicAdd(&cur2[N + src[ee]], 1);
    perm2[pb] = ee;                      // bwd slots live at [E, 2E)
}

// ---------------- sigma = sigmoid(relu(bn(g)) + e), float4-vectorized --------
__global__ __launch_bounds__(256) void k_edge_sigma(
    const float4* g, const float4* __restrict__ e,
    float4* sig, float4* ecopy,
    const float* __restrict__ scale, const float* __restrict__ shift,
    long long total4)
{
    long long idx = (long long)blockIdx.x * 256 + threadIdx.x;
    if (idx >= total4) return;
    int q = (int)(idx & 15);
    float4 sc = reinterpret_cast<const float4*>(scale)[q];
    float4 sh = reinterpret_cast<const float4*>(shift)[q];
    float4 gv = g[idx];
    float4 ev = e[idx];
    float4 o;
    o.x = 1.f / (1.f + __expf(-(fmaxf(gv.x * sc.x + sh.x, 0.f) + ev.x)));
    o.y = 1.f / (1.f + __expf(-(fmaxf(gv.y * sc.y + sh.y, 0.f) + ev.y)));
    o.z = 1.f / (1.f + __expf(-(fmaxf(gv.z * sc.z + sh.z, 0.f) + ev.z)));
    o.w = 1.f / (1.f + __expf(-(fmaxf(gv.w * sc.w + sh.w, 0.f) + ev.w)));
    sig[idx] = o;
    if (ecopy) ecopy[idx] = ev;
}

// ---------------- gather: wave per node, 4 edge slots x float4 cols ----------
__global__ __launch_bounds__(256) void k_gather(
    const float* __restrict__ sigma, const int* __restrict__ perm,
    const int* __restrict__ row, const int* __restrict__ other_idx,
    const float* __restrict__ Ah, float* __restrict__ agg, int N)
{
    int wid  = (blockIdx.x * 256 + threadIdx.x) >> 6;
    int lane = threadIdx.x & 63;
    if (wid >= N) return;
    int q  = lane >> 4;      // edge slot 0..3
    int dj = lane & 15;      // float4 column slot
    int beg = row[wid], end = row[wid + 1];
    float4 num = {0.f, 0.f, 0.f, 0.f};
    float4 den = {0.f, 0.f, 0.f, 0.f};
    const float4* sig4 = reinterpret_cast<const float4*>(sigma);
    const float4* Ah4  = reinterpret_cast<const float4*>(Ah);
    for (int k = beg + q; k < end; k += 4) {
        int eid = perm[k];
        int o   = other_idx[eid];
        float4 s4 = sig4[(size_t)eid * 16 + dj];
        float4 a4 = Ah4[(size_t)o * 16 + dj];
        num.x += s4.x * a4.x; num.y += s4.y * a4.y;
        num.z += s4.z * a4.z; num.w += s4.w * a4.w;
        den.x += s4.x; den.y += s4.y; den.z += s4.z; den.w += s4.w;
    }
    // reduce across the 4 edge slots (lanes xor 16, 32)
    #pragma unroll
    for (int off = 16; off <= 32; off <<= 1) {
        num.x += __shfl_xor(num.x, off); num.y += __shfl_xor(num.y, off);
        num.z += __shfl_xor(num.z, off); num.w += __shfl_xor(num.w, off);
        den.x += __shfl_xor(den.x, off); den.y += __shfl_xor(den.y, off);
        den.z += __shfl_xor(den.z, off); den.w += __shfl_xor(den.w, off);
    }
    if (q == 0) {
        float4 res;
        res.x = num.x / (den.x + DEG_EPS);
        res.y = num.y / (den.y + DEG_EPS);
        res.z = num.z / (den.z + DEG_EPS);
        res.w = num.w / (den.w + DEG_EPS);
        reinterpret_cast<float4*>(agg)[(size_t)wid * 16 + dj] = res;
    }
}

// ---------------- h_pre = A1h + agg_f + agg_b, + column stats ----------------
__global__ __launch_bounds__(256) void k_node_pre(
    const float* __restrict__ A1h,
    const float* __restrict__ agg_f, const float* __restrict__ agg_b,
    float* __restrict__ hpre, float* __restrict__ sums, long long total)
{
    int tid = threadIdx.x;
    long long idx = (long long)blockIdx.x * 256 + tid;
    long long stride = (long long)gridDim.x * 256;
    float ps = 0.f, pq = 0.f;
    for (; idx < total; idx += stride) {
        float v = A1h[idx] + agg_f[idx] + agg_b[idx];
        hpre[idx] = v;
        ps += v; pq += v * v;
    }
    __shared__ float red[256];
    red[tid] = ps; __syncthreads();
    if (tid < 64) fatomic_add(&sums[tid],      red[tid] + red[tid+64] + red[tid+128] + red[tid+192]);
    __syncthreads();
    red[tid] = pq; __syncthreads();
    if (tid < 64) fatomic_add(&sums[64 + tid], red[tid] + red[tid+64] + red[tid+128] + red[tid+192]);
}

// ---------------- finish h: BN affine + relu + residual (in place) -----------
__global__ __launch_bounds__(256) void k_node_out(
    const float* __restrict__ h,
    const float* __restrict__ scale, const float* __restrict__ shift,
    float* __restrict__ out, long long total)
{
    long long idx = (long long)blockIdx.x * 256 + threadIdx.x;
    long long stride = (long long)gridDim.x * 256;
    for (; idx < total; idx += stride) {
        int d = (int)(idx & (DD - 1));
        float v = out[idx] * scale[d] + shift[d];
        out[idx] = fmaxf(v, 0.f) + h[idx];
    }
}

extern "C" void kernel_launch(void* const* d_in, const int* in_sizes, int n_in,
                              void* d_out, int out_size, void* d_ws, size_t ws_size,
                              hipStream_t stream)
{
    const float* h    = (const float*)d_in[0];
    const float* e    = (const float*)d_in[1];
    const int*   src  = (const int*)d_in[2];
    const int*   dst  = (const int*)d_in[3];
    const float* A1w  = (const float*)d_in[4];
    const float* A1b  = (const float*)d_in[5];
    const float* A2w  = (const float*)d_in[6];
    const float* A2b  = (const float*)d_in[7];
    const float* A3w  = (const float*)d_in[8];
    const float* A3b  = (const float*)d_in[9];
    const float* B1w  = (const float*)d_in[10];
    const float* B1b  = (const float*)d_in[11];
    const float* B2w  = (const float*)d_in[12];
    const float* B2b  = (const float*)d_in[13];
    const float* B3w  = (const float*)d_in[14];
    const float* B3b  = (const float*)d_in[15];
    const float* bnhg = (const float*)d_in[16];
    const float* bnhb = (const float*)d_in[17];
    const float* bneg = (const float*)d_in[18];
    const float* bneb = (const float*)d_in[19];

    const int N = in_sizes[0] / DD;
    const int E = in_sizes[1] / DD;
    const size_t ND = (size_t)N * DD;
    const size_t ED = (size_t)E * DD;

    float* ws    = (float*)d_ws;
    float* A1h   = ws + 0 * ND;
    float* A2h   = ws + 1 * ND;
    float* A3h   = ws + 2 * ND;
    float* B1h   = ws + 3 * ND;
    float* B2h   = ws + 4 * ND;
    float* agg_f = ws + 5 * ND;
    float* agg_b = ws + 6 * ND;
    float* stats = ws + 7 * ND;   // 512 floats (e/h: sum,sq,scale,shift)

    const size_t int_count = 4 * (size_t)N + 1 + 2 * (size_t)E;
    const size_t need_big  = (7 * ND + 512 + ED) * sizeof(float) + int_count * sizeof(int);
    const bool   ws_big    = ws_size >= need_big;

    float* sig_ws = stats + 512;                        // ED floats (only if ws_big)
    int*   ibase  = (int*)(ws_big ? (sig_ws + ED) : (stats + 512));
    int* cur2  = ibase;                 // 2N (counts -> cursors)
    int* row2  = ibase + 2 * N;         // 2N+1 (fwd rows [0,N], bwd rows [N,2N])
    int* perm2 = ibase + 4 * N + 1;     // 2E  (fwd [0,E), bwd [E,2E))

    float* out  = (float*)d_out;
    float* gbuf = out + ND;   // out e-region: g -> (sigma | e)

    hipMemsetAsync(stats, 0, 512 * sizeof(float), stream);
    hipMemsetAsync(cur2, 0, 2 * (size_t)N * sizeof(int), stream);

    dim3 blk(256);
    int nb_e  = (E + 255) / 256;
    int nt_n  = (N + TILE - 1) / TILE;
    int nt_e  = (E + TILE - 1) / TILE;

    k_tile_linear<<<dim3(nt_n, 5), blk, 0, stream>>>(h, N,
        A1w, A1b, A1h,  A2w, A2b, A2h,  A3w, A3b, A3h,
        B1w, B1b, B1h,  B2w, B2b, B2h);

    // CSR build (fwd+bwd merged)
    k_count<<<nb_e, blk, 0, stream>>>(src, dst, cur2, N, E);
    k_scan<<<1, 1024, 0, stream>>>(cur2, row2, cur2, 2 * N, 2 * E);
    k_place<<<nb_e, blk, 0, stream>>>(src, dst, cur2, perm2, N, E);

    // fused edge gate + BN-e stats
    k_edge_fused<<<nt_e, blk, 0, stream>>>(e, src, dst, B1h, B2h, B3w, B3b,
                                           gbuf, stats, E);
    k_bn_final<<<1, 64, 0, stream>>>(stats, 1.0f / (float)E, bneg, bneb,
                                     stats + 128, stats + 192);

    long long total4 = (long long)(ED / 4);
    int nb_s = (int)((total4 + 255) / 256);
    float* sigma = ws_big ? sig_ws : gbuf;
    k_edge_sigma<<<nb_s, blk, 0, stream>>>(
        (const float4*)gbuf, (const float4*)e,
        (float4*)sigma, ws_big ? (float4*)gbuf : nullptr,
        stats + 128, stats + 192, total4);

    int nb_g = (int)(((size_t)N * DD + 255) / 256);
    k_gather<<<nb_g, blk, 0, stream>>>(sigma, perm2, row2,     src, A2h, agg_f, N);
    k_gather<<<nb_g, blk, 0, stream>>>(sigma, perm2, row2 + N, dst, A3h, agg_b, N);

    k_node_pre<<<1024, blk, 0, stream>>>(A1h, agg_f, agg_b,
        out, stats + 256, (long long)ND);
    k_bn_final<<<1, 64, 0, stream>>>(stats + 256, 1.0f / (float)N, bnhg, bnhb,
                                     stats + 384, stats + 448);
    k_node_out<<<1024, blk, 0, stream>>>(h, stats + 384, stats + 448,
                                         out, (long long)ND);

    if (!ws_big) {
        hipMemcpyAsync(gbuf, e, ED * sizeof(float), hipMemcpyDeviceToDevice, stream);
    }
}

// Round 7
// 911.526 us; speedup vs baseline: 1.8705x; 1.2141x over previous
//
#include <hip/hip_runtime.h>
#include <cstdint>
#include <cstddef>

#define DD 64
#define TILE 64
#define LSTR 65   // padded LDS row stride (floats): bank = (row + col) % 32 -> <=2-way (free)
constexpr float BN_EPS  = 1e-5f;
constexpr float DEG_EPS = 1e-6f;

__device__ __forceinline__ float fatomic_add(float* p, float v) {
    return unsafeAtomicAdd(p, v);   // hardware global_atomic_add_f32
}

// =============== tiled linear: o = x @ W^T + b, single LDS buffer ============
// grid.x = row-chunks of 64, grid.y = which of 5 matrices
__global__ __launch_bounds__(256) void k_tile_linear(
    const float* __restrict__ x, int R,
    const float* __restrict__ w0, const float* __restrict__ b0, float* __restrict__ o0,
    const float* __restrict__ w1, const float* __restrict__ b1, float* __restrict__ o1,
    const float* __restrict__ w2, const float* __restrict__ b2, float* __restrict__ o2,
    const float* __restrict__ w3, const float* __restrict__ b3, float* __restrict__ o3,
    const float* __restrict__ w4, const float* __restrict__ b4, float* __restrict__ o4)
{
    const float* w; const float* b; float* o;
    switch (blockIdx.y) {
        case 0:  w = w0; b = b0; o = o0; break;
        case 1:  w = w1; b = b1; o = o1; break;
        case 2:  w = w2; b = b2; o = o2; break;
        case 3:  w = w3; b = b3; o = o3; break;
        default: w = w4; b = b4; o = o4; break;
    }
    __shared__ float ldsE[TILE * LSTR];
    int tid  = threadIdx.x;
    int lane = tid & 63;
    int base = blockIdx.x * TILE;
    int rem  = R - base; if (rem > TILE) rem = TILE;
    int qu   = __builtin_amdgcn_readfirstlane(tid >> 6);   // wave id 0..3, SGPR

    // phase 1: stage x rows -> ldsE (coalesced 1KB/wave-instr global reads)
    const float4* x4 = reinterpret_cast<const float4*>(x + (size_t)base * DD);
    #pragma unroll
    for (int j = 0; j < 4; ++j) {
        int f4 = j * 256 + tid;          // float4 index in tile
        int r  = f4 >> 4, c = f4 & 15;
        if (r < rem) {
            float4 v = x4[f4];
            ldsE[r * LSTR + c * 4 + 0] = v.x;
            ldsE[r * LSTR + c * 4 + 1] = v.y;
            ldsE[r * LSTR + c * 4 + 2] = v.z;
            ldsE[r * LSTR + c * 4 + 3] = v.w;
        }
    }
    __syncthreads();

    // phase 2: GEMV, thread = (row=lane, d-quarter=qu); W via uniform s_load
    float acc[16];
    #pragma unroll
    for (int i = 0; i < 16; ++i) acc[i] = b[qu * 16 + i];
    #pragma unroll 4
    for (int k = 0; k < 64; ++k) {
        float ev = ldsE[lane * LSTR + k];
        const float* wq = w + (size_t)(qu * 16) * DD + k;
        #pragma unroll
        for (int i = 0; i < 16; ++i)
            acc[i] = fmaf(ev, wq[(size_t)i * DD], acc[i]);
    }
    __syncthreads();   // all reads of ldsE done -> safe to overwrite
    #pragma unroll
    for (int i = 0; i < 16; ++i)
        ldsE[lane * LSTR + qu * 16 + i] = acc[i];
    __syncthreads();

    // phase 3: linear write-out (coalesced 1KB/wave-instr global stores)
    float4* outp4 = reinterpret_cast<float4*>(o + (size_t)base * DD);
    #pragma unroll
    for (int j = 0; j < 4; ++j) {
        int f4 = j * 256 + tid;
        int r  = f4 >> 4, c = f4 & 15;
        if (r < rem) {
            float4 v;
            v.x = ldsE[r * LSTR + c * 4 + 0];
            v.y = ldsE[r * LSTR + c * 4 + 1];
            v.z = ldsE[r * LSTR + c * 4 + 2];
            v.w = ldsE[r * LSTR + c * 4 + 3];
            outp4[f4] = v;
        }
    }
}

// =============== fused edge gate: g = B3 e + b3 + B1h[src] + B2h[dst] ========
// Block per 64-edge tile, single LDS buffer (17.7 KB -> 8 blocks/CU).
__global__ __launch_bounds__(256) void k_edge_fused(
    const float* __restrict__ e,
    const int* __restrict__ src, const int* __restrict__ dst,
    const float* __restrict__ B1h, const float* __restrict__ B2h,
    const float* __restrict__ w, const float* __restrict__ b,
    float* __restrict__ g, float* __restrict__ sums, int E)
{
    __shared__ float ldsE[TILE * LSTR];
    __shared__ float red[256];
    int tid  = threadIdx.x;
    int lane = tid & 63;
    int base = blockIdx.x * TILE;
    int rem  = E - base; if (rem > TILE) rem = TILE;
    int qu   = __builtin_amdgcn_readfirstlane(tid >> 6);

    // phase 1: stage e tile
    const float4* e4 = reinterpret_cast<const float4*>(e + (size_t)base * DD);
    #pragma unroll
    for (int j = 0; j < 4; ++j) {
        int f4 = j * 256 + tid;
        int r  = f4 >> 4, c = f4 & 15;
        if (r < rem) {
            float4 v = e4[f4];
            ldsE[r * LSTR + c * 4 + 0] = v.x;
            ldsE[r * LSTR + c * 4 + 1] = v.y;
            ldsE[r * LSTR + c * 4 + 2] = v.z;
            ldsE[r * LSTR + c * 4 + 3] = v.w;
        }
    }
    __syncthreads();

    // phase 2: GEMV B3 * e_row + b3 (acc in regs)
    float acc[16];
    #pragma unroll
    for (int i = 0; i < 16; ++i) acc[i] = b[qu * 16 + i];
    #pragma unroll 4
    for (int k = 0; k < 64; ++k) {
        float ev = ldsE[lane * LSTR + k];
        const float* wq = w + (size_t)(qu * 16) * DD + k;
        #pragma unroll
        for (int i = 0; i < 16; ++i)
            acc[i] = fmaf(ev, wq[(size_t)i * DD], acc[i]);
    }
    __syncthreads();   // reads done -> overwrite ldsE with g0
    #pragma unroll
    for (int i = 0; i < 16; ++i)
        ldsE[lane * LSTR + qu * 16 + i] = acc[i];
    __syncthreads();

    // phase 3: wave-per-edge row adds + stats + coalesced g write (lane = col d)
    // full unroll: 16x2 wave-uniform s_loads + 32 row loads issue early (MLP)
    float ps = 0.f, pq = 0.f;
    #pragma unroll
    for (int it = 0; it < 16; ++it) {
        int el = qu * 16 + it;               // wave-uniform
        if (el < rem) {
            int ee = base + el;
            int s = src[ee], t = dst[ee];    // scalar loads (uniform address)
            float v = ldsE[el * LSTR + lane]
                    + B1h[(size_t)s * DD + lane]
                    + B2h[(size_t)t * DD + lane];
            g[(size_t)ee * DD + lane] = v;
            ps += v; pq += v * v;
        }
    }
    red[tid] = ps; __syncthreads();
    if (tid < 64) fatomic_add(&sums[tid],      red[tid] + red[tid+64] + red[tid+128] + red[tid+192]);
    __syncthreads();
    red[tid] = pq; __syncthreads();
    if (tid < 64) fatomic_add(&sums[64 + tid], red[tid] + red[tid+64] + red[tid+128] + red[tid+192]);
}

// ---------------- fold stats into scale/shift --------------------------------
__global__ void k_bn_final(const float* __restrict__ sums, float inv_cnt,
                           const float* __restrict__ gamma, const float* __restrict__ beta,
                           float* __restrict__ scale, float* __restrict__ shift)
{
    int d = threadIdx.x;
    if (d >= DD) return;
    float mean = sums[d] * inv_cnt;
    float var  = fmaxf(sums[64 + d] * inv_cnt - mean * mean, 0.f);
    float rs   = rsqrtf(var + BN_EPS);
    float sc   = gamma[d] * rs;
    scale[d] = sc;
    shift[d] = beta[d] - mean * sc;
}

// ---------------- CSR build ---------------------------------------------------
__global__ __launch_bounds__(256) void k_count(
    const int* __restrict__ src, const int* __restrict__ dst,
    int* __restrict__ cnt2, int N, int E)
{
    int ee = blockIdx.x * 256 + threadIdx.x;
    if (ee >= E) return;
    atomicAdd(&cnt2[dst[ee]], 1);        // fwd counts at [0,N)
    atomicAdd(&cnt2[N + src[ee]], 1);    // bwd counts at [N,2N)
}

// hierarchical exclusive scan: block-local -> carry -> add
__global__ __launch_bounds__(1024) void k_scan_blk(
    const int* __restrict__ cnt, int* __restrict__ row, int* __restrict__ part, int n)
{
    __shared__ int tmp[1024];
    int tid = threadIdx.x;
    int i   = blockIdx.x * 1024 + tid;
    int v   = (i < n) ? cnt[i] : 0;
    tmp[tid] = v; __syncthreads();
    for (int off = 1; off < 1024; off <<= 1) {
        int t = (tid >= off) ? tmp[tid - off] : 0;
        __syncthreads();
        tmp[tid] += t;
        __syncthreads();
    }
    if (i < n) row[i] = tmp[tid] - v;            // local exclusive
    if (tid == 1023) part[blockIdx.x] = tmp[1023];  // block total
}

__global__ __launch_bounds__(1024) void k_scan_carry(int* part, int nb)
{
    __shared__ int tmp[1024];
    int tid = threadIdx.x;
    int carry = 0;
    for (int base = 0; base < nb; base += 1024) {
        int i = base + tid;
        int v = (i < nb) ? part[i] : 0;
        tmp[tid] = v; __syncthreads();
        for (int off = 1; off < 1024; off <<= 1) {
            int t = (tid >= off) ? tmp[tid - off] : 0;
            __syncthreads();
            tmp[tid] += t;
            __syncthreads();
        }
        if (i < nb) part[i] = carry + tmp[tid] - v;
        carry += tmp[1023];
        __syncthreads();
    }
}

__global__ __launch_bounds__(1024) void k_scan_add(
    int* __restrict__ row, int* __restrict__ cur, const int* __restrict__ part,
    int n, int total)
{
    int i = blockIdx.x * 1024 + threadIdx.x;
    if (i < n) {
        int r = row[i] + part[blockIdx.x];
        row[i] = r; cur[i] = r;
    }
    if (i == 0) row[n] = total;
}

// place packed (eid, other-node) pairs -> kills one dependent load in gather
__global__ __launch_bounds__(256) void k_place(
    const int* __restrict__ src, const int* __restrict__ dst,
    int* __restrict__ cur2, int2* __restrict__ pair2, int N, int E)
{
    int ee = blockIdx.x * 256 + threadIdx.x;
    if (ee >= E) return;
    int s = src[ee], t = dst[ee];
    int pf = atomicAdd(&cur2[t], 1);
    pair2[pf] = make_int2(ee, s);
    int pb = atomicAdd(&cur2[N + s], 1);
    pair2[pb] = make_int2(ee, t);        // bwd slots live at [E, 2E)
}

// ---------------- sigma = sigmoid(relu(bn(g)) + e), float4-vectorized --------
__global__ __launch_bounds__(256) void k_edge_sigma(
    const float4* g, const float4* __restrict__ e,
    float4* sig, float4* ecopy,
    const float* __restrict__ scale, const float* __restrict__ shift,
    long long total4)
{
    long long idx = (long long)blockIdx.x * 256 + threadIdx.x;
    if (idx >= total4) return;
    int q = (int)(idx & 15);
    float4 sc = reinterpret_cast<const float4*>(scale)[q];
    float4 sh = reinterpret_cast<const float4*>(shift)[q];
    float4 gv = g[idx];
    float4 ev = e[idx];
    float4 o;
    o.x = 1.f / (1.f + __expf(-(fmaxf(gv.x * sc.x + sh.x, 0.f) + ev.x)));
    o.y = 1.f / (1.f + __expf(-(fmaxf(gv.y * sc.y + sh.y, 0.f) + ev.y)));
    o.z = 1.f / (1.f + __expf(-(fmaxf(gv.z * sc.z + sh.z, 0.f) + ev.z)));
    o.w = 1.f / (1.f + __expf(-(fmaxf(gv.w * sc.w + sh.w, 0.f) + ev.w)));
    sig[idx] = o;
    if (ecopy) ecopy[idx] = ev;
}

// ---------------- gather: wave per node, 4 edge slots x float4 cols ----------
__global__ __launch_bounds__(256) void k_gather(
    const float* __restrict__ sigma, const int2* __restrict__ pair2,
    const int* __restrict__ row,
    const float* __restrict__ Ah, float* __restrict__ agg, int N)
{
    int wid  = (blockIdx.x * 256 + threadIdx.x) >> 6;
    int lane = threadIdx.x & 63;
    if (wid >= N) return;
    int q  = lane >> 4;      // edge slot 0..3
    int dj = lane & 15;      // float4 column slot
    int beg = row[wid], end = row[wid + 1];
    float4 num = {0.f, 0.f, 0.f, 0.f};
    float4 den = {0.f, 0.f, 0.f, 0.f};
    const float4* sig4 = reinterpret_cast<const float4*>(sigma);
    const float4* Ah4  = reinterpret_cast<const float4*>(Ah);
    for (int k = beg + q; k < end; k += 4) {
        int2 p = pair2[k];                        // {eid, other}
        float4 s4 = sig4[(size_t)p.x * 16 + dj];
        float4 a4 = Ah4[(size_t)p.y * 16 + dj];
        num.x += s4.x * a4.x; num.y += s4.y * a4.y;
        num.z += s4.z * a4.z; num.w += s4.w * a4.w;
        den.x += s4.x; den.y += s4.y; den.z += s4.z; den.w += s4.w;
    }
    // reduce across the 4 edge slots (lanes xor 16, 32)
    #pragma unroll
    for (int off = 16; off <= 32; off <<= 1) {
        num.x += __shfl_xor(num.x, off); num.y += __shfl_xor(num.y, off);
        num.z += __shfl_xor(num.z, off); num.w += __shfl_xor(num.w, off);
        den.x += __shfl_xor(den.x, off); den.y += __shfl_xor(den.y, off);
        den.z += __shfl_xor(den.z, off); den.w += __shfl_xor(den.w, off);
    }
    if (q == 0) {
        float4 res;
        res.x = num.x / (den.x + DEG_EPS);
        res.y = num.y / (den.y + DEG_EPS);
        res.z = num.z / (den.z + DEG_EPS);
        res.w = num.w / (den.w + DEG_EPS);
        reinterpret_cast<float4*>(agg)[(size_t)wid * 16 + dj] = res;
    }
}

// ---------------- h_pre = A1h + agg_f + agg_b, + column stats ----------------
__global__ __launch_bounds__(256) void k_node_pre(
    const float* __restrict__ A1h,
    const float* __restrict__ agg_f, const float* __restrict__ agg_b,
    float* __restrict__ hpre, float* __restrict__ sums, long long total)
{
    int tid = threadIdx.x;
    long long idx = (long long)blockIdx.x * 256 + tid;
    long long stride = (long long)gridDim.x * 256;
    float ps = 0.f, pq = 0.f;
    for (; idx < total; idx += stride) {
        float v = A1h[idx] + agg_f[idx] + agg_b[idx];
        hpre[idx] = v;
        ps += v; pq += v * v;
    }
    __shared__ float red[256];
    red[tid] = ps; __syncthreads();
    if (tid < 64) fatomic_add(&sums[tid],      red[tid] + red[tid+64] + red[tid+128] + red[tid+192]);
    __syncthreads();
    red[tid] = pq; __syncthreads();
    if (tid < 64) fatomic_add(&sums[64 + tid], red[tid] + red[tid+64] + red[tid+128] + red[tid+192]);
}

// ---------------- finish h: BN affine + relu + residual (in place) -----------
__global__ __launch_bounds__(256) void k_node_out(
    const float* __restrict__ h,
    const float* __restrict__ scale, const float* __restrict__ shift,
    float* __restrict__ out, long long total)
{
    long long idx = (long long)blockIdx.x * 256 + threadIdx.x;
    long long stride = (long long)gridDim.x * 256;
    for (; idx < total; idx += stride) {
        int d = (int)(idx & (DD - 1));
        float v = out[idx] * scale[d] + shift[d];
        out[idx] = fmaxf(v, 0.f) + h[idx];
    }
}

extern "C" void kernel_launch(void* const* d_in, const int* in_sizes, int n_in,
                              void* d_out, int out_size, void* d_ws, size_t ws_size,
                              hipStream_t stream)
{
    const float* h    = (const float*)d_in[0];
    const float* e    = (const float*)d_in[1];
    const int*   src  = (const int*)d_in[2];
    const int*   dst  = (const int*)d_in[3];
    const float* A1w  = (const float*)d_in[4];
    const float* A1b  = (const float*)d_in[5];
    const float* A2w  = (const float*)d_in[6];
    const float* A2b  = (const float*)d_in[7];
    const float* A3w  = (const float*)d_in[8];
    const float* A3b  = (const float*)d_in[9];
    const float* B1w  = (const float*)d_in[10];
    const float* B1b  = (const float*)d_in[11];
    const float* B2w  = (const float*)d_in[12];
    const float* B2b  = (const float*)d_in[13];
    const float* B3w  = (const float*)d_in[14];
    const float* B3b  = (const float*)d_in[15];
    const float* bnhg = (const float*)d_in[16];
    const float* bnhb = (const float*)d_in[17];
    const float* bneg = (const float*)d_in[18];
    const float* bneb = (const float*)d_in[19];

    const int N = in_sizes[0] / DD;
    const int E = in_sizes[1] / DD;
    const size_t ND = (size_t)N * DD;
    const size_t ED = (size_t)E * DD;

    float* ws    = (float*)d_ws;
    float* A1h   = ws + 0 * ND;
    float* A2h   = ws + 1 * ND;
    float* A3h   = ws + 2 * ND;
    float* B1h   = ws + 3 * ND;
    float* B2h   = ws + 4 * ND;
    float* agg_f = ws + 5 * ND;
    float* agg_b = ws + 6 * ND;
    float* stats = ws + 7 * ND;   // 512 floats (e/h: sum,sq,scale,shift)

    const int nscan   = 2 * N;
    const int nb_scan = (nscan + 1023) / 1024;
    // ints: cur2 (2N) | row2 (2N+1) | partials (nb_scan) | pair2 (2E int2)
    const size_t int_count = (size_t)(4 * N + 1 + nb_scan) + 4 * (size_t)E + 2;
    const size_t need_big  = (7 * ND + 512 + ED) * sizeof(float) + int_count * sizeof(int);
    const bool   ws_big    = ws_size >= need_big;

    float* sig_ws = stats + 512;                        // ED floats (only if ws_big)
    int*   ibase  = (int*)(ws_big ? (sig_ws + ED) : (stats + 512));
    int*  cur2   = ibase;                     // 2N (counts -> cursors)
    int*  row2   = ibase + 2 * N;             // 2N+1
    int*  part   = ibase + 4 * N + 1;         // nb_scan
    int2* pair2  = (int2*)(((uintptr_t)(part + nb_scan) + 7) & ~(uintptr_t)7); // 2E pairs

    float* out  = (float*)d_out;
    float* gbuf = out + ND;   // out e-region: g -> (sigma | e)

    hipMemsetAsync(stats, 0, 512 * sizeof(float), stream);
    hipMemsetAsync(cur2, 0, 2 * (size_t)N * sizeof(int), stream);

    dim3 blk(256);
    int nb_e  = (E + 255) / 256;
    int nt_n  = (N + TILE - 1) / TILE;
    int nt_e  = (E + TILE - 1) / TILE;

    k_tile_linear<<<dim3(nt_n, 5), blk, 0, stream>>>(h, N,
        A1w, A1b, A1h,  A2w, A2b, A2h,  A3w, A3b, A3h,
        B1w, B1b, B1h,  B2w, B2b, B2h);

    // CSR build (fwd+bwd merged), hierarchical scan
    k_count<<<nb_e, blk, 0, stream>>>(src, dst, cur2, N, E);
    k_scan_blk<<<nb_scan, 1024, 0, stream>>>(cur2, row2, part, nscan);
    k_scan_carry<<<1, 1024, 0, stream>>>(part, nb_scan);
    k_scan_add<<<nb_scan, 1024, 0, stream>>>(row2, cur2, part, nscan, 2 * E);
    k_place<<<nb_e, blk, 0, stream>>>(src, dst, cur2, pair2, N, E);

    // fused edge gate + BN-e stats
    k_edge_fused<<<nt_e, blk, 0, stream>>>(e, src, dst, B1h, B2h, B3w, B3b,
                                           gbuf, stats, E);
    k_bn_final<<<1, 64, 0, stream>>>(stats, 1.0f / (float)E, bneg, bneb,
                                     stats + 128, stats + 192);

    long long total4 = (long long)(ED / 4);
    int nb_s = (int)((total4 + 255) / 256);
    float* sigma = ws_big ? sig_ws : gbuf;
    k_edge_sigma<<<nb_s, blk, 0, stream>>>(
        (const float4*)gbuf, (const float4*)e,
        (float4*)sigma, ws_big ? (float4*)gbuf : nullptr,
        stats + 128, stats + 192, total4);

    int nb_g = (int)(((size_t)N * DD + 255) / 256);
    k_gather<<<nb_g, blk, 0, stream>>>(sigma, pair2, row2,     A2h, agg_f, N);
    k_gather<<<nb_g, blk, 0, stream>>>(sigma, pair2, row2 + N, A3h, agg_b, N);

    k_node_pre<<<1024, blk, 0, stream>>>(A1h, agg_f, agg_b,
        out, stats + 256, (long long)ND);
    k_bn_final<<<1, 64, 0, stream>>>(stats + 256, 1.0f / (float)N, bnhg, bnhb,
                                     stats + 384, stats + 448);
    k_node_out<<<1024, blk, 0, stream>>>(h, stats + 384, stats + 448,
                                         out, (long long)ND);

    if (!ws_big) {
        hipMemcpyAsync(gbuf, e, ED * sizeof(float), hipMemcpyDeviceToDevice, stream);
    }
}

// Round 8
// 736.137 us; speedup vs baseline: 2.3161x; 1.2383x over previous
//
#include <hip/hip_runtime.h>
#include <cstdint>
#include <cstddef>

#define DD 64
#define TILE 64
#define LSTR 65   // padded LDS row stride (floats): bank = (row + col) % 32 -> <=2-way (free)
#define NREP 64   // stat-replica count: spreads block atomics over 64*128 floats
constexpr float BN_EPS  = 1e-5f;
constexpr float DEG_EPS = 1e-6f;

__device__ __forceinline__ float fatomic_add(float* p, float v) {
    return unsafeAtomicAdd(p, v);   // hardware global_atomic_add_f32
}

// =============== tiled linear: o = x @ W^T + b, single LDS buffer ============
// grid.x = row-chunks of 64, grid.y = which of 5 matrices
__global__ __launch_bounds__(256) void k_tile_linear(
    const float* __restrict__ x, int R,
    const float* __restrict__ w0, const float* __restrict__ b0, float* __restrict__ o0,
    const float* __restrict__ w1, const float* __restrict__ b1, float* __restrict__ o1,
    const float* __restrict__ w2, const float* __restrict__ b2, float* __restrict__ o2,
    const float* __restrict__ w3, const float* __restrict__ b3, float* __restrict__ o3,
    const float* __restrict__ w4, const float* __restrict__ b4, float* __restrict__ o4)
{
    const float* w; const float* b; float* o;
    switch (blockIdx.y) {
        case 0:  w = w0; b = b0; o = o0; break;
        case 1:  w = w1; b = b1; o = o1; break;
        case 2:  w = w2; b = b2; o = o2; break;
        case 3:  w = w3; b = b3; o = o3; break;
        default: w = w4; b = b4; o = o4; break;
    }
    __shared__ float ldsE[TILE * LSTR];
    int tid  = threadIdx.x;
    int lane = tid & 63;
    int base = blockIdx.x * TILE;
    int rem  = R - base; if (rem > TILE) rem = TILE;
    int qu   = __builtin_amdgcn_readfirstlane(tid >> 6);   // wave id 0..3, SGPR

    // phase 1: stage x rows -> ldsE (coalesced 1KB/wave-instr global reads)
    const float4* x4 = reinterpret_cast<const float4*>(x + (size_t)base * DD);
    #pragma unroll
    for (int j = 0; j < 4; ++j) {
        int f4 = j * 256 + tid;          // float4 index in tile
        int r  = f4 >> 4, c = f4 & 15;
        if (r < rem) {
            float4 v = x4[f4];
            ldsE[r * LSTR + c * 4 + 0] = v.x;
            ldsE[r * LSTR + c * 4 + 1] = v.y;
            ldsE[r * LSTR + c * 4 + 2] = v.z;
            ldsE[r * LSTR + c * 4 + 3] = v.w;
        }
    }
    __syncthreads();

    // phase 2: GEMV, thread = (row=lane, d-quarter=qu); W via uniform s_load
    float acc[16];
    #pragma unroll
    for (int i = 0; i < 16; ++i) acc[i] = b[qu * 16 + i];
    #pragma unroll 4
    for (int k = 0; k < 64; ++k) {
        float ev = ldsE[lane * LSTR + k];
        const float* wq = w + (size_t)(qu * 16) * DD + k;
        #pragma unroll
        for (int i = 0; i < 16; ++i)
            acc[i] = fmaf(ev, wq[(size_t)i * DD], acc[i]);
    }
    __syncthreads();   // all reads of ldsE done -> safe to overwrite
    #pragma unroll
    for (int i = 0; i < 16; ++i)
        ldsE[lane * LSTR + qu * 16 + i] = acc[i];
    __syncthreads();

    // phase 3: linear write-out (coalesced 1KB/wave-instr global stores)
    float4* outp4 = reinterpret_cast<float4*>(o + (size_t)base * DD);
    #pragma unroll
    for (int j = 0; j < 4; ++j) {
        int f4 = j * 256 + tid;
        int r  = f4 >> 4, c = f4 & 15;
        if (r < rem) {
            float4 v;
            v.x = ldsE[r * LSTR + c * 4 + 0];
            v.y = ldsE[r * LSTR + c * 4 + 1];
            v.z = ldsE[r * LSTR + c * 4 + 2];
            v.w = ldsE[r * LSTR + c * 4 + 3];
            outp4[f4] = v;
        }
    }
}

// =============== fused edge gate: g = B3 e + b3 + B1h[src] + B2h[dst] ========
// Block per 64-edge tile, single LDS buffer. Stats go to a per-block replica
// (blockIdx & 63) to avoid the 128-float atomic hotspot.
__global__ __launch_bounds__(256) void k_edge_fused(
    const float* __restrict__ e,
    const int* __restrict__ src, const int* __restrict__ dst,
    const float* __restrict__ B1h, const float* __restrict__ B2h,
    const float* __restrict__ w, const float* __restrict__ b,
    float* __restrict__ g, float* __restrict__ sums, int E)
{
    __shared__ float ldsE[TILE * LSTR];
    __shared__ float red[256];
    int tid  = threadIdx.x;
    int lane = tid & 63;
    int base = blockIdx.x * TILE;
    int rem  = E - base; if (rem > TILE) rem = TILE;
    int qu   = __builtin_amdgcn_readfirstlane(tid >> 6);

    // phase 1: stage e tile
    const float4* e4 = reinterpret_cast<const float4*>(e + (size_t)base * DD);
    #pragma unroll
    for (int j = 0; j < 4; ++j) {
        int f4 = j * 256 + tid;
        int r  = f4 >> 4, c = f4 & 15;
        if (r < rem) {
            float4 v = e4[f4];
            ldsE[r * LSTR + c * 4 + 0] = v.x;
            ldsE[r * LSTR + c * 4 + 1] = v.y;
            ldsE[r * LSTR + c * 4 + 2] = v.z;
            ldsE[r * LSTR + c * 4 + 3] = v.w;
        }
    }
    __syncthreads();

    // phase 2: GEMV B3 * e_row + b3 (acc in regs)
    float acc[16];
    #pragma unroll
    for (int i = 0; i < 16; ++i) acc[i] = b[qu * 16 + i];
    #pragma unroll 4
    for (int k = 0; k < 64; ++k) {
        float ev = ldsE[lane * LSTR + k];
        const float* wq = w + (size_t)(qu * 16) * DD + k;
        #pragma unroll
        for (int i = 0; i < 16; ++i)
            acc[i] = fmaf(ev, wq[(size_t)i * DD], acc[i]);
    }
    __syncthreads();   // reads done -> overwrite ldsE with g0
    #pragma unroll
    for (int i = 0; i < 16; ++i)
        ldsE[lane * LSTR + qu * 16 + i] = acc[i];
    __syncthreads();

    // phase 3: wave-per-edge row adds + stats + coalesced g write (lane = col d)
    float ps = 0.f, pq = 0.f;
    #pragma unroll
    for (int it = 0; it < 16; ++it) {
        int el = qu * 16 + it;               // wave-uniform
        if (el < rem) {
            int ee = base + el;
            int s = src[ee], t = dst[ee];    // scalar loads (uniform address)
            float v = ldsE[el * LSTR + lane]
                    + B1h[(size_t)s * DD + lane]
                    + B2h[(size_t)t * DD + lane];
            g[(size_t)ee * DD + lane] = v;
            ps += v; pq += v * v;
        }
    }
    float* srep = sums + (size_t)(blockIdx.x & (NREP - 1)) * 128;
    red[tid] = ps; __syncthreads();
    if (tid < 64) fatomic_add(&srep[tid],      red[tid] + red[tid+64] + red[tid+128] + red[tid+192]);
    __syncthreads();
    red[tid] = pq; __syncthreads();
    if (tid < 64) fatomic_add(&srep[64 + tid], red[tid] + red[tid+64] + red[tid+128] + red[tid+192]);
}

// ---------------- fold replicated stats into scale/shift ---------------------
// reps: NREP replicas of [sum(64) | sumsq(64)]
__global__ void k_bn_final(const float* __restrict__ reps, float inv_cnt,
                           const float* __restrict__ gamma, const float* __restrict__ beta,
                           float* __restrict__ scale, float* __restrict__ shift)
{
    int d = threadIdx.x;
    if (d >= DD) return;
    float s = 0.f, q = 0.f;
    #pragma unroll 8
    for (int r = 0; r < NREP; ++r) {
        s += reps[r * 128 + d];
        q += reps[r * 128 + 64 + d];
    }
    float mean = s * inv_cnt;
    float var  = fmaxf(q * inv_cnt - mean * mean, 0.f);
    float rs   = rsqrtf(var + BN_EPS);
    float sc   = gamma[d] * rs;
    scale[d] = sc;
    shift[d] = beta[d] - mean * sc;
}

// ---------------- CSR build ---------------------------------------------------
__global__ __launch_bounds__(256) void k_count(
    const int* __restrict__ src, const int* __restrict__ dst,
    int* __restrict__ cnt2, int N, int E)
{
    int ee = blockIdx.x * 256 + threadIdx.x;
    if (ee >= E) return;
    atomicAdd(&cnt2[dst[ee]], 1);        // fwd counts at [0,N)
    atomicAdd(&cnt2[N + src[ee]], 1);    // bwd counts at [N,2N)
}

// hierarchical exclusive scan: block-local -> carry -> add
__global__ __launch_bounds__(1024) void k_scan_blk(
    const int* __restrict__ cnt, int* __restrict__ row, int* __restrict__ part, int n)
{
    __shared__ int tmp[1024];
    int tid = threadIdx.x;
    int i   = blockIdx.x * 1024 + tid;
    int v   = (i < n) ? cnt[i] : 0;
    tmp[tid] = v; __syncthreads();
    for (int off = 1; off < 1024; off <<= 1) {
        int t = (tid >= off) ? tmp[tid - off] : 0;
        __syncthreads();
        tmp[tid] += t;
        __syncthreads();
    }
    if (i < n) row[i] = tmp[tid] - v;            // local exclusive
    if (tid == 1023) part[blockIdx.x] = tmp[1023];  // block total
}

__global__ __launch_bounds__(1024) void k_scan_carry(int* part, int nb)
{
    __shared__ int tmp[1024];
    int tid = threadIdx.x;
    int carry = 0;
    for (int base = 0; base < nb; base += 1024) {
        int i = base + tid;
        int v = (i < nb) ? part[i] : 0;
        tmp[tid] = v; __syncthreads();
        for (int off = 1; off < 1024; off <<= 1) {
            int t = (tid >= off) ? tmp[tid - off] : 0;
            __syncthreads();
            tmp[tid] += t;
            __syncthreads();
        }
        if (i < nb) part[i] = carry + tmp[tid] - v;
        carry += tmp[1023];
        __syncthreads();
    }
}

__global__ __launch_bounds__(1024) void k_scan_add(
    int* __restrict__ row, int* __restrict__ cur, const int* __restrict__ part,
    int n, int total)
{
    int i = blockIdx.x * 1024 + threadIdx.x;
    if (i < n) {
        int r = row[i] + part[blockIdx.x];
        row[i] = r; cur[i] = r;
    }
    if (i == 0) row[n] = total;
}

// place packed (eid, other-node) pairs -> kills one dependent load in gather
__global__ __launch_bounds__(256) void k_place(
    const int* __restrict__ src, const int* __restrict__ dst,
    int* __restrict__ cur2, int2* __restrict__ pair2, int N, int E)
{
    int ee = blockIdx.x * 256 + threadIdx.x;
    if (ee >= E) return;
    int s = src[ee], t = dst[ee];
    int pf = atomicAdd(&cur2[t], 1);
    pair2[pf] = make_int2(ee, s);
    int pb = atomicAdd(&cur2[N + s], 1);
    pair2[pb] = make_int2(ee, t);        // bwd slots live at [E, 2E)
}

// ---------------- sigma = sigmoid(relu(bn(g)) + e), float4-vectorized --------
__global__ __launch_bounds__(256) void k_edge_sigma(
    const float4* g, const float4* __restrict__ e,
    float4* sig, float4* ecopy,
    const float* __restrict__ scale, const float* __restrict__ shift,
    long long total4)
{
    long long idx = (long long)blockIdx.x * 256 + threadIdx.x;
    if (idx >= total4) return;
    int q = (int)(idx & 15);
    float4 sc = reinterpret_cast<const float4*>(scale)[q];
    float4 sh = reinterpret_cast<const float4*>(shift)[q];
    float4 gv = g[idx];
    float4 ev = e[idx];
    float4 o;
    o.x = 1.f / (1.f + __expf(-(fmaxf(gv.x * sc.x + sh.x, 0.f) + ev.x)));
    o.y = 1.f / (1.f + __expf(-(fmaxf(gv.y * sc.y + sh.y, 0.f) + ev.y)));
    o.z = 1.f / (1.f + __expf(-(fmaxf(gv.z * sc.z + sh.z, 0.f) + ev.z)));
    o.w = 1.f / (1.f + __expf(-(fmaxf(gv.w * sc.w + sh.w, 0.f) + ev.w)));
    sig[idx] = o;
    if (ecopy) ecopy[idx] = ev;
}

// ---------------- gather: wave per node, 4 edge slots x float4 cols ----------
__global__ __launch_bounds__(256) void k_gather(
    const float* __restrict__ sigma, const int2* __restrict__ pair2,
    const int* __restrict__ row,
    const float* __restrict__ Ah, float* __restrict__ agg, int N)
{
    int wid  = (blockIdx.x * 256 + threadIdx.x) >> 6;
    int lane = threadIdx.x & 63;
    if (wid >= N) return;
    int q  = lane >> 4;      // edge slot 0..3
    int dj = lane & 15;      // float4 column slot
    int beg = row[wid], end = row[wid + 1];
    float4 num = {0.f, 0.f, 0.f, 0.f};
    float4 den = {0.f, 0.f, 0.f, 0.f};
    const float4* sig4 = reinterpret_cast<const float4*>(sigma);
    const float4* Ah4  = reinterpret_cast<const float4*>(Ah);
    for (int k = beg + q; k < end; k += 4) {
        int2 p = pair2[k];                        // {eid, other}
        float4 s4 = sig4[(size_t)p.x * 16 + dj];
        float4 a4 = Ah4[(size_t)p.y * 16 + dj];
        num.x += s4.x * a4.x; num.y += s4.y * a4.y;
        num.z += s4.z * a4.z; num.w += s4.w * a4.w;
        den.x += s4.x; den.y += s4.y; den.z += s4.z; den.w += s4.w;
    }
    // reduce across the 4 edge slots (lanes xor 16, 32)
    #pragma unroll
    for (int off = 16; off <= 32; off <<= 1) {
        num.x += __shfl_xor(num.x, off); num.y += __shfl_xor(num.y, off);
        num.z += __shfl_xor(num.z, off); num.w += __shfl_xor(num.w, off);
        den.x += __shfl_xor(den.x, off); den.y += __shfl_xor(den.y, off);
        den.z += __shfl_xor(den.z, off); den.w += __shfl_xor(den.w, off);
    }
    if (q == 0) {
        float4 res;
        res.x = num.x / (den.x + DEG_EPS);
        res.y = num.y / (den.y + DEG_EPS);
        res.z = num.z / (den.z + DEG_EPS);
        res.w = num.w / (den.w + DEG_EPS);
        reinterpret_cast<float4*>(agg)[(size_t)wid * 16 + dj] = res;
    }
}

// ---------------- h_pre = A1h + agg_f + agg_b, + replicated column stats -----
__global__ __launch_bounds__(256) void k_node_pre(
    const float* __restrict__ A1h,
    const float* __restrict__ agg_f, const float* __restrict__ agg_b,
    float* __restrict__ hpre, float* __restrict__ sums, long long total)
{
    int tid = threadIdx.x;
    long long idx = (long long)blockIdx.x * 256 + tid;
    long long stride = (long long)gridDim.x * 256;
    float ps = 0.f, pq = 0.f;
    for (; idx < total; idx += stride) {
        float v = A1h[idx] + agg_f[idx] + agg_b[idx];
        hpre[idx] = v;
        ps += v; pq += v * v;
    }
    float* srep = sums + (size_t)(blockIdx.x & (NREP - 1)) * 128;
    __shared__ float red[256];
    red[tid] = ps; __syncthreads();
    if (tid < 64) fatomic_add(&srep[tid],      red[tid] + red[tid+64] + red[tid+128] + red[tid+192]);
    __syncthreads();
    red[tid] = pq; __syncthreads();
    if (tid < 64) fatomic_add(&srep[64 + tid], red[tid] + red[tid+64] + red[tid+128] + red[tid+192]);
}

// ---------------- finish h: BN affine + relu + residual (in place) -----------
__global__ __launch_bounds__(256) void k_node_out(
    const float* __restrict__ h,
    const float* __restrict__ scale, const float* __restrict__ shift,
    float* __restrict__ out, long long total)
{
    long long idx = (long long)blockIdx.x * 256 + threadIdx.x;
    long long stride = (long long)gridDim.x * 256;
    for (; idx < total; idx += stride) {
        int d = (int)(idx & (DD - 1));
        float v = out[idx] * scale[d] + shift[d];
        out[idx] = fmaxf(v, 0.f) + h[idx];
    }
}

extern "C" void kernel_launch(void* const* d_in, const int* in_sizes, int n_in,
                              void* d_out, int out_size, void* d_ws, size_t ws_size,
                              hipStream_t stream)
{
    const float* h    = (const float*)d_in[0];
    const float* e    = (const float*)d_in[1];
    const int*   src  = (const int*)d_in[2];
    const int*   dst  = (const int*)d_in[3];
    const float* A1w  = (const float*)d_in[4];
    const float* A1b  = (const float*)d_in[5];
    const float* A2w  = (const float*)d_in[6];
    const float* A2b  = (const float*)d_in[7];
    const float* A3w  = (const float*)d_in[8];
    const float* A3b  = (const float*)d_in[9];
    const float* B1w  = (const float*)d_in[10];
    const float* B1b  = (const float*)d_in[11];
    const float* B2w  = (const float*)d_in[12];
    const float* B2b  = (const float*)d_in[13];
    const float* B3w  = (const float*)d_in[14];
    const float* B3b  = (const float*)d_in[15];
    const float* bnhg = (const float*)d_in[16];
    const float* bnhb = (const float*)d_in[17];
    const float* bneg = (const float*)d_in[18];
    const float* bneb = (const float*)d_in[19];

    const int N = in_sizes[0] / DD;
    const int E = in_sizes[1] / DD;
    const size_t ND = (size_t)N * DD;
    const size_t ED = (size_t)E * DD;

    float* ws    = (float*)d_ws;
    float* A1h   = ws + 0 * ND;
    float* A2h   = ws + 1 * ND;
    float* A3h   = ws + 2 * ND;
    float* B1h   = ws + 3 * ND;
    float* B2h   = ws + 4 * ND;
    float* agg_f = ws + 5 * ND;
    float* agg_b = ws + 6 * ND;
    float* stats = ws + 7 * ND;
    // stats layout (floats):
    //   [0 .. 8192)      e-stat replicas: NREP x (sum64 | sumsq64)
    //   [8192 .. 16384)  h-stat replicas
    //   [16384..16448) e_scale  [16448..16512) e_shift
    //   [16512..16576) h_scale  [16576..16640) h_shift
    const size_t STATS_F = 16640;
    float* e_rep   = stats;
    float* h_rep   = stats + 8192;
    float* e_scale = stats + 16384;
    float* e_shift = stats + 16448;
    float* h_scale = stats + 16512;
    float* h_shift = stats + 16576;

    const int nscan   = 2 * N;
    const int nb_scan = (nscan + 1023) / 1024;
    // ints: cur2 (2N) | row2 (2N+1) | partials (nb_scan) | pair2 (2E int2)
    const size_t int_count = (size_t)(4 * N + 1 + nb_scan) + 4 * (size_t)E + 2;
    const size_t need_big  = (7 * ND + STATS_F + ED) * sizeof(float) + int_count * sizeof(int);
    const bool   ws_big    = ws_size >= need_big;

    float* sig_ws = stats + STATS_F;                    // ED floats (only if ws_big)
    int*   ibase  = (int*)(ws_big ? (sig_ws + ED) : (stats + STATS_F));
    int*  cur2   = ibase;                     // 2N (counts -> cursors)
    int*  row2   = ibase + 2 * N;             // 2N+1
    int*  part   = ibase + 4 * N + 1;         // nb_scan
    int2* pair2  = (int2*)(((uintptr_t)(part + nb_scan) + 7) & ~(uintptr_t)7); // 2E pairs

    float* out  = (float*)d_out;
    float* gbuf = out + ND;   // out e-region: g -> (sigma | e)

    hipMemsetAsync(stats, 0, STATS_F * sizeof(float), stream);
    hipMemsetAsync(cur2, 0, 2 * (size_t)N * sizeof(int), stream);

    dim3 blk(256);
    int nb_e  = (E + 255) / 256;
    int nt_n  = (N + TILE - 1) / TILE;
    int nt_e  = (E + TILE - 1) / TILE;

    k_tile_linear<<<dim3(nt_n, 5), blk, 0, stream>>>(h, N,
        A1w, A1b, A1h,  A2w, A2b, A2h,  A3w, A3b, A3h,
        B1w, B1b, B1h,  B2w, B2b, B2h);

    // CSR build (fwd+bwd merged), hierarchical scan
    k_count<<<nb_e, blk, 0, stream>>>(src, dst, cur2, N, E);
    k_scan_blk<<<nb_scan, 1024, 0, stream>>>(cur2, row2, part, nscan);
    k_scan_carry<<<1, 1024, 0, stream>>>(part, nb_scan);
    k_scan_add<<<nb_scan, 1024, 0, stream>>>(row2, cur2, part, nscan, 2 * E);
    k_place<<<nb_e, blk, 0, stream>>>(src, dst, cur2, pair2, N, E);

    // fused edge gate + BN-e stats (replicated)
    k_edge_fused<<<nt_e, blk, 0, stream>>>(e, src, dst, B1h, B2h, B3w, B3b,
                                           gbuf, e_rep, E);
    k_bn_final<<<1, 64, 0, stream>>>(e_rep, 1.0f / (float)E, bneg, bneb,
                                     e_scale, e_shift);

    long long total4 = (long long)(ED / 4);
    int nb_s = (int)((total4 + 255) / 256);
    float* sigma = ws_big ? sig_ws : gbuf;
    k_edge_sigma<<<nb_s, blk, 0, stream>>>(
        (const float4*)gbuf, (const float4*)e,
        (float4*)sigma, ws_big ? (float4*)gbuf : nullptr,
        e_scale, e_shift, total4);

    int nb_g = (int)(((size_t)N * DD + 255) / 256);
    k_gather<<<nb_g, blk, 0, stream>>>(sigma, pair2, row2,     A2h, agg_f, N);
    k_gather<<<nb_g, blk, 0, stream>>>(sigma, pair2, row2 + N, A3h, agg_b, N);

    k_node_pre<<<1024, blk, 0, stream>>>(A1h, agg_f, agg_b,
        out, h_rep, (long long)ND);
    k_bn_final<<<1, 64, 0, stream>>>(h_rep, 1.0f / (float)N, bnhg, bnhb,
                                     h_scale, h_shift);
    k_node_out<<<1024, blk, 0, stream>>>(h, h_scale, h_shift,
                                         out, (long long)ND);

    if (!ws_big) {
        hipMemcpyAsync(gbuf, e, ED * sizeof(float), hipMemcpyDeviceToDevice, stream);
    }
}

// Round 9
// 704.770 us; speedup vs baseline: 2.4192x; 1.0445x over previous
//
#include <hip/hip_runtime.h>
#include <cstdint>
#include <cstddef>

#define DD 64
#define TILE 64
#define LSTR 65   // padded LDS row stride (floats): bank = (row + col) % 32 -> <=2-way (free)
#define NREP 64   // stat-replica count: spreads block atomics over 64*128 floats
constexpr float BN_EPS  = 1e-5f;
constexpr float DEG_EPS = 1e-6f;

__device__ __forceinline__ float fatomic_add(float* p, float v) {
    return unsafeAtomicAdd(p, v);   // hardware global_atomic_add_f32
}

// =============== tiled linear: o = x @ W^T + b, single LDS buffer ============
// grid.x = row-chunks of 64, grid.y = which of 5 matrices
__global__ __launch_bounds__(256) void k_tile_linear(
    const float* __restrict__ x, int R,
    const float* __restrict__ w0, const float* __restrict__ b0, float* __restrict__ o0,
    const float* __restrict__ w1, const float* __restrict__ b1, float* __restrict__ o1,
    const float* __restrict__ w2, const float* __restrict__ b2, float* __restrict__ o2,
    const float* __restrict__ w3, const float* __restrict__ b3, float* __restrict__ o3,
    const float* __restrict__ w4, const float* __restrict__ b4, float* __restrict__ o4)
{
    const float* w; const float* b; float* o;
    switch (blockIdx.y) {
        case 0:  w = w0; b = b0; o = o0; break;
        case 1:  w = w1; b = b1; o = o1; break;
        case 2:  w = w2; b = b2; o = o2; break;
        case 3:  w = w3; b = b3; o = o3; break;
        default: w = w4; b = b4; o = o4; break;
    }
    __shared__ float ldsE[TILE * LSTR];
    int tid  = threadIdx.x;
    int lane = tid & 63;
    int base = blockIdx.x * TILE;
    int rem  = R - base; if (rem > TILE) rem = TILE;
    int qu   = __builtin_amdgcn_readfirstlane(tid >> 6);   // wave id 0..3, SGPR

    // phase 1: stage x rows -> ldsE (coalesced 1KB/wave-instr global reads)
    const float4* x4 = reinterpret_cast<const float4*>(x + (size_t)base * DD);
    #pragma unroll
    for (int j = 0; j < 4; ++j) {
        int f4 = j * 256 + tid;          // float4 index in tile
        int r  = f4 >> 4, c = f4 & 15;
        if (r < rem) {
            float4 v = x4[f4];
            ldsE[r * LSTR + c * 4 + 0] = v.x;
            ldsE[r * LSTR + c * 4 + 1] = v.y;
            ldsE[r * LSTR + c * 4 + 2] = v.z;
            ldsE[r * LSTR + c * 4 + 3] = v.w;
        }
    }
    __syncthreads();

    // phase 2: GEMV, thread = (row=lane, d-quarter=qu); W via uniform s_load
    float acc[16];
    #pragma unroll
    for (int i = 0; i < 16; ++i) acc[i] = b[qu * 16 + i];
    #pragma unroll 4
    for (int k = 0; k < 64; ++k) {
        float ev = ldsE[lane * LSTR + k];
        const float* wq = w + (size_t)(qu * 16) * DD + k;
        #pragma unroll
        for (int i = 0; i < 16; ++i)
            acc[i] = fmaf(ev, wq[(size_t)i * DD], acc[i]);
    }
    __syncthreads();   // all reads of ldsE done -> safe to overwrite
    #pragma unroll
    for (int i = 0; i < 16; ++i)
        ldsE[lane * LSTR + qu * 16 + i] = acc[i];
    __syncthreads();

    // phase 3: linear write-out (coalesced 1KB/wave-instr global stores)
    float4* outp4 = reinterpret_cast<float4*>(o + (size_t)base * DD);
    #pragma unroll
    for (int j = 0; j < 4; ++j) {
        int f4 = j * 256 + tid;
        int r  = f4 >> 4, c = f4 & 15;
        if (r < rem) {
            float4 v;
            v.x = ldsE[r * LSTR + c * 4 + 0];
            v.y = ldsE[r * LSTR + c * 4 + 1];
            v.z = ldsE[r * LSTR + c * 4 + 2];
            v.w = ldsE[r * LSTR + c * 4 + 3];
            outp4[f4] = v;
        }
    }
}

// =============== fused edge gate: g = B3 e + b3 + B1h[src] + B2h[dst] ========
// Block per 64-edge tile. B-row loads are issued at kernel start (addresses
// depend only on src/dst) so their L3 latency hides under stage+GEMV.
__global__ __launch_bounds__(256) void k_edge_fused(
    const float* __restrict__ e,
    const int* __restrict__ src, const int* __restrict__ dst,
    const float* __restrict__ B1h, const float* __restrict__ B2h,
    const float* __restrict__ w, const float* __restrict__ b,
    float* __restrict__ g, float* __restrict__ sums, int E)
{
    __shared__ float ldsE[TILE * LSTR];
    __shared__ float red[256];
    int tid  = threadIdx.x;
    int lane = tid & 63;
    int base = blockIdx.x * TILE;
    int rem  = E - base; if (rem > TILE) rem = TILE;
    int qu   = __builtin_amdgcn_readfirstlane(tid >> 6);

    // phase 0a: read e tile into regs (issue first -> ds_write waits only on these)
    const float4* e4 = reinterpret_cast<const float4*>(e + (size_t)base * DD);
    float4 ev[4];
    #pragma unroll
    for (int j = 0; j < 4; ++j) {
        int f4 = j * 256 + tid;
        int r  = f4 >> 4;
        ev[j] = (r < rem) ? e4[f4] : float4{0.f, 0.f, 0.f, 0.f};
    }

    // phase 0b: issue this wave's 32 B-row loads (latency hides under GEMV)
    float b1r[16], b2r[16];
    #pragma unroll
    for (int it = 0; it < 16; ++it) {
        int el = qu * 16 + it;               // wave-uniform
        if (el < rem) {
            int ee = base + el;
            int s = src[ee], t = dst[ee];    // scalar loads (uniform address)
            b1r[it] = B1h[(size_t)s * DD + lane];
            b2r[it] = B2h[(size_t)t * DD + lane];
        } else { b1r[it] = 0.f; b2r[it] = 0.f; }
    }

    // phase 1: stage e tile to LDS
    #pragma unroll
    for (int j = 0; j < 4; ++j) {
        int f4 = j * 256 + tid;
        int r  = f4 >> 4, c = f4 & 15;
        if (r < rem) {
            ldsE[r * LSTR + c * 4 + 0] = ev[j].x;
            ldsE[r * LSTR + c * 4 + 1] = ev[j].y;
            ldsE[r * LSTR + c * 4 + 2] = ev[j].z;
            ldsE[r * LSTR + c * 4 + 3] = ev[j].w;
        }
    }
    __syncthreads();

    // phase 2: GEMV B3 * e_row + b3 (acc in regs)
    float acc[16];
    #pragma unroll
    for (int i = 0; i < 16; ++i) acc[i] = b[qu * 16 + i];
    #pragma unroll 4
    for (int k = 0; k < 64; ++k) {
        float evk = ldsE[lane * LSTR + k];
        const float* wq = w + (size_t)(qu * 16) * DD + k;
        #pragma unroll
        for (int i = 0; i < 16; ++i)
            acc[i] = fmaf(evk, wq[(size_t)i * DD], acc[i]);
    }
    __syncthreads();   // reads done -> overwrite ldsE with g0
    #pragma unroll
    for (int i = 0; i < 16; ++i)
        ldsE[lane * LSTR + qu * 16 + i] = acc[i];
    __syncthreads();

    // phase 3: add prefetched rows + stats + coalesced g write (lane = col d)
    float ps = 0.f, pq = 0.f;
    #pragma unroll
    for (int it = 0; it < 16; ++it) {
        int el = qu * 16 + it;
        if (el < rem) {
            int ee = base + el;
            float v = ldsE[el * LSTR + lane] + b1r[it] + b2r[it];
            g[(size_t)ee * DD + lane] = v;
            ps += v; pq += v * v;
        }
    }
    float* srep = sums + (size_t)(blockIdx.x & (NREP - 1)) * 128;
    red[tid] = ps; __syncthreads();
    if (tid < 64) fatomic_add(&srep[tid],      red[tid] + red[tid+64] + red[tid+128] + red[tid+192]);
    __syncthreads();
    red[tid] = pq; __syncthreads();
    if (tid < 64) fatomic_add(&srep[64 + tid], red[tid] + red[tid+64] + red[tid+128] + red[tid+192]);
}

// ---------------- fold replicated stats into scale/shift ---------------------
__global__ void k_bn_final(const float* __restrict__ reps, float inv_cnt,
                           const float* __restrict__ gamma, const float* __restrict__ beta,
                           float* __restrict__ scale, float* __restrict__ shift)
{
    int d = threadIdx.x;
    if (d >= DD) return;
    float s = 0.f, q = 0.f;
    #pragma unroll 8
    for (int r = 0; r < NREP; ++r) {
        s += reps[r * 128 + d];
        q += reps[r * 128 + 64 + d];
    }
    float mean = s * inv_cnt;
    float var  = fmaxf(q * inv_cnt - mean * mean, 0.f);
    float rs   = rsqrtf(var + BN_EPS);
    float sc   = gamma[d] * rs;
    scale[d] = sc;
    shift[d] = beta[d] - mean * sc;
}

// ---------------- CSR build ---------------------------------------------------
__global__ __launch_bounds__(256) void k_count(
    const int* __restrict__ src, const int* __restrict__ dst,
    int* __restrict__ cnt2, int N, int E)
{
    int ee = blockIdx.x * 256 + threadIdx.x;
    if (ee >= E) return;
    atomicAdd(&cnt2[dst[ee]], 1);        // fwd counts at [0,N)
    atomicAdd(&cnt2[N + src[ee]], 1);    // bwd counts at [N,2N)
}

// hierarchical exclusive scan: block-local -> carry -> add
__global__ __launch_bounds__(1024) void k_scan_blk(
    const int* __restrict__ cnt, int* __restrict__ row, int* __restrict__ part, int n)
{
    __shared__ int tmp[1024];
    int tid = threadIdx.x;
    int i   = blockIdx.x * 1024 + tid;
    int v   = (i < n) ? cnt[i] : 0;
    tmp[tid] = v; __syncthreads();
    for (int off = 1; off < 1024; off <<= 1) {
        int t = (tid >= off) ? tmp[tid - off] : 0;
        __syncthreads();
        tmp[tid] += t;
        __syncthreads();
    }
    if (i < n) row[i] = tmp[tid] - v;            // local exclusive
    if (tid == 1023) part[blockIdx.x] = tmp[1023];  // block total
}

__global__ __launch_bounds__(1024) void k_scan_carry(int* part, int nb)
{
    __shared__ int tmp[1024];
    int tid = threadIdx.x;
    int carry = 0;
    for (int base = 0; base < nb; base += 1024) {
        int i = base + tid;
        int v = (i < nb) ? part[i] : 0;
        tmp[tid] = v; __syncthreads();
        for (int off = 1; off < 1024; off <<= 1) {
            int t = (tid >= off) ? tmp[tid - off] : 0;
            __syncthreads();
            tmp[tid] += t;
            __syncthreads();
        }
        if (i < nb) part[i] = carry + tmp[tid] - v;
        carry += tmp[1023];
        __syncthreads();
    }
}

__global__ __launch_bounds__(1024) void k_scan_add(
    int* __restrict__ row, int* __restrict__ cur, const int* __restrict__ part,
    int n, int total)
{
    int i = blockIdx.x * 1024 + threadIdx.x;
    if (i < n) {
        int r = row[i] + part[blockIdx.x];
        row[i] = r; cur[i] = r;
    }
    if (i == 0) row[n] = total;
}

// place packed (eid, other-node) pairs
__global__ __launch_bounds__(256) void k_place(
    const int* __restrict__ src, const int* __restrict__ dst,
    int* __restrict__ cur2, int2* __restrict__ pair2, int N, int E)
{
    int ee = blockIdx.x * 256 + threadIdx.x;
    if (ee >= E) return;
    int s = src[ee], t = dst[ee];
    int pf = atomicAdd(&cur2[t], 1);
    pair2[pf] = make_int2(ee, s);
    int pb = atomicAdd(&cur2[N + s], 1);
    pair2[pb] = make_int2(ee, t);        // bwd slots live at [E, 2E)
}

// ---------------- sigma = sigmoid(relu(bn(g)) + e), float4-vectorized --------
__global__ __launch_bounds__(256) void k_edge_sigma(
    const float4* g, const float4* __restrict__ e,
    float4* sig, float4* ecopy,
    const float* __restrict__ scale, const float* __restrict__ shift,
    long long total4)
{
    long long idx = (long long)blockIdx.x * 256 + threadIdx.x;
    if (idx >= total4) return;
    int q = (int)(idx & 15);
    float4 sc = reinterpret_cast<const float4*>(scale)[q];
    float4 sh = reinterpret_cast<const float4*>(shift)[q];
    float4 gv = g[idx];
    float4 evv = e[idx];
    float4 o;
    o.x = 1.f / (1.f + __expf(-(fmaxf(gv.x * sc.x + sh.x, 0.f) + evv.x)));
    o.y = 1.f / (1.f + __expf(-(fmaxf(gv.y * sc.y + sh.y, 0.f) + evv.y)));
    o.z = 1.f / (1.f + __expf(-(fmaxf(gv.z * sc.z + sh.z, 0.f) + evv.z)));
    o.w = 1.f / (1.f + __expf(-(fmaxf(gv.w * sc.w + sh.w, 0.f) + evv.w)));
    sig[idx] = o;
    if (ecopy) ecopy[idx] = evv;
}

// ---------------- merged gather: 2N waves (fwd then bwd), 8 edge slots -------
__global__ __launch_bounds__(256) void k_gather2(
    const float* __restrict__ sigma, const int2* __restrict__ pair2,
    const int* __restrict__ row2,
    const float* __restrict__ A2h, const float* __restrict__ A3h,
    float* __restrict__ agg_f, float* __restrict__ agg_b, int N)
{
    int gw = (blockIdx.x * 256 + threadIdx.x) >> 6;
    if (gw >= 2 * N) return;
    int lane = threadIdx.x & 63;
    bool bwd = gw >= N;
    int wid  = bwd ? gw - N : gw;
    const float4* Ah4 = reinterpret_cast<const float4*>(bwd ? A3h : A2h);
    float* agg        = bwd ? agg_b : agg_f;
    int beg = row2[gw], end = row2[gw + 1];   // fwd rows [0,N), bwd rows [N,2N)
    int q  = lane >> 4;      // edge slot 0..3
    int dj = lane & 15;      // float4 column slot
    float4 num = {0.f, 0.f, 0.f, 0.f};
    float4 den = {0.f, 0.f, 0.f, 0.f};
    const float4* sig4 = reinterpret_cast<const float4*>(sigma);
    for (int k = beg + q; k < end; k += 8) {
        int  k2   = k + 4;
        bool hasb = k2 < end;
        int2 pa = pair2[k];
        int2 pb = hasb ? pair2[k2] : pa;
        float4 sa = sig4[(size_t)pa.x * 16 + dj];
        float4 aa = Ah4[(size_t)pa.y * 16 + dj];
        float4 sb = sig4[(size_t)pb.x * 16 + dj];
        float4 ab = Ah4[(size_t)pb.y * 16 + dj];
        num.x += sa.x * aa.x; num.y += sa.y * aa.y;
        num.z += sa.z * aa.z; num.w += sa.w * aa.w;
        den.x += sa.x; den.y += sa.y; den.z += sa.z; den.w += sa.w;
        if (hasb) {
            num.x += sb.x * ab.x; num.y += sb.y * ab.y;
            num.z += sb.z * ab.z; num.w += sb.w * ab.w;
            den.x += sb.x; den.y += sb.y; den.z += sb.z; den.w += sb.w;
        }
    }
    #pragma unroll
    for (int off = 16; off <= 32; off <<= 1) {
        num.x += __shfl_xor(num.x, off); num.y += __shfl_xor(num.y, off);
        num.z += __shfl_xor(num.z, off); num.w += __shfl_xor(num.w, off);
        den.x += __shfl_xor(den.x, off); den.y += __shfl_xor(den.y, off);
        den.z += __shfl_xor(den.z, off); den.w += __shfl_xor(den.w, off);
    }
    if (q == 0) {
        float4 res;
        res.x = num.x / (den.x + DEG_EPS);
        res.y = num.y / (den.y + DEG_EPS);
        res.z = num.z / (den.z + DEG_EPS);
        res.w = num.w / (den.w + DEG_EPS);
        reinterpret_cast<float4*>(agg)[(size_t)wid * 16 + dj] = res;
    }
}

// ---------------- h_pre = A1h + agg_f + agg_b, + replicated column stats -----
__global__ __launch_bounds__(256) void k_node_pre(
    const float* __restrict__ A1h,
    const float* __restrict__ agg_f, const float* __restrict__ agg_b,
    float* __restrict__ hpre, float* __restrict__ sums, long long total)
{
    int tid = threadIdx.x;
    long long idx = (long long)blockIdx.x * 256 + tid;
    long long stride = (long long)gridDim.x * 256;
    float ps = 0.f, pq = 0.f;
    for (; idx < total; idx += stride) {
        float v = A1h[idx] + agg_f[idx] + agg_b[idx];
        hpre[idx] = v;
        ps += v; pq += v * v;
    }
    float* srep = sums + (size_t)(blockIdx.x & (NREP - 1)) * 128;
    __shared__ float red[256];
    red[tid] = ps; __syncthreads();
    if (tid < 64) fatomic_add(&srep[tid],      red[tid] + red[tid+64] + red[tid+128] + red[tid+192]);
    __syncthreads();
    red[tid] = pq; __syncthreads();
    if (tid < 64) fatomic_add(&srep[64 + tid], red[tid] + red[tid+64] + red[tid+128] + red[tid+192]);
}

// ---------------- finish h: BN affine + relu + residual (in place) -----------
__global__ __launch_bounds__(256) void k_node_out(
    const float* __restrict__ h,
    const float* __restrict__ scale, const float* __restrict__ shift,
    float* __restrict__ out, long long total)
{
    long long idx = (long long)blockIdx.x * 256 + threadIdx.x;
    long long stride = (long long)gridDim.x * 256;
    for (; idx < total; idx += stride) {
        int d = (int)(idx & (DD - 1));
        float v = out[idx] * scale[d] + shift[d];
        out[idx] = fmaxf(v, 0.f) + h[idx];
    }
}

extern "C" void kernel_launch(void* const* d_in, const int* in_sizes, int n_in,
                              void* d_out, int out_size, void* d_ws, size_t ws_size,
                              hipStream_t stream)
{
    const float* h    = (const float*)d_in[0];
    const float* e    = (const float*)d_in[1];
    const int*   src  = (const int*)d_in[2];
    const int*   dst  = (const int*)d_in[3];
    const float* A1w  = (const float*)d_in[4];
    const float* A1b  = (const float*)d_in[5];
    const float* A2w  = (const float*)d_in[6];
    const float* A2b  = (const float*)d_in[7];
    const float* A3w  = (const float*)d_in[8];
    const float* A3b  = (const float*)d_in[9];
    const float* B1w  = (const float*)d_in[10];
    const float* B1b  = (const float*)d_in[11];
    const float* B2w  = (const float*)d_in[12];
    const float* B2b  = (const float*)d_in[13];
    const float* B3w  = (const float*)d_in[14];
    const float* B3b  = (const float*)d_in[15];
    const float* bnhg = (const float*)d_in[16];
    const float* bnhb = (const float*)d_in[17];
    const float* bneg = (const float*)d_in[18];
    const float* bneb = (const float*)d_in[19];

    const int N = in_sizes[0] / DD;
    const int E = in_sizes[1] / DD;
    const size_t ND = (size_t)N * DD;
    const size_t ED = (size_t)E * DD;

    float* ws    = (float*)d_ws;
    float* A1h   = ws + 0 * ND;
    float* A2h   = ws + 1 * ND;
    float* A3h   = ws + 2 * ND;
    float* B1h   = ws + 3 * ND;
    float* B2h   = ws + 4 * ND;
    float* agg_f = ws + 5 * ND;
    float* agg_b = ws + 6 * ND;
    float* stats = ws + 7 * ND;
    // stats layout (floats):
    //   [0 .. 8192)      e-stat replicas: NREP x (sum64 | sumsq64)
    //   [8192 .. 16384)  h-stat replicas
    //   [16384..16448) e_scale  [16448..16512) e_shift
    //   [16512..16576) h_scale  [16576..16640) h_shift
    const size_t STATS_F = 16640;
    float* e_rep   = stats;
    float* h_rep   = stats + 8192;
    float* e_scale = stats + 16384;
    float* e_shift = stats + 16448;
    float* h_scale = stats + 16512;
    float* h_shift = stats + 16576;

    const int nscan   = 2 * N;
    const int nb_scan = (nscan + 1023) / 1024;
    const size_t int_count = (size_t)(4 * N + 1 + nb_scan) + 4 * (size_t)E + 2;
    const size_t need_big  = (7 * ND + STATS_F + ED) * sizeof(float) + int_count * sizeof(int);
    const bool   ws_big    = ws_size >= need_big;

    float* sig_ws = stats + STATS_F;                    // ED floats (only if ws_big)
    int*   ibase  = (int*)(ws_big ? (sig_ws + ED) : (stats + STATS_F));
    int*  cur2   = ibase;                     // 2N (counts -> cursors)
    int*  row2   = ibase + 2 * N;             // 2N+1
    int*  part   = ibase + 4 * N + 1;         // nb_scan
    int2* pair2  = (int2*)(((uintptr_t)(part + nb_scan) + 7) & ~(uintptr_t)7); // 2E pairs

    float* out  = (float*)d_out;
    float* gbuf = out + ND;   // out e-region: g -> (sigma | e)

    hipMemsetAsync(stats, 0, STATS_F * sizeof(float), stream);
    hipMemsetAsync(cur2, 0, 2 * (size_t)N * sizeof(int), stream);

    dim3 blk(256);
    int nb_e  = (E + 255) / 256;
    int nt_n  = (N + TILE - 1) / TILE;
    int nt_e  = (E + TILE - 1) / TILE;

    k_tile_linear<<<dim3(nt_n, 5), blk, 0, stream>>>(h, N,
        A1w, A1b, A1h,  A2w, A2b, A2h,  A3w, A3b, A3h,
        B1w, B1b, B1h,  B2w, B2b, B2h);

    // CSR build (fwd+bwd merged), hierarchical scan
    k_count<<<nb_e, blk, 0, stream>>>(src, dst, cur2, N, E);
    k_scan_blk<<<nb_scan, 1024, 0, stream>>>(cur2, row2, part, nscan);
    k_scan_carry<<<1, 1024, 0, stream>>>(part, nb_scan);
    k_scan_add<<<nb_scan, 1024, 0, stream>>>(row2, cur2, part, nscan, 2 * E);
    k_place<<<nb_e, blk, 0, stream>>>(src, dst, cur2, pair2, N, E);

    // fused edge gate + BN-e stats (replicated)
    k_edge_fused<<<nt_e, blk, 0, stream>>>(e, src, dst, B1h, B2h, B3w, B3b,
                                           gbuf, e_rep, E);
    k_bn_final<<<1, 64, 0, stream>>>(e_rep, 1.0f / (float)E, bneg, bneb,
                                     e_scale, e_shift);

    long long total4 = (long long)(ED / 4);
    int nb_s = (int)((total4 + 255) / 256);
    float* sigma = ws_big ? sig_ws : gbuf;
    k_edge_sigma<<<nb_s, blk, 0, stream>>>(
        (const float4*)gbuf, (const float4*)e,
        (float4*)sigma, ws_big ? (float4*)gbuf : nullptr,
        e_scale, e_shift, total4);

    int nb_g2 = (int)(((size_t)2 * N * 64 + 255) / 256);
    k_gather2<<<nb_g2, blk, 0, stream>>>(sigma, pair2, row2, A2h, A3h,
                                         agg_f, agg_b, N);

    k_node_pre<<<1024, blk, 0, stream>>>(A1h, agg_f, agg_b,
        out, h_rep, (long long)ND);
    k_bn_final<<<1, 64, 0, stream>>>(h_rep, 1.0f / (float)N, bnhg, bnhb,
                                     h_scale, h_shift);
    k_node_out<<<1024, blk, 0, stream>>>(h, h_scale, h_shift,
                                         out, (long long)ND);

    if (!ws_big) {
        hipMemcpyAsync(gbuf, e, ED * sizeof(float), hipMemcpyDeviceToDevice, stream);
    }
}

// Round 10
// 680.820 us; speedup vs baseline: 2.5043x; 1.0352x over previous
//
#include <hip/hip_runtime.h>
#include <cstdint>
#include <cstddef>

#define DD 64
#define TILE 64
#define LSTR 65   // padded LDS row stride (floats): bank = (row + col) % 32 -> <=2-way (free)
#define NREP 64   // stat-replica count: spreads block atomics over 64*128 floats
constexpr float BN_EPS  = 1e-5f;
constexpr float DEG_EPS = 1e-6f;

__device__ __forceinline__ float fatomic_add(float* p, float v) {
    return unsafeAtomicAdd(p, v);   // hardware global_atomic_add_f32
}

// =============== tiled linear: o = x @ W^T + b, single LDS buffer ============
// grid.x = row-chunks of 64, grid.y = which of 5 matrices
__global__ __launch_bounds__(256) void k_tile_linear(
    const float* __restrict__ x, int R,
    const float* __restrict__ w0, const float* __restrict__ b0, float* __restrict__ o0,
    const float* __restrict__ w1, const float* __restrict__ b1, float* __restrict__ o1,
    const float* __restrict__ w2, const float* __restrict__ b2, float* __restrict__ o2,
    const float* __restrict__ w3, const float* __restrict__ b3, float* __restrict__ o3,
    const float* __restrict__ w4, const float* __restrict__ b4, float* __restrict__ o4)
{
    const float* w; const float* b; float* o;
    switch (blockIdx.y) {
        case 0:  w = w0; b = b0; o = o0; break;
        case 1:  w = w1; b = b1; o = o1; break;
        case 2:  w = w2; b = b2; o = o2; break;
        case 3:  w = w3; b = b3; o = o3; break;
        default: w = w4; b = b4; o = o4; break;
    }
    __shared__ float ldsE[TILE * LSTR];
    int tid  = threadIdx.x;
    int lane = tid & 63;
    int base = blockIdx.x * TILE;
    int rem  = R - base; if (rem > TILE) rem = TILE;
    int qu   = __builtin_amdgcn_readfirstlane(tid >> 6);   // wave id 0..3, SGPR

    const float4* x4 = reinterpret_cast<const float4*>(x + (size_t)base * DD);
    #pragma unroll
    for (int j = 0; j < 4; ++j) {
        int f4 = j * 256 + tid;          // float4 index in tile
        int r  = f4 >> 4, c = f4 & 15;
        if (r < rem) {
            float4 v = x4[f4];
            ldsE[r * LSTR + c * 4 + 0] = v.x;
            ldsE[r * LSTR + c * 4 + 1] = v.y;
            ldsE[r * LSTR + c * 4 + 2] = v.z;
            ldsE[r * LSTR + c * 4 + 3] = v.w;
        }
    }
    __syncthreads();

    float acc[16];
    #pragma unroll
    for (int i = 0; i < 16; ++i) acc[i] = b[qu * 16 + i];
    #pragma unroll 4
    for (int k = 0; k < 64; ++k) {
        float ev = ldsE[lane * LSTR + k];
        const float* wq = w + (size_t)(qu * 16) * DD + k;
        #pragma unroll
        for (int i = 0; i < 16; ++i)
            acc[i] = fmaf(ev, wq[(size_t)i * DD], acc[i]);
    }
    __syncthreads();   // all reads of ldsE done -> safe to overwrite
    #pragma unroll
    for (int i = 0; i < 16; ++i)
        ldsE[lane * LSTR + qu * 16 + i] = acc[i];
    __syncthreads();

    float4* outp4 = reinterpret_cast<float4*>(o + (size_t)base * DD);
    #pragma unroll
    for (int j = 0; j < 4; ++j) {
        int f4 = j * 256 + tid;
        int r  = f4 >> 4, c = f4 & 15;
        if (r < rem) {
            float4 v;
            v.x = ldsE[r * LSTR + c * 4 + 0];
            v.y = ldsE[r * LSTR + c * 4 + 1];
            v.z = ldsE[r * LSTR + c * 4 + 2];
            v.w = ldsE[r * LSTR + c * 4 + 3];
            outp4[f4] = v;
        }
    }
}

// =============== fused edge gate: g = B3 e + b3 + B1h[src] + B2h[dst] ========
// Block per 64-edge tile. Also writes the e-passthrough (ecopy) from regs.
__global__ __launch_bounds__(256) void k_edge_fused(
    const float* __restrict__ e,
    const int* __restrict__ src, const int* __restrict__ dst,
    const float* __restrict__ B1h, const float* __restrict__ B2h,
    const float* __restrict__ w, const float* __restrict__ b,
    float* __restrict__ g, float4* ecopy, float* __restrict__ sums, int E)
{
    __shared__ float ldsE[TILE * LSTR];
    __shared__ float red[256];
    int tid  = threadIdx.x;
    int lane = tid & 63;
    int base = blockIdx.x * TILE;
    int rem  = E - base; if (rem > TILE) rem = TILE;
    int qu   = __builtin_amdgcn_readfirstlane(tid >> 6);

    // phase 0a: read e tile into regs
    const float4* e4 = reinterpret_cast<const float4*>(e + (size_t)base * DD);
    float4 ev[4];
    #pragma unroll
    for (int j = 0; j < 4; ++j) {
        int f4 = j * 256 + tid;
        int r  = f4 >> 4;
        ev[j] = (r < rem) ? e4[f4] : float4{0.f, 0.f, 0.f, 0.f};
    }

    // phase 0b: issue this wave's 32 B-row loads (latency hides under GEMV)
    float b1r[16], b2r[16];
    #pragma unroll
    for (int it = 0; it < 16; ++it) {
        int el = qu * 16 + it;               // wave-uniform
        if (el < rem) {
            int ee = base + el;
            int s = src[ee], t = dst[ee];    // scalar loads (uniform address)
            b1r[it] = B1h[(size_t)s * DD + lane];
            b2r[it] = B2h[(size_t)t * DD + lane];
        } else { b1r[it] = 0.f; b2r[it] = 0.f; }
    }

    // phase 1: stage e tile to LDS (+ optional e passthrough from regs)
    #pragma unroll
    for (int j = 0; j < 4; ++j) {
        int f4 = j * 256 + tid;
        int r  = f4 >> 4, c = f4 & 15;
        if (r < rem) {
            ldsE[r * LSTR + c * 4 + 0] = ev[j].x;
            ldsE[r * LSTR + c * 4 + 1] = ev[j].y;
            ldsE[r * LSTR + c * 4 + 2] = ev[j].z;
            ldsE[r * LSTR + c * 4 + 3] = ev[j].w;
            if (ecopy) ecopy[(size_t)base * 16 + f4] = ev[j];
        }
    }
    __syncthreads();

    // phase 2: GEMV B3 * e_row + b3 (acc in regs)
    float acc[16];
    #pragma unroll
    for (int i = 0; i < 16; ++i) acc[i] = b[qu * 16 + i];
    #pragma unroll 4
    for (int k = 0; k < 64; ++k) {
        float evk = ldsE[lane * LSTR + k];
        const float* wq = w + (size_t)(qu * 16) * DD + k;
        #pragma unroll
        for (int i = 0; i < 16; ++i)
            acc[i] = fmaf(evk, wq[(size_t)i * DD], acc[i]);
    }
    __syncthreads();   // reads done -> overwrite ldsE with g0
    #pragma unroll
    for (int i = 0; i < 16; ++i)
        ldsE[lane * LSTR + qu * 16 + i] = acc[i];
    __syncthreads();

    // phase 3: add prefetched rows + stats + coalesced g write (lane = col d)
    float ps = 0.f, pq = 0.f;
    #pragma unroll
    for (int it = 0; it < 16; ++it) {
        int el = qu * 16 + it;
        if (el < rem) {
            int ee = base + el;
            float v = ldsE[el * LSTR + lane] + b1r[it] + b2r[it];
            g[(size_t)ee * DD + lane] = v;
            ps += v; pq += v * v;
        }
    }
    float* srep = sums + (size_t)(blockIdx.x & (NREP - 1)) * 128;
    red[tid] = ps; __syncthreads();
    if (tid < 64) fatomic_add(&srep[tid],      red[tid] + red[tid+64] + red[tid+128] + red[tid+192]);
    __syncthreads();
    red[tid] = pq; __syncthreads();
    if (tid < 64) fatomic_add(&srep[64 + tid], red[tid] + red[tid+64] + red[tid+128] + red[tid+192]);
}

// ---------------- fold replicated stats into scale/shift ---------------------
__global__ void k_bn_final(const float* __restrict__ reps, float inv_cnt,
                           const float* __restrict__ gamma, const float* __restrict__ beta,
                           float* __restrict__ scale, float* __restrict__ shift)
{
    int d = threadIdx.x;
    if (d >= DD) return;
    float s = 0.f, q = 0.f;
    #pragma unroll 8
    for (int r = 0; r < NREP; ++r) {
        s += reps[r * 128 + d];
        q += reps[r * 128 + 64 + d];
    }
    float mean = s * inv_cnt;
    float var  = fmaxf(q * inv_cnt - mean * mean, 0.f);
    float rs   = rsqrtf(var + BN_EPS);
    float sc   = gamma[d] * rs;
    scale[d] = sc;
    shift[d] = beta[d] - mean * sc;
}

// ---------------- CSR build ---------------------------------------------------
__global__ __launch_bounds__(256) void k_count(
    const int* __restrict__ src, const int* __restrict__ dst,
    int* __restrict__ cnt2, int N, int E)
{
    int ee = blockIdx.x * 256 + threadIdx.x;
    if (ee >= E) return;
    atomicAdd(&cnt2[dst[ee]], 1);        // fwd counts at [0,N)
    atomicAdd(&cnt2[N + src[ee]], 1);    // bwd counts at [N,2N)
}

// hierarchical exclusive scan: block-local -> carry -> add
__global__ __launch_bounds__(1024) void k_scan_blk(
    const int* __restrict__ cnt, int* __restrict__ row, int* __restrict__ part, int n)
{
    __shared__ int tmp[1024];
    int tid = threadIdx.x;
    int i   = blockIdx.x * 1024 + tid;
    int v   = (i < n) ? cnt[i] : 0;
    tmp[tid] = v; __syncthreads();
    for (int off = 1; off < 1024; off <<= 1) {
        int t = (tid >= off) ? tmp[tid - off] : 0;
        __syncthreads();
        tmp[tid] += t;
        __syncthreads();
    }
    if (i < n) row[i] = tmp[tid] - v;            // local exclusive
    if (tid == 1023) part[blockIdx.x] = tmp[1023];  // block total
}

__global__ __launch_bounds__(1024) void k_scan_carry(int* part, int nb)
{
    __shared__ int tmp[1024];
    int tid = threadIdx.x;
    int carry = 0;
    for (int base = 0; base < nb; base += 1024) {
        int i = base + tid;
        int v = (i < nb) ? part[i] : 0;
        tmp[tid] = v; __syncthreads();
        for (int off = 1; off < 1024; off <<= 1) {
            int t = (tid >= off) ? tmp[tid - off] : 0;
            __syncthreads();
            tmp[tid] += t;
            __syncthreads();
        }
        if (i < nb) part[i] = carry + tmp[tid] - v;
        carry += tmp[1023];
        __syncthreads();
    }
}

__global__ __launch_bounds__(1024) void k_scan_add(
    int* __restrict__ row, int* __restrict__ cur, const int* __restrict__ part,
    int n, int total)
{
    int i = blockIdx.x * 1024 + threadIdx.x;
    if (i < n) {
        int r = row[i] + part[blockIdx.x];
        row[i] = r; cur[i] = r;
    }
    if (i == 0) row[n] = total;
}

// place packed (eid, other-node) pairs
__global__ __launch_bounds__(256) void k_place(
    const int* __restrict__ src, const int* __restrict__ dst,
    int* __restrict__ cur2, int2* __restrict__ pair2, int N, int E)
{
    int ee = blockIdx.x * 256 + threadIdx.x;
    if (ee >= E) return;
    int s = src[ee], t = dst[ee];
    int pf = atomicAdd(&cur2[t], 1);
    pair2[pf] = make_int2(ee, s);
    int pb = atomicAdd(&cur2[N + s], 1);
    pair2[pb] = make_int2(ee, t);        // bwd slots live at [E, 2E)
}

// ---------------- merged gather with inline sigma recompute ------------------
// 2N waves (fwd then bwd). sigma = sigmoid(relu(g*sc+sh)+e) computed on the fly
// from the g and e rows -- the sigma tensor is never materialized.
__global__ __launch_bounds__(256) void k_gather2(
    const float* __restrict__ g, const float* __restrict__ efeat,
    const int2* __restrict__ pair2, const int* __restrict__ row2,
    const float* __restrict__ A2h, const float* __restrict__ A3h,
    const float* __restrict__ e_scale, const float* __restrict__ e_shift,
    float* __restrict__ agg_f, float* __restrict__ agg_b, int N)
{
    int gw = (blockIdx.x * 256 + threadIdx.x) >> 6;
    if (gw >= 2 * N) return;
    int lane = threadIdx.x & 63;
    bool bwd = gw >= N;
    int wid  = bwd ? gw - N : gw;
    const float4* Ah4 = reinterpret_cast<const float4*>(bwd ? A3h : A2h);
    float* agg        = bwd ? agg_b : agg_f;
    int beg = row2[gw], end = row2[gw + 1];   // fwd rows [0,N), bwd rows [N,2N)
    int q  = lane >> 4;      // edge slot 0..3
    int dj = lane & 15;      // float4 column slot
    float4 sc = reinterpret_cast<const float4*>(e_scale)[dj];
    float4 sh = reinterpret_cast<const float4*>(e_shift)[dj];
    float4 num = {0.f, 0.f, 0.f, 0.f};
    float4 den = {0.f, 0.f, 0.f, 0.f};
    const float4* g4 = reinterpret_cast<const float4*>(g);
    const float4* e4 = reinterpret_cast<const float4*>(efeat);
    for (int k = beg + q; k < end; k += 8) {
        int  k2   = k + 4;
        bool hasb = k2 < end;
        int2 pa = pair2[k];
        int2 pb = hasb ? pair2[k2] : pa;
        float4 ga = g4[(size_t)pa.x * 16 + dj];
        float4 ea = e4[(size_t)pa.x * 16 + dj];
        float4 aa = Ah4[(size_t)pa.y * 16 + dj];
        float4 gb = g4[(size_t)pb.x * 16 + dj];
        float4 eb = e4[(size_t)pb.x * 16 + dj];
        float4 ab = Ah4[(size_t)pb.y * 16 + dj];
        float4 sa;
        sa.x = 1.f / (1.f + __expf(-(fmaxf(ga.x * sc.x + sh.x, 0.f) + ea.x)));
        sa.y = 1.f / (1.f + __expf(-(fmaxf(ga.y * sc.y + sh.y, 0.f) + ea.y)));
        sa.z = 1.f / (1.f + __expf(-(fmaxf(ga.z * sc.z + sh.z, 0.f) + ea.z)));
        sa.w = 1.f / (1.f + __expf(-(fmaxf(ga.w * sc.w + sh.w, 0.f) + ea.w)));
        num.x += sa.x * aa.x; num.y += sa.y * aa.y;
        num.z += sa.z * aa.z; num.w += sa.w * aa.w;
        den.x += sa.x; den.y += sa.y; den.z += sa.z; den.w += sa.w;
        if (hasb) {
            float4 sb;
            sb.x = 1.f / (1.f + __expf(-(fmaxf(gb.x * sc.x + sh.x, 0.f) + eb.x)));
            sb.y = 1.f / (1.f + __expf(-(fmaxf(gb.y * sc.y + sh.y, 0.f) + eb.y)));
            sb.z = 1.f / (1.f + __expf(-(fmaxf(gb.z * sc.z + sh.z, 0.f) + eb.z)));
            sb.w = 1.f / (1.f + __expf(-(fmaxf(gb.w * sc.w + sh.w, 0.f) + eb.w)));
            num.x += sb.x * ab.x; num.y += sb.y * ab.y;
            num.z += sb.z * ab.z; num.w += sb.w * ab.w;
            den.x += sb.x; den.y += sb.y; den.z += sb.z; den.w += sb.w;
        }
    }
    #pragma unroll
    for (int off = 16; off <= 32; off <<= 1) {
        num.x += __shfl_xor(num.x, off); num.y += __shfl_xor(num.y, off);
        num.z += __shfl_xor(num.z, off); num.w += __shfl_xor(num.w, off);
        den.x += __shfl_xor(den.x, off); den.y += __shfl_xor(den.y, off);
        den.z += __shfl_xor(den.z, off); den.w += __shfl_xor(den.w, off);
    }
    if (q == 0) {
        float4 res;
        res.x = num.x / (den.x + DEG_EPS);
        res.y = num.y / (den.y + DEG_EPS);
        res.z = num.z / (den.z + DEG_EPS);
        res.w = num.w / (den.w + DEG_EPS);
        reinterpret_cast<float4*>(agg)[(size_t)wid * 16 + dj] = res;
    }
}

// ---------------- h_pre = A1h + agg_f + agg_b, + replicated column stats -----
__global__ __launch_bounds__(256) void k_node_pre(
    const float* __restrict__ A1h,
    const float* __restrict__ agg_f, const float* __restrict__ agg_b,
    float* __restrict__ hpre, float* __restrict__ sums, long long total)
{
    int tid = threadIdx.x;
    long long idx = (long long)blockIdx.x * 256 + tid;
    long long stride = (long long)gridDim.x * 256;
    float ps = 0.f, pq = 0.f;
    for (; idx < total; idx += stride) {
        float v = A1h[idx] + agg_f[idx] + agg_b[idx];
        hpre[idx] = v;
        ps += v; pq += v * v;
    }
    float* srep = sums + (size_t)(blockIdx.x & (NREP - 1)) * 128;
    __shared__ float red[256];
    red[tid] = ps; __syncthreads();
    if (tid < 64) fatomic_add(&srep[tid],      red[tid] + red[tid+64] + red[tid+128] + red[tid+192]);
    __syncthreads();
    red[tid] = pq; __syncthreads();
    if (tid < 64) fatomic_add(&srep[64 + tid], red[tid] + red[tid+64] + red[tid+128] + red[tid+192]);
}

// ---------------- finish h: BN affine + relu + residual (in place) -----------
__global__ __launch_bounds__(256) void k_node_out(
    const float* __restrict__ h,
    const float* __restrict__ scale, const float* __restrict__ shift,
    float* __restrict__ out, long long total)
{
    long long idx = (long long)blockIdx.x * 256 + threadIdx.x;
    long long stride = (long long)gridDim.x * 256;
    for (; idx < total; idx += stride) {
        int d = (int)(idx & (DD - 1));
        float v = out[idx] * scale[d] + shift[d];
        out[idx] = fmaxf(v, 0.f) + h[idx];
    }
}

extern "C" void kernel_launch(void* const* d_in, const int* in_sizes, int n_in,
                              void* d_out, int out_size, void* d_ws, size_t ws_size,
                              hipStream_t stream)
{
    const float* h    = (const float*)d_in[0];
    const float* e    = (const float*)d_in[1];
    const int*   src  = (const int*)d_in[2];
    const int*   dst  = (const int*)d_in[3];
    const float* A1w  = (const float*)d_in[4];
    const float* A1b  = (const float*)d_in[5];
    const float* A2w  = (const float*)d_in[6];
    const float* A2b  = (const float*)d_in[7];
    const float* A3w  = (const float*)d_in[8];
    const float* A3b  = (const float*)d_in[9];
    const float* B1w  = (const float*)d_in[10];
    const float* B1b  = (const float*)d_in[11];
    const float* B2w  = (const float*)d_in[12];
    const float* B2b  = (const float*)d_in[13];
    const float* B3w  = (const float*)d_in[14];
    const float* B3b  = (const float*)d_in[15];
    const float* bnhg = (const float*)d_in[16];
    const float* bnhb = (const float*)d_in[17];
    const float* bneg = (const float*)d_in[18];
    const float* bneb = (const float*)d_in[19];

    const int N = in_sizes[0] / DD;
    const int E = in_sizes[1] / DD;
    const size_t ND = (size_t)N * DD;
    const size_t ED = (size_t)E * DD;

    float* ws    = (float*)d_ws;
    float* A1h   = ws + 0 * ND;
    float* A2h   = ws + 1 * ND;
    float* A3h   = ws + 2 * ND;
    float* B1h   = ws + 3 * ND;
    float* B2h   = ws + 4 * ND;
    float* agg_f = ws + 5 * ND;
    float* agg_b = ws + 6 * ND;
    float* stats = ws + 7 * ND;
    // stats layout (floats):
    //   [0 .. 8192)      e-stat replicas: NREP x (sum64 | sumsq64)
    //   [8192 .. 16384)  h-stat replicas
    //   [16384..16448) e_scale  [16448..16512) e_shift
    //   [16512..16576) h_scale  [16576..16640) h_shift
    const size_t STATS_F = 16640;
    float* e_rep   = stats;
    float* h_rep   = stats + 8192;
    float* e_scale = stats + 16384;
    float* e_shift = stats + 16448;
    float* h_scale = stats + 16512;
    float* h_shift = stats + 16576;

    const int nscan   = 2 * N;
    const int nb_scan = (nscan + 1023) / 1024;
    const size_t int_count = (size_t)(4 * N + 1 + nb_scan) + 4 * (size_t)E + 2;
    const size_t need_big  = (7 * ND + STATS_F + ED) * sizeof(float) + int_count * sizeof(int);
    const bool   ws_big    = ws_size >= need_big;

    float* g_ws  = stats + STATS_F;                     // ED floats (only if ws_big)
    int*   ibase = (int*)(ws_big ? (g_ws + ED) : (stats + STATS_F));
    int*  cur2   = ibase;                     // 2N (counts -> cursors)
    int*  row2   = ibase + 2 * N;             // 2N+1
    int*  part   = ibase + 4 * N + 1;         // nb_scan
    int2* pair2  = (int2*)(((uintptr_t)(part + nb_scan) + 7) & ~(uintptr_t)7); // 2E pairs

    float* out  = (float*)d_out;
    float* gbuf = out + ND;   // out e-region

    hipMemsetAsync(stats, 0, STATS_F * sizeof(float), stream);
    hipMemsetAsync(cur2, 0, 2 * (size_t)N * sizeof(int), stream);

    dim3 blk(256);
    int nb_e  = (E + 255) / 256;
    int nt_n  = (N + TILE - 1) / TILE;
    int nt_e  = (E + TILE - 1) / TILE;

    k_tile_linear<<<dim3(nt_n, 5), blk, 0, stream>>>(h, N,
        A1w, A1b, A1h,  A2w, A2b, A2h,  A3w, A3b, A3h,
        B1w, B1b, B1h,  B2w, B2b, B2h);

    // CSR build (fwd+bwd merged), hierarchical scan
    k_count<<<nb_e, blk, 0, stream>>>(src, dst, cur2, N, E);
    k_scan_blk<<<nb_scan, 1024, 0, stream>>>(cur2, row2, part, nscan);
    k_scan_carry<<<1, 1024, 0, stream>>>(part, nb_scan);
    k_scan_add<<<nb_scan, 1024, 0, stream>>>(row2, cur2, part, nscan, 2 * E);
    k_place<<<nb_e, blk, 0, stream>>>(src, dst, cur2, pair2, N, E);

    // fused edge gate + BN-e stats (+ e passthrough when ws_big)
    // ws_big: g -> workspace, e copy -> out e-region (no memcpy needed at all)
    // !ws_big: g -> out e-region, memcpy e over it after gather
    float* gmem = ws_big ? g_ws : gbuf;
    k_edge_fused<<<nt_e, blk, 0, stream>>>(e, src, dst, B1h, B2h, B3w, B3b,
                                           gmem, ws_big ? (float4*)gbuf : nullptr,
                                           e_rep, E);
    k_bn_final<<<1, 64, 0, stream>>>(e_rep, 1.0f / (float)E, bneg, bneb,
                                     e_scale, e_shift);

    // merged gather with inline sigma recompute
    int nb_g2 = (int)(((size_t)2 * N * 64 + 255) / 256);
    k_gather2<<<nb_g2, blk, 0, stream>>>(gmem, e, pair2, row2, A2h, A3h,
                                         e_scale, e_shift, agg_f, agg_b, N);

    k_node_pre<<<1024, blk, 0, stream>>>(A1h, agg_f, agg_b,
        out, h_rep, (long long)ND);
    k_bn_final<<<1, 64, 0, stream>>>(h_rep, 1.0f / (float)N, bnhg, bnhb,
                                     h_scale, h_shift);
    k_node_out<<<1024, blk, 0, stream>>>(h, h_scale, h_shift,
                                         out, (long long)ND);

    if (!ws_big) {
        hipMemcpyAsync(gbuf, e, ED * sizeof(float), hipMemcpyDeviceToDevice, stream);
    }
}

// Round 11
// 628.913 us; speedup vs baseline: 2.7110x; 1.0825x over previous
//
#include <hip/hip_runtime.h>
#include <cstdint>
#include <cstddef>

#define DD 64
#define TILE 64
#define LSTR 65   // padded LDS row stride (floats): bank = (row + col) % 32 -> <=2-way (free)
#define NREP 64   // stat-replica count: spreads block atomics over 64*128 floats
constexpr float BN_EPS  = 1e-5f;
constexpr float DEG_EPS = 1e-6f;

__device__ __forceinline__ float fatomic_add(float* p, float v) {
    return unsafeAtomicAdd(p, v);   // hardware global_atomic_add_f32
}

__device__ __forceinline__ uint32_t bf16r(float x) {   // round-to-nearest-even bf16
    uint32_t u = __float_as_uint(x);
    return (u + 0x7fffu + ((u >> 16) & 1u)) >> 16;
}
__device__ __forceinline__ uint32_t pack_ge(float g, float e) {
    return (bf16r(e) << 16) | bf16r(g);
}

// =============== tiled linear: o = x @ W^T + b, single LDS buffer ============
__global__ __launch_bounds__(256) void k_tile_linear(
    const float* __restrict__ x, int R,
    const float* __restrict__ w0, const float* __restrict__ b0, float* __restrict__ o0,
    const float* __restrict__ w1, const float* __restrict__ b1, float* __restrict__ o1,
    const float* __restrict__ w2, const float* __restrict__ b2, float* __restrict__ o2,
    const float* __restrict__ w3, const float* __restrict__ b3, float* __restrict__ o3,
    const float* __restrict__ w4, const float* __restrict__ b4, float* __restrict__ o4)
{
    const float* w; const float* b; float* o;
    switch (blockIdx.y) {
        case 0:  w = w0; b = b0; o = o0; break;
        case 1:  w = w1; b = b1; o = o1; break;
        case 2:  w = w2; b = b2; o = o2; break;
        case 3:  w = w3; b = b3; o = o3; break;
        default: w = w4; b = b4; o = o4; break;
    }
    __shared__ float ldsE[TILE * LSTR];
    int tid  = threadIdx.x;
    int lane = tid & 63;
    int base = blockIdx.x * TILE;
    int rem  = R - base; if (rem > TILE) rem = TILE;
    int qu   = __builtin_amdgcn_readfirstlane(tid >> 6);   // wave id 0..3, SGPR

    const float4* x4 = reinterpret_cast<const float4*>(x + (size_t)base * DD);
    #pragma unroll
    for (int j = 0; j < 4; ++j) {
        int f4 = j * 256 + tid;          // float4 index in tile
        int r  = f4 >> 4, c = f4 & 15;
        if (r < rem) {
            float4 v = x4[f4];
            ldsE[r * LSTR + c * 4 + 0] = v.x;
            ldsE[r * LSTR + c * 4 + 1] = v.y;
            ldsE[r * LSTR + c * 4 + 2] = v.z;
            ldsE[r * LSTR + c * 4 + 3] = v.w;
        }
    }
    __syncthreads();

    float acc[16];
    #pragma unroll
    for (int i = 0; i < 16; ++i) acc[i] = b[qu * 16 + i];
    #pragma unroll 4
    for (int k = 0; k < 64; ++k) {
        float ev = ldsE[lane * LSTR + k];
        const float* wq = w + (size_t)(qu * 16) * DD + k;
        #pragma unroll
        for (int i = 0; i < 16; ++i)
            acc[i] = fmaf(ev, wq[(size_t)i * DD], acc[i]);
    }
    __syncthreads();   // all reads of ldsE done -> safe to overwrite
    #pragma unroll
    for (int i = 0; i < 16; ++i)
        ldsE[lane * LSTR + qu * 16 + i] = acc[i];
    __syncthreads();

    float4* outp4 = reinterpret_cast<float4*>(o + (size_t)base * DD);
    #pragma unroll
    for (int j = 0; j < 4; ++j) {
        int f4 = j * 256 + tid;
        int r  = f4 >> 4, c = f4 & 15;
        if (r < rem) {
            float4 v;
            v.x = ldsE[r * LSTR + c * 4 + 0];
            v.y = ldsE[r * LSTR + c * 4 + 1];
            v.z = ldsE[r * LSTR + c * 4 + 2];
            v.w = ldsE[r * LSTR + c * 4 + 3];
            outp4[f4] = v;
        }
    }
}

// =============== fused edge gate =============================================
// g = B3 e + b3 + B1h[src] + B2h[dst]; writes packed bf16 (g,e) rows + fp32
// e passthrough + fp32 BN stats (replicated).
__global__ __launch_bounds__(256) void k_edge_fused(
    const float* __restrict__ e,
    const int* __restrict__ src, const int* __restrict__ dst,
    const float* __restrict__ B1h, const float* __restrict__ B2h,
    const float* __restrict__ w, const float* __restrict__ b,
    uint32_t* __restrict__ packed, float4* ecopy, float* __restrict__ sums, int E)
{
    __shared__ float ldsE[TILE * LSTR];
    __shared__ float red[256];
    int tid  = threadIdx.x;
    int lane = tid & 63;
    int base = blockIdx.x * TILE;
    int rem  = E - base; if (rem > TILE) rem = TILE;
    int qu   = __builtin_amdgcn_readfirstlane(tid >> 6);

    // phase 0a: read e tile into regs
    const float4* e4 = reinterpret_cast<const float4*>(e + (size_t)base * DD);
    float4 ev[4];
    #pragma unroll
    for (int j = 0; j < 4; ++j) {
        int f4 = j * 256 + tid;
        int r  = f4 >> 4;
        ev[j] = (r < rem) ? e4[f4] : float4{0.f, 0.f, 0.f, 0.f};
    }

    // phase 0b: issue this wave's 32 B-row loads (latency hides under GEMV)
    float b1r[16], b2r[16];
    #pragma unroll
    for (int it = 0; it < 16; ++it) {
        int el = qu * 16 + it;               // wave-uniform
        if (el < rem) {
            int ee = base + el;
            int s = src[ee], t = dst[ee];    // scalar loads (uniform address)
            b1r[it] = B1h[(size_t)s * DD + lane];
            b2r[it] = B2h[(size_t)t * DD + lane];
        } else { b1r[it] = 0.f; b2r[it] = 0.f; }
    }

    // phase 1: stage e tile to LDS (+ e passthrough from regs)
    #pragma unroll
    for (int j = 0; j < 4; ++j) {
        int f4 = j * 256 + tid;
        int r  = f4 >> 4, c = f4 & 15;
        if (r < rem) {
            ldsE[r * LSTR + c * 4 + 0] = ev[j].x;
            ldsE[r * LSTR + c * 4 + 1] = ev[j].y;
            ldsE[r * LSTR + c * 4 + 2] = ev[j].z;
            ldsE[r * LSTR + c * 4 + 3] = ev[j].w;
            if (ecopy) ecopy[(size_t)base * 16 + f4] = ev[j];
        }
    }
    __syncthreads();

    // phase 2: GEMV B3 * e_row + b3 (acc in regs)
    float acc[16];
    #pragma unroll
    for (int i = 0; i < 16; ++i) acc[i] = b[qu * 16 + i];
    #pragma unroll 4
    for (int k = 0; k < 64; ++k) {
        float evk = ldsE[lane * LSTR + k];
        const float* wq = w + (size_t)(qu * 16) * DD + k;
        #pragma unroll
        for (int i = 0; i < 16; ++i)
            acc[i] = fmaf(evk, wq[(size_t)i * DD], acc[i]);
    }
    __syncthreads();   // reads done -> overwrite ldsE with g0
    #pragma unroll
    for (int i = 0; i < 16; ++i)
        ldsE[lane * LSTR + qu * 16 + i] = acc[i];
    __syncthreads();

    // phase 3: add prefetched rows, fp32 stats, packed bf16 (g,e) write.
    // e re-read here is coalesced and L2-hot (same lines read in phase 0a).
    float ps = 0.f, pq = 0.f;
    #pragma unroll
    for (int it = 0; it < 16; ++it) {
        int el = qu * 16 + it;
        if (el < rem) {
            int ee = base + el;
            float evf = e[(size_t)ee * DD + lane];
            float v = ldsE[el * LSTR + lane] + b1r[it] + b2r[it];
            packed[(size_t)ee * DD + lane] = pack_ge(v, evf);
            ps += v; pq += v * v;
        }
    }
    float* srep = sums + (size_t)(blockIdx.x & (NREP - 1)) * 128;
    red[tid] = ps; __syncthreads();
    if (tid < 64) fatomic_add(&srep[tid],      red[tid] + red[tid+64] + red[tid+128] + red[tid+192]);
    __syncthreads();
    red[tid] = pq; __syncthreads();
    if (tid < 64) fatomic_add(&srep[64 + tid], red[tid] + red[tid+64] + red[tid+128] + red[tid+192]);
}

// ---------------- fold replicated stats into scale/shift ---------------------
__global__ void k_bn_final(const float* __restrict__ reps, float inv_cnt,
                           const float* __restrict__ gamma, const float* __restrict__ beta,
                           float* __restrict__ scale, float* __restrict__ shift)
{
    int d = threadIdx.x;
    if (d >= DD) return;
    float s = 0.f, q = 0.f;
    #pragma unroll 8
    for (int r = 0; r < NREP; ++r) {
        s += reps[r * 128 + d];
        q += reps[r * 128 + 64 + d];
    }
    float mean = s * inv_cnt;
    float var  = fmaxf(q * inv_cnt - mean * mean, 0.f);
    float rs   = rsqrtf(var + BN_EPS);
    float sc   = gamma[d] * rs;
    scale[d] = sc;
    shift[d] = beta[d] - mean * sc;
}

// ---------------- CSR build ---------------------------------------------------
__global__ __launch_bounds__(256) void k_count(
    const int* __restrict__ src, const int* __restrict__ dst,
    int* __restrict__ cnt2, int N, int E)
{
    int ee = blockIdx.x * 256 + threadIdx.x;
    if (ee >= E) return;
    atomicAdd(&cnt2[dst[ee]], 1);        // fwd counts at [0,N)
    atomicAdd(&cnt2[N + src[ee]], 1);    // bwd counts at [N,2N)
}

// hierarchical exclusive scan: block-local -> carry -> add
__global__ __launch_bounds__(1024) void k_scan_blk(
    const int* __restrict__ cnt, int* __restrict__ row, int* __restrict__ part, int n)
{
    __shared__ int tmp[1024];
    int tid = threadIdx.x;
    int i   = blockIdx.x * 1024 + tid;
    int v   = (i < n) ? cnt[i] : 0;
    tmp[tid] = v; __syncthreads();
    for (int off = 1; off < 1024; off <<= 1) {
        int t = (tid >= off) ? tmp[tid - off] : 0;
        __syncthreads();
        tmp[tid] += t;
        __syncthreads();
    }
    if (i < n) row[i] = tmp[tid] - v;            // local exclusive
    if (tid == 1023) part[blockIdx.x] = tmp[1023];  // block total
}

__global__ __launch_bounds__(1024) void k_scan_carry(int* part, int nb)
{
    __shared__ int tmp[1024];
    int tid = threadIdx.x;
    int carry = 0;
    for (int base = 0; base < nb; base += 1024) {
        int i = base + tid;
        int v = (i < nb) ? part[i] : 0;
        tmp[tid] = v; __syncthreads();
        for (int off = 1; off < 1024; off <<= 1) {
            int t = (tid >= off) ? tmp[tid - off] : 0;
            __syncthreads();
            tmp[tid] += t;
            __syncthreads();
        }
        if (i < nb) part[i] = carry + tmp[tid] - v;
        carry += tmp[1023];
        __syncthreads();
    }
}

__global__ __launch_bounds__(1024) void k_scan_add(
    int* __restrict__ row, int* __restrict__ cur, const int* __restrict__ part,
    int n, int total)
{
    int i = blockIdx.x * 1024 + threadIdx.x;
    if (i < n) {
        int r = row[i] + part[blockIdx.x];
        row[i] = r; cur[i] = r;
    }
    if (i == 0) row[n] = total;
}

// place packed (eid, other-node) pairs
__global__ __launch_bounds__(256) void k_place(
    const int* __restrict__ src, const int* __restrict__ dst,
    int* __restrict__ cur2, int2* __restrict__ pair2, int N, int E)
{
    int ee = blockIdx.x * 256 + threadIdx.x;
    if (ee >= E) return;
    int s = src[ee], t = dst[ee];
    int pf = atomicAdd(&cur2[t], 1);
    pair2[pf] = make_int2(ee, s);
    int pb = atomicAdd(&cur2[N + s], 1);
    pair2[pb] = make_int2(ee, t);        // bwd slots live at [E, 2E)
}

// ---------------- merged gather, sigma recomputed from packed bf16 (g,e) -----
// 2N waves (fwd then bwd). One 256B packed-row read per edge instance; the
// 205 MB packed tensor is L3-resident.
__global__ __launch_bounds__(256) void k_gather2(
    const uint32_t* __restrict__ packed,
    const int2* __restrict__ pair2, const int* __restrict__ row2,
    const float* __restrict__ A2h, const float* __restrict__ A3h,
    const float* __restrict__ e_scale, const float* __restrict__ e_shift,
    float* __restrict__ agg_f, float* __restrict__ agg_b, int N)
{
    int gw = (blockIdx.x * 256 + threadIdx.x) >> 6;
    if (gw >= 2 * N) return;
    int lane = threadIdx.x & 63;
    bool bwd = gw >= N;
    int wid  = bwd ? gw - N : gw;
    const float4* Ah4 = reinterpret_cast<const float4*>(bwd ? A3h : A2h);
    float* agg        = bwd ? agg_b : agg_f;
    int beg = row2[gw], end = row2[gw + 1];   // fwd rows [0,N), bwd rows [N,2N)
    int q  = lane >> 4;      // edge slot 0..3
    int dj = lane & 15;      // float4 column slot
    float4 sc = reinterpret_cast<const float4*>(e_scale)[dj];
    float4 sh = reinterpret_cast<const float4*>(e_shift)[dj];
    float4 num = {0.f, 0.f, 0.f, 0.f};
    float4 den = {0.f, 0.f, 0.f, 0.f};
    const uint4* p4 = reinterpret_cast<const uint4*>(packed);
    for (int k = beg + q; k < end; k += 8) {
        int  k2   = k + 4;
        bool hasb = k2 < end;
        int2 pa = pair2[k];
        int2 pb = hasb ? pair2[k2] : pa;
        uint4  wa = p4[(size_t)pa.x * 16 + dj];
        float4 aa = Ah4[(size_t)pa.y * 16 + dj];
        uint4  wb = p4[(size_t)pb.x * 16 + dj];
        float4 ab = Ah4[(size_t)pb.y * 16 + dj];
        float4 sa;
        {
            float gx = __uint_as_float(wa.x << 16), ex = __uint_as_float(wa.x & 0xffff0000u);
            float gy = __uint_as_float(wa.y << 16), ey = __uint_as_float(wa.y & 0xffff0000u);
            float gz = __uint_as_float(wa.z << 16), ez = __uint_as_float(wa.z & 0xffff0000u);
            float gw4 = __uint_as_float(wa.w << 16), ew = __uint_as_float(wa.w & 0xffff0000u);
            sa.x = 1.f / (1.f + __expf(-(fmaxf(gx * sc.x + sh.x, 0.f) + ex)));
            sa.y = 1.f / (1.f + __expf(-(fmaxf(gy * sc.y + sh.y, 0.f) + ey)));
            sa.z = 1.f / (1.f + __expf(-(fmaxf(gz * sc.z + sh.z, 0.f) + ez)));
            sa.w = 1.f / (1.f + __expf(-(fmaxf(gw4 * sc.w + sh.w, 0.f) + ew)));
        }
        num.x += sa.x * aa.x; num.y += sa.y * aa.y;
        num.z += sa.z * aa.z; num.w += sa.w * aa.w;
        den.x += sa.x; den.y += sa.y; den.z += sa.z; den.w += sa.w;
        if (hasb) {
            float4 sb;
            float gx = __uint_as_float(wb.x << 16), ex = __uint_as_float(wb.x & 0xffff0000u);
            float gy = __uint_as_float(wb.y << 16), ey = __uint_as_float(wb.y & 0xffff0000u);
            float gz = __uint_as_float(wb.z << 16), ez = __uint_as_float(wb.z & 0xffff0000u);
            float gw4 = __uint_as_float(wb.w << 16), ew = __uint_as_float(wb.w & 0xffff0000u);
            sb.x = 1.f / (1.f + __expf(-(fmaxf(gx * sc.x + sh.x, 0.f) + ex)));
            sb.y = 1.f / (1.f + __expf(-(fmaxf(gy * sc.y + sh.y, 0.f) + ey)));
            sb.z = 1.f / (1.f + __expf(-(fmaxf(gz * sc.z + sh.z, 0.f) + ez)));
            sb.w = 1.f / (1.f + __expf(-(fmaxf(gw4 * sc.w + sh.w, 0.f) + ew)));
            num.x += sb.x * ab.x; num.y += sb.y * ab.y;
            num.z += sb.z * ab.z; num.w += sb.w * ab.w;
            den.x += sb.x; den.y += sb.y; den.z += sb.z; den.w += sb.w;
        }
    }
    #pragma unroll
    for (int off = 16; off <= 32; off <<= 1) {
        num.x += __shfl_xor(num.x, off); num.y += __shfl_xor(num.y, off);
        num.z += __shfl_xor(num.z, off); num.w += __shfl_xor(num.w, off);
        den.x += __shfl_xor(den.x, off); den.y += __shfl_xor(den.y, off);
        den.z += __shfl_xor(den.z, off); den.w += __shfl_xor(den.w, off);
    }
    if (q == 0) {
        float4 res;
        res.x = num.x / (den.x + DEG_EPS);
        res.y = num.y / (den.y + DEG_EPS);
        res.z = num.z / (den.z + DEG_EPS);
        res.w = num.w / (den.w + DEG_EPS);
        reinterpret_cast<float4*>(agg)[(size_t)wid * 16 + dj] = res;
    }
}

// ---------------- h_pre = A1h + agg_f + agg_b, + replicated column stats -----
__global__ __launch_bounds__(256) void k_node_pre(
    const float* __restrict__ A1h,
    const float* __restrict__ agg_f, const float* __restrict__ agg_b,
    float* __restrict__ hpre, float* __restrict__ sums, long long total)
{
    int tid = threadIdx.x;
    long long idx = (long long)blockIdx.x * 256 + tid;
    long long stride = (long long)gridDim.x * 256;
    float ps = 0.f, pq = 0.f;
    for (; idx < total; idx += stride) {
        float v = A1h[idx] + agg_f[idx] + agg_b[idx];
        hpre[idx] = v;
        ps += v; pq += v * v;
    }
    float* srep = sums + (size_t)(blockIdx.x & (NREP - 1)) * 128;
    __shared__ float red[256];
    red[tid] = ps; __syncthreads();
    if (tid < 64) fatomic_add(&srep[tid],      red[tid] + red[tid+64] + red[tid+128] + red[tid+192]);
    __syncthreads();
    red[tid] = pq; __syncthreads();
    if (tid < 64) fatomic_add(&srep[64 + tid], red[tid] + red[tid+64] + red[tid+128] + red[tid+192]);
}

// ---------------- finish h: BN affine + relu + residual (in place) -----------
__global__ __launch_bounds__(256) void k_node_out(
    const float* __restrict__ h,
    const float* __restrict__ scale, const float* __restrict__ shift,
    float* __restrict__ out, long long total)
{
    long long idx = (long long)blockIdx.x * 256 + threadIdx.x;
    long long stride = (long long)gridDim.x * 256;
    for (; idx < total; idx += stride) {
        int d = (int)(idx & (DD - 1));
        float v = out[idx] * scale[d] + shift[d];
        out[idx] = fmaxf(v, 0.f) + h[idx];
    }
}

extern "C" void kernel_launch(void* const* d_in, const int* in_sizes, int n_in,
                              void* d_out, int out_size, void* d_ws, size_t ws_size,
                              hipStream_t stream)
{
    const float* h    = (const float*)d_in[0];
    const float* e    = (const float*)d_in[1];
    const int*   src  = (const int*)d_in[2];
    const int*   dst  = (const int*)d_in[3];
    const float* A1w  = (const float*)d_in[4];
    const float* A1b  = (const float*)d_in[5];
    const float* A2w  = (const float*)d_in[6];
    const float* A2b  = (const float*)d_in[7];
    const float* A3w  = (const float*)d_in[8];
    const float* A3b  = (const float*)d_in[9];
    const float* B1w  = (const float*)d_in[10];
    const float* B1b  = (const float*)d_in[11];
    const float* B2w  = (const float*)d_in[12];
    const float* B2b  = (const float*)d_in[13];
    const float* B3w  = (const float*)d_in[14];
    const float* B3b  = (const float*)d_in[15];
    const float* bnhg = (const float*)d_in[16];
    const float* bnhb = (const float*)d_in[17];
    const float* bneg = (const float*)d_in[18];
    const float* bneb = (const float*)d_in[19];

    const int N = in_sizes[0] / DD;
    const int E = in_sizes[1] / DD;
    const size_t ND = (size_t)N * DD;
    const size_t ED = (size_t)E * DD;

    float* ws    = (float*)d_ws;
    float* A1h   = ws + 0 * ND;
    float* A2h   = ws + 1 * ND;
    float* A3h   = ws + 2 * ND;
    float* B1h   = ws + 3 * ND;
    float* B2h   = ws + 4 * ND;
    float* agg_f = ws + 5 * ND;
    float* agg_b = ws + 6 * ND;
    float* stats = ws + 7 * ND;
    // stats layout (floats):
    //   [0 .. 8192)      e-stat replicas: NREP x (sum64 | sumsq64)
    //   [8192 .. 16384)  h-stat replicas
    //   [16384..16448) e_scale  [16448..16512) e_shift
    //   [16512..16576) h_scale  [16576..16640) h_shift
    const size_t STATS_F = 16640;
    float* e_rep   = stats;
    float* h_rep   = stats + 8192;
    float* e_scale = stats + 16384;
    float* e_shift = stats + 16448;
    float* h_scale = stats + 16512;
    float* h_shift = stats + 16576;

    const int nscan   = 2 * N;
    const int nb_scan = (nscan + 1023) / 1024;
    const size_t int_count = (size_t)(4 * N + 1 + nb_scan) + 4 * (size_t)E + 2;
    const size_t need_big  = (7 * ND + STATS_F + ED) * sizeof(float) + int_count * sizeof(int);
    const bool   ws_big    = ws_size >= need_big;

    uint32_t* pk_ws = (uint32_t*)(stats + STATS_F);     // ED uint32 (only if ws_big)
    int*      ibase = (int*)(ws_big ? (float*)(pk_ws + ED) : (stats + STATS_F));
    int*  cur2   = ibase;                     // 2N (counts -> cursors)
    int*  row2   = ibase + 2 * N;             // 2N+1
    int*  part   = ibase + 4 * N + 1;         // nb_scan
    int2* pair2  = (int2*)(((uintptr_t)(part + nb_scan) + 7) & ~(uintptr_t)7); // 2E pairs

    float* out  = (float*)d_out;
    float* gbuf = out + ND;   // out e-region

    hipMemsetAsync(stats, 0, STATS_F * sizeof(float), stream);
    hipMemsetAsync(cur2, 0, 2 * (size_t)N * sizeof(int), stream);

    dim3 blk(256);
    int nb_e  = (E + 255) / 256;
    int nt_n  = (N + TILE - 1) / TILE;
    int nt_e  = (E + TILE - 1) / TILE;

    k_tile_linear<<<dim3(nt_n, 5), blk, 0, stream>>>(h, N,
        A1w, A1b, A1h,  A2w, A2b, A2h,  A3w, A3b, A3h,
        B1w, B1b, B1h,  B2w, B2b, B2h);

    // CSR build (fwd+bwd merged), hierarchical scan
    k_count<<<nb_e, blk, 0, stream>>>(src, dst, cur2, N, E);
    k_scan_blk<<<nb_scan, 1024, 0, stream>>>(cur2, row2, part, nscan);
    k_scan_carry<<<1, 1024, 0, stream>>>(part, nb_scan);
    k_scan_add<<<nb_scan, 1024, 0, stream>>>(row2, cur2, part, nscan, 2 * E);
    k_place<<<nb_e, blk, 0, stream>>>(src, dst, cur2, pair2, N, E);

    // fused edge gate + BN-e stats + packed (g,e) + e passthrough
    // ws_big: packed -> workspace, e copy -> out e-region (no memcpy at all)
    // !ws_big: packed -> out e-region, memcpy e over it after gather
    uint32_t* pkmem = ws_big ? pk_ws : (uint32_t*)gbuf;
    k_edge_fused<<<nt_e, blk, 0, stream>>>(e, src, dst, B1h, B2h, B3w, B3b,
                                           pkmem, ws_big ? (float4*)gbuf : nullptr,
                                           e_rep, E);
    k_bn_final<<<1, 64, 0, stream>>>(e_rep, 1.0f / (float)E, bneg, bneb,
                                     e_scale, e_shift);

    // merged gather with inline sigma recompute from packed rows
    int nb_g2 = (int)(((size_t)2 * N * 64 + 255) / 256);
    k_gather2<<<nb_g2, blk, 0, stream>>>(pkmem, pair2, row2, A2h, A3h,
                                         e_scale, e_shift, agg_f, agg_b, N);

    k_node_pre<<<1024, blk, 0, stream>>>(A1h, agg_f, agg_b,
        out, h_rep, (long long)ND);
    k_bn_final<<<1, 64, 0, stream>>>(h_rep, 1.0f / (float)N, bnhg, bnhb,
                                     h_scale, h_shift);
    k_node_out<<<1024, blk, 0, stream>>>(h, h_scale, h_shift,
                                         out, (long long)ND);

    if (!ws_big) {
        hipMemcpyAsync(gbuf, e, ED * sizeof(float), hipMemcpyDeviceToDevice, stream);
    }
}

// Round 12
// 615.096 us; speedup vs baseline: 2.7719x; 1.0225x over previous
//
#include <hip/hip_runtime.h>
#include <cstdint>
#include <cstddef>

#define DD 64
#define TILE 64
#define LSTR 65   // padded f32 LDS row stride (k_tile_linear)
#define EBS 66    // bf16 LDS row stride in u16 (33 u32): 2-way bank alias max
#define NREP 64   // stat-replica count: spreads block atomics over 64*128 floats
constexpr float BN_EPS  = 1e-5f;
constexpr float DEG_EPS = 1e-6f;

__device__ __forceinline__ float fatomic_add(float* p, float v) {
    return unsafeAtomicAdd(p, v);   // hardware global_atomic_add_f32
}

__device__ __forceinline__ uint32_t bf16r(float x) {   // round-to-nearest-even bf16
    uint32_t u = __float_as_uint(x);
    return (u + 0x7fffu + ((u >> 16) & 1u)) >> 16;
}
__device__ __forceinline__ uint32_t pack2(float lo, float hi) {
    return (bf16r(hi) << 16) | bf16r(lo);
}

// =============== tiled linear: o = x @ W^T + b, single LDS buffer ============
__global__ __launch_bounds__(256) void k_tile_linear(
    const float* __restrict__ x, int R,
    const float* __restrict__ w0, const float* __restrict__ b0, float* __restrict__ o0,
    const float* __restrict__ w1, const float* __restrict__ b1, float* __restrict__ o1,
    const float* __restrict__ w2, const float* __restrict__ b2, float* __restrict__ o2,
    const float* __restrict__ w3, const float* __restrict__ b3, float* __restrict__ o3,
    const float* __restrict__ w4, const float* __restrict__ b4, float* __restrict__ o4)
{
    const float* w; const float* b; float* o;
    switch (blockIdx.y) {
        case 0:  w = w0; b = b0; o = o0; break;
        case 1:  w = w1; b = b1; o = o1; break;
        case 2:  w = w2; b = b2; o = o2; break;
        case 3:  w = w3; b = b3; o = o3; break;
        default: w = w4; b = b4; o = o4; break;
    }
    __shared__ float ldsE[TILE * LSTR];
    int tid  = threadIdx.x;
    int lane = tid & 63;
    int base = blockIdx.x * TILE;
    int rem  = R - base; if (rem > TILE) rem = TILE;
    int qu   = __builtin_amdgcn_readfirstlane(tid >> 6);   // wave id 0..3, SGPR

    const float4* x4 = reinterpret_cast<const float4*>(x + (size_t)base * DD);
    #pragma unroll
    for (int j = 0; j < 4; ++j) {
        int f4 = j * 256 + tid;          // float4 index in tile
        int r  = f4 >> 4, c = f4 & 15;
        if (r < rem) {
            float4 v = x4[f4];
            ldsE[r * LSTR + c * 4 + 0] = v.x;
            ldsE[r * LSTR + c * 4 + 1] = v.y;
            ldsE[r * LSTR + c * 4 + 2] = v.z;
            ldsE[r * LSTR + c * 4 + 3] = v.w;
        }
    }
    __syncthreads();

    float acc[16];
    #pragma unroll
    for (int i = 0; i < 16; ++i) acc[i] = b[qu * 16 + i];
    #pragma unroll 4
    for (int k = 0; k < 64; ++k) {
        float ev = ldsE[lane * LSTR + k];
        const float* wq = w + (size_t)(qu * 16) * DD + k;
        #pragma unroll
        for (int i = 0; i < 16; ++i)
            acc[i] = fmaf(ev, wq[(size_t)i * DD], acc[i]);
    }
    __syncthreads();   // all reads of ldsE done -> safe to overwrite
    #pragma unroll
    for (int i = 0; i < 16; ++i)
        ldsE[lane * LSTR + qu * 16 + i] = acc[i];
    __syncthreads();

    float4* outp4 = reinterpret_cast<float4*>(o + (size_t)base * DD);
    #pragma unroll
    for (int j = 0; j < 4; ++j) {
        int f4 = j * 256 + tid;
        int r  = f4 >> 4, c = f4 & 15;
        if (r < rem) {
            float4 v;
            v.x = ldsE[r * LSTR + c * 4 + 0];
            v.y = ldsE[r * LSTR + c * 4 + 1];
            v.z = ldsE[r * LSTR + c * 4 + 2];
            v.w = ldsE[r * LSTR + c * 4 + 3];
            outp4[f4] = v;
        }
    }
}

// =============== fused edge gate (bf16 LDS) ==================================
// g = B3 e + b3 + B1h[src] + B2h[dst]; bf16-e and bf16-g0 both live in LDS so
// phase 3 touches NO global reads beyond the prefetched B-rows.
__global__ __launch_bounds__(256) void k_edge_fused(
    const float* __restrict__ e,
    const int* __restrict__ src, const int* __restrict__ dst,
    const float* __restrict__ B1h, const float* __restrict__ B2h,
    const float* __restrict__ w, const float* __restrict__ b,
    uint32_t* __restrict__ packed, float4* ecopy, float* __restrict__ sums, int E)
{
    __shared__ uint16_t ldsEb[TILE * EBS];   // bf16 e   (8448 B)
    __shared__ uint16_t ldsGb[TILE * EBS];   // bf16 g0  (8448 B)
    __shared__ float red[256];
    uint32_t* eb32 = reinterpret_cast<uint32_t*>(ldsEb);
    uint32_t* gb32 = reinterpret_cast<uint32_t*>(ldsGb);
    int tid  = threadIdx.x;
    int lane = tid & 63;
    int base = blockIdx.x * TILE;
    int rem  = E - base; if (rem > TILE) rem = TILE;
    int qu   = __builtin_amdgcn_readfirstlane(tid >> 6);

    // phase 0a: read e tile into regs
    const float4* e4 = reinterpret_cast<const float4*>(e + (size_t)base * DD);
    float4 ev[4];
    #pragma unroll
    for (int j = 0; j < 4; ++j) {
        int f4 = j * 256 + tid;
        int r  = f4 >> 4;
        ev[j] = (r < rem) ? e4[f4] : float4{0.f, 0.f, 0.f, 0.f};
    }

    // phase 0b: issue this wave's 32 B-row loads (latency hides under GEMV)
    float b1r[16], b2r[16];
    #pragma unroll
    for (int it = 0; it < 16; ++it) {
        int el = qu * 16 + it;               // wave-uniform
        if (el < rem) {
            int ee = base + el;
            int s = src[ee], t = dst[ee];    // scalar loads (uniform address)
            b1r[it] = B1h[(size_t)s * DD + lane];
            b2r[it] = B2h[(size_t)t * DD + lane];
        } else { b1r[it] = 0.f; b2r[it] = 0.f; }
    }

    // phase 1: bf16-pack e tile to LDS (+ fp32 e passthrough from regs)
    #pragma unroll
    for (int j = 0; j < 4; ++j) {
        int f4 = j * 256 + tid;
        int r  = f4 >> 4, c = f4 & 15;
        if (r < rem) {
            eb32[r * 33 + 2 * c + 0] = pack2(ev[j].x, ev[j].y);
            eb32[r * 33 + 2 * c + 1] = pack2(ev[j].z, ev[j].w);
            if (ecopy) ecopy[(size_t)base * 16 + f4] = ev[j];
        }
    }
    __syncthreads();

    // phase 2: GEMV B3 * e_row + b3 (bf16 e pairs from LDS, uniform W s_loads)
    float acc[16];
    #pragma unroll
    for (int i = 0; i < 16; ++i) acc[i] = b[qu * 16 + i];
    #pragma unroll 4
    for (int k2 = 0; k2 < 32; ++k2) {
        uint32_t ee2 = eb32[lane * 33 + k2];
        float f0 = __uint_as_float(ee2 << 16);
        float f1 = __uint_as_float(ee2 & 0xffff0000u);
        const float* wq = w + (size_t)(qu * 16) * DD + 2 * k2;
        #pragma unroll
        for (int i = 0; i < 16; ++i) {
            acc[i] = fmaf(f0, wq[(size_t)i * DD + 0], acc[i]);
            acc[i] = fmaf(f1, wq[(size_t)i * DD + 1], acc[i]);
        }
    }
    // write bf16 g0 (own array -> no barrier needed before the write)
    #pragma unroll
    for (int i2 = 0; i2 < 8; ++i2)
        gb32[lane * 33 + qu * 8 + i2] = pack2(acc[2 * i2], acc[2 * i2 + 1]);
    __syncthreads();

    // phase 3: v = g0 + B1row + B2row (regs), stats, packed (g,e) write.
    float ps = 0.f, pq = 0.f;
    #pragma unroll
    for (int it = 0; it < 16; ++it) {
        int el = qu * 16 + it;
        if (el < rem) {
            int ee = base + el;
            uint32_t ebits = ldsEb[el * EBS + lane];
            uint32_t gbits = ldsGb[el * EBS + lane];
            float gv = __uint_as_float(gbits << 16);
            float v  = gv + b1r[it] + b2r[it];
            packed[(size_t)ee * DD + lane] = (ebits << 16) | bf16r(v);
            ps += v; pq += v * v;
        }
    }
    float* srep = sums + (size_t)(blockIdx.x & (NREP - 1)) * 128;
    red[tid] = ps; __syncthreads();
    if (tid < 64) fatomic_add(&srep[tid],      red[tid] + red[tid+64] + red[tid+128] + red[tid+192]);
    __syncthreads();
    red[tid] = pq; __syncthreads();
    if (tid < 64) fatomic_add(&srep[64 + tid], red[tid] + red[tid+64] + red[tid+128] + red[tid+192]);
}

// ---------------- fold replicated stats into scale/shift ---------------------
__global__ void k_bn_final(const float* __restrict__ reps, float inv_cnt,
                           const float* __restrict__ gamma, const float* __restrict__ beta,
                           float* __restrict__ scale, float* __restrict__ shift)
{
    int d = threadIdx.x;
    if (d >= DD) return;
    float s = 0.f, q = 0.f;
    #pragma unroll 8
    for (int r = 0; r < NREP; ++r) {
        s += reps[r * 128 + d];
        q += reps[r * 128 + 64 + d];
    }
    float mean = s * inv_cnt;
    float var  = fmaxf(q * inv_cnt - mean * mean, 0.f);
    float rs   = rsqrtf(var + BN_EPS);
    float sc   = gamma[d] * rs;
    scale[d] = sc;
    shift[d] = beta[d] - mean * sc;
}

// ---------------- CSR build ---------------------------------------------------
__global__ __launch_bounds__(256) void k_count(
    const int* __restrict__ src, const int* __restrict__ dst,
    int* __restrict__ cnt2, int N, int E)
{
    int ee = blockIdx.x * 256 + threadIdx.x;
    if (ee >= E) return;
    atomicAdd(&cnt2[dst[ee]], 1);        // fwd counts at [0,N)
    atomicAdd(&cnt2[N + src[ee]], 1);    // bwd counts at [N,2N)
}

// hierarchical exclusive scan: block-local -> carry -> add
__global__ __launch_bounds__(1024) void k_scan_blk(
    const int* __restrict__ cnt, int* __restrict__ row, int* __restrict__ part, int n)
{
    __shared__ int tmp[1024];
    int tid = threadIdx.x;
    int i   = blockIdx.x * 1024 + tid;
    int v   = (i < n) ? cnt[i] : 0;
    tmp[tid] = v; __syncthreads();
    for (int off = 1; off < 1024; off <<= 1) {
        int t = (tid >= off) ? tmp[tid - off] : 0;
        __syncthreads();
        tmp[tid] += t;
        __syncthreads();
    }
    if (i < n) row[i] = tmp[tid] - v;            // local exclusive
    if (tid == 1023) part[blockIdx.x] = tmp[1023];  // block total
}

__global__ __launch_bounds__(1024) void k_scan_carry(int* part, int nb)
{
    __shared__ int tmp[1024];
    int tid = threadIdx.x;
    int carry = 0;
    for (int base = 0; base < nb; base += 1024) {
        int i = base + tid;
        int v = (i < nb) ? part[i] : 0;
        tmp[tid] = v; __syncthreads();
        for (int off = 1; off < 1024; off <<= 1) {
            int t = (tid >= off) ? tmp[tid - off] : 0;
            __syncthreads();
            tmp[tid] += t;
            __syncthreads();
        }
        if (i < nb) part[i] = carry + tmp[tid] - v;
        carry += tmp[1023];
        __syncthreads();
    }
}

__global__ __launch_bounds__(1024) void k_scan_add(
    int* __restrict__ row, int* __restrict__ cur, const int* __restrict__ part,
    int n, int total)
{
    int i = blockIdx.x * 1024 + threadIdx.x;
    if (i < n) {
        int r = row[i] + part[blockIdx.x];
        row[i] = r; cur[i] = r;
    }
    if (i == 0) row[n] = total;
}

// place packed (eid, other-node) pairs
__global__ __launch_bounds__(256) void k_place(
    const int* __restrict__ src, const int* __restrict__ dst,
    int* __restrict__ cur2, int2* __restrict__ pair2, int N, int E)
{
    int ee = blockIdx.x * 256 + threadIdx.x;
    if (ee >= E) return;
    int s = src[ee], t = dst[ee];
    int pf = atomicAdd(&cur2[t], 1);
    pair2[pf] = make_int2(ee, s);
    int pb = atomicAdd(&cur2[N + s], 1);
    pair2[pb] = make_int2(ee, t);        // bwd slots live at [E, 2E)
}

// ---------------- merged gather, sigma recomputed from packed bf16 (g,e) -----
__global__ __launch_bounds__(256) void k_gather2(
    const uint32_t* __restrict__ packed,
    const int2* __restrict__ pair2, const int* __restrict__ row2,
    const float* __restrict__ A2h, const float* __restrict__ A3h,
    const float* __restrict__ e_scale, const float* __restrict__ e_shift,
    float* __restrict__ agg_f, float* __restrict__ agg_b, int N)
{
    int gw = (blockIdx.x * 256 + threadIdx.x) >> 6;
    if (gw >= 2 * N) return;
    int lane = threadIdx.x & 63;
    bool bwd = gw >= N;
    int wid  = bwd ? gw - N : gw;
    const float4* Ah4 = reinterpret_cast<const float4*>(bwd ? A3h : A2h);
    float* agg        = bwd ? agg_b : agg_f;
    int beg = row2[gw], end = row2[gw + 1];   // fwd rows [0,N), bwd rows [N,2N)
    int q  = lane >> 4;      // edge slot 0..3
    int dj = lane & 15;      // float4 column slot
    float4 sc = reinterpret_cast<const float4*>(e_scale)[dj];
    float4 sh = reinterpret_cast<const float4*>(e_shift)[dj];
    float4 num = {0.f, 0.f, 0.f, 0.f};
    float4 den = {0.f, 0.f, 0.f, 0.f};
    const uint4* p4 = reinterpret_cast<const uint4*>(packed);
    for (int k = beg + q; k < end; k += 8) {
        int  k2   = k + 4;
        bool hasb = k2 < end;
        int2 pa = pair2[k];
        int2 pb = hasb ? pair2[k2] : pa;
        uint4  wa = p4[(size_t)pa.x * 16 + dj];
        float4 aa = Ah4[(size_t)pa.y * 16 + dj];
        uint4  wb = p4[(size_t)pb.x * 16 + dj];
        float4 ab = Ah4[(size_t)pb.y * 16 + dj];
        float4 sa;
        {
            float gx = __uint_as_float(wa.x << 16), ex = __uint_as_float(wa.x & 0xffff0000u);
            float gy = __uint_as_float(wa.y << 16), ey = __uint_as_float(wa.y & 0xffff0000u);
            float gz = __uint_as_float(wa.z << 16), ez = __uint_as_float(wa.z & 0xffff0000u);
            float gw4 = __uint_as_float(wa.w << 16), ew = __uint_as_float(wa.w & 0xffff0000u);
            sa.x = 1.f / (1.f + __expf(-(fmaxf(gx * sc.x + sh.x, 0.f) + ex)));
            sa.y = 1.f / (1.f + __expf(-(fmaxf(gy * sc.y + sh.y, 0.f) + ey)));
            sa.z = 1.f / (1.f + __expf(-(fmaxf(gz * sc.z + sh.z, 0.f) + ez)));
            sa.w = 1.f / (1.f + __expf(-(fmaxf(gw4 * sc.w + sh.w, 0.f) + ew)));
        }
        num.x += sa.x * aa.x; num.y += sa.y * aa.y;
        num.z += sa.z * aa.z; num.w += sa.w * aa.w;
        den.x += sa.x; den.y += sa.y; den.z += sa.z; den.w += sa.w;
        if (hasb) {
            float4 sb;
            float gx = __uint_as_float(wb.x << 16), ex = __uint_as_float(wb.x & 0xffff0000u);
            float gy = __uint_as_float(wb.y << 16), ey = __uint_as_float(wb.y & 0xffff0000u);
            float gz = __uint_as_float(wb.z << 16), ez = __uint_as_float(wb.z & 0xffff0000u);
            float gw4 = __uint_as_float(wb.w << 16), ew = __uint_as_float(wb.w & 0xffff0000u);
            sb.x = 1.f / (1.f + __expf(-(fmaxf(gx * sc.x + sh.x, 0.f) + ex)));
            sb.y = 1.f / (1.f + __expf(-(fmaxf(gy * sc.y + sh.y, 0.f) + ey)));
            sb.z = 1.f / (1.f + __expf(-(fmaxf(gz * sc.z + sh.z, 0.f) + ez)));
            sb.w = 1.f / (1.f + __expf(-(fmaxf(gw4 * sc.w + sh.w, 0.f) + ew)));
            num.x += sb.x * ab.x; num.y += sb.y * ab.y;
            num.z += sb.z * ab.z; num.w += sb.w * ab.w;
            den.x += sb.x; den.y += sb.y; den.z += sb.z; den.w += sb.w;
        }
    }
    #pragma unroll
    for (int off = 16; off <= 32; off <<= 1) {
        num.x += __shfl_xor(num.x, off); num.y += __shfl_xor(num.y, off);
        num.z += __shfl_xor(num.z, off); num.w += __shfl_xor(num.w, off);
        den.x += __shfl_xor(den.x, off); den.y += __shfl_xor(den.y, off);
        den.z += __shfl_xor(den.z, off); den.w += __shfl_xor(den.w, off);
    }
    if (q == 0) {
        float4 res;
        res.x = num.x / (den.x + DEG_EPS);
        res.y = num.y / (den.y + DEG_EPS);
        res.z = num.z / (den.z + DEG_EPS);
        res.w = num.w / (den.w + DEG_EPS);
        reinterpret_cast<float4*>(agg)[(size_t)wid * 16 + dj] = res;
    }
}

// ---------------- h_pre = A1h + agg_f + agg_b, + replicated column stats -----
__global__ __launch_bounds__(256) void k_node_pre(
    const float* __restrict__ A1h,
    const float* __restrict__ agg_f, const float* __restrict__ agg_b,
    float* __restrict__ hpre, float* __restrict__ sums, long long total)
{
    int tid = threadIdx.x;
    long long idx = (long long)blockIdx.x * 256 + tid;
    long long stride = (long long)gridDim.x * 256;
    float ps = 0.f, pq = 0.f;
    for (; idx < total; idx += stride) {
        float v = A1h[idx] + agg_f[idx] + agg_b[idx];
        hpre[idx] = v;
        ps += v; pq += v * v;
    }
    float* srep = sums + (size_t)(blockIdx.x & (NREP - 1)) * 128;
    __shared__ float red[256];
    red[tid] = ps; __syncthreads();
    if (tid < 64) fatomic_add(&srep[tid],      red[tid] + red[tid+64] + red[tid+128] + red[tid+192]);
    __syncthreads();
    red[tid] = pq; __syncthreads();
    if (tid < 64) fatomic_add(&srep[64 + tid], red[tid] + red[tid+64] + red[tid+128] + red[tid+192]);
}

// ---------------- finish h: BN affine + relu + residual (in place) -----------
__global__ __launch_bounds__(256) void k_node_out(
    const float* __restrict__ h,
    const float* __restrict__ scale, const float* __restrict__ shift,
    float* __restrict__ out, long long total)
{
    long long idx = (long long)blockIdx.x * 256 + threadIdx.x;
    long long stride = (long long)gridDim.x * 256;
    for (; idx < total; idx += stride) {
        int d = (int)(idx & (DD - 1));
        float v = out[idx] * scale[d] + shift[d];
        out[idx] = fmaxf(v, 0.f) + h[idx];
    }
}

extern "C" void kernel_launch(void* const* d_in, const int* in_sizes, int n_in,
                              void* d_out, int out_size, void* d_ws, size_t ws_size,
                              hipStream_t stream)
{
    const float* h    = (const float*)d_in[0];
    const float* e    = (const float*)d_in[1];
    const int*   src  = (const int*)d_in[2];
    const int*   dst  = (const int*)d_in[3];
    const float* A1w  = (const float*)d_in[4];
    const float* A1b  = (const float*)d_in[5];
    const float* A2w  = (const float*)d_in[6];
    const float* A2b  = (const float*)d_in[7];
    const float* A3w  = (const float*)d_in[8];
    const float* A3b  = (const float*)d_in[9];
    const float* B1w  = (const float*)d_in[10];
    const float* B1b  = (const float*)d_in[11];
    const float* B2w  = (const float*)d_in[12];
    const float* B2b  = (const float*)d_in[13];
    const float* B3w  = (const float*)d_in[14];
    const float* B3b  = (const float*)d_in[15];
    const float* bnhg = (const float*)d_in[16];
    const float* bnhb = (const float*)d_in[17];
    const float* bneg = (const float*)d_in[18];
    const float* bneb = (const float*)d_in[19];

    const int N = in_sizes[0] / DD;
    const int E = in_sizes[1] / DD;
    const size_t ND = (size_t)N * DD;
    const size_t ED = (size_t)E * DD;

    float* ws    = (float*)d_ws;
    float* A1h   = ws + 0 * ND;
    float* A2h   = ws + 1 * ND;
    float* A3h   = ws + 2 * ND;
    float* B1h   = ws + 3 * ND;
    float* B2h   = ws + 4 * ND;
    float* agg_f = ws + 5 * ND;
    float* agg_b = ws + 6 * ND;
    float* stats = ws + 7 * ND;
    const size_t STATS_F = 16640;
    float* e_rep   = stats;
    float* h_rep   = stats + 8192;
    float* e_scale = stats + 16384;
    float* e_shift = stats + 16448;
    float* h_scale = stats + 16512;
    float* h_shift = stats + 16576;

    const int nscan   = 2 * N;
    const int nb_scan = (nscan + 1023) / 1024;
    const size_t int_count = (size_t)(4 * N + 1 + nb_scan) + 4 * (size_t)E + 2;
    const size_t need_big  = (7 * ND + STATS_F + ED) * sizeof(float) + int_count * sizeof(int);
    const bool   ws_big    = ws_size >= need_big;

    uint32_t* pk_ws = (uint32_t*)(stats + STATS_F);     // ED uint32 (only if ws_big)
    int*      ibase = (int*)(ws_big ? (float*)(pk_ws + ED) : (stats + STATS_F));
    int*  cur2   = ibase;                     // 2N (counts -> cursors)
    int*  row2   = ibase + 2 * N;             // 2N+1
    int*  part   = ibase + 4 * N + 1;         // nb_scan
    int2* pair2  = (int2*)(((uintptr_t)(part + nb_scan) + 7) & ~(uintptr_t)7); // 2E pairs

    float* out  = (float*)d_out;
    float* gbuf = out + ND;   // out e-region

    hipMemsetAsync(stats, 0, STATS_F * sizeof(float), stream);
    hipMemsetAsync(cur2, 0, 2 * (size_t)N * sizeof(int), stream);

    dim3 blk(256);
    int nb_e  = (E + 255) / 256;
    int nt_n  = (N + TILE - 1) / TILE;
    int nt_e  = (E + TILE - 1) / TILE;

    k_tile_linear<<<dim3(nt_n, 5), blk, 0, stream>>>(h, N,
        A1w, A1b, A1h,  A2w, A2b, A2h,  A3w, A3b, A3h,
        B1w, B1b, B1h,  B2w, B2b, B2h);

    // CSR build (fwd+bwd merged), hierarchical scan
    k_count<<<nb_e, blk, 0, stream>>>(src, dst, cur2, N, E);
    k_scan_blk<<<nb_scan, 1024, 0, stream>>>(cur2, row2, part, nscan);
    k_scan_carry<<<1, 1024, 0, stream>>>(part, nb_scan);
    k_scan_add<<<nb_scan, 1024, 0, stream>>>(row2, cur2, part, nscan, 2 * E);
    k_place<<<nb_e, blk, 0, stream>>>(src, dst, cur2, pair2, N, E);

    // fused edge gate + BN-e stats + packed (g,e) + e passthrough
    uint32_t* pkmem = ws_big ? pk_ws : (uint32_t*)gbuf;
    k_edge_fused<<<nt_e, blk, 0, stream>>>(e, src, dst, B1h, B2h, B3w, B3b,
                                           pkmem, ws_big ? (float4*)gbuf : nullptr,
                                           e_rep, E);
    k_bn_final<<<1, 64, 0, stream>>>(e_rep, 1.0f / (float)E, bneg, bneb,
                                     e_scale, e_shift);

    // merged gather with inline sigma recompute from packed rows
    int nb_g2 = (int)(((size_t)2 * N * 64 + 255) / 256);
    k_gather2<<<nb_g2, blk, 0, stream>>>(pkmem, pair2, row2, A2h, A3h,
                                         e_scale, e_shift, agg_f, agg_b, N);

    k_node_pre<<<1024, blk, 0, stream>>>(A1h, agg_f, agg_b,
        out, h_rep, (long long)ND);
    k_bn_final<<<1, 64, 0, stream>>>(h_rep, 1.0f / (float)N, bnhg, bnhb,
                                     h_scale, h_shift);
    k_node_out<<<1024, blk, 0, stream>>>(h, h_scale, h_shift,
                                         out, (long long)ND);

    if (!ws_big) {
        hipMemcpyAsync(gbuf, e, ED * sizeof(float), hipMemcpyDeviceToDevice, stream);
    }
}

// Round 13
// 568.152 us; speedup vs baseline: 3.0009x; 1.0826x over previous
//
#include <hip/hip_runtime.h>
#include <cstdint>
#include <cstddef>

#define DD 64
#define TILE 64
#define LSTR 65   // padded f32 LDS row stride (k_tile_linear)
#define ESTR 72   // bf16 LDS row stride (u16 units): 144B rows, 16B-aligned frags
#define NREP 64   // stat-replica count: spreads block atomics over 64*128 floats
constexpr float BN_EPS  = 1e-5f;
constexpr float DEG_EPS = 1e-6f;

typedef __attribute__((ext_vector_type(8))) short bf16x8;
typedef __attribute__((ext_vector_type(4))) float f32x4;
typedef __attribute__((ext_vector_type(4))) unsigned int u32x4;

__device__ __forceinline__ float fatomic_add(float* p, float v) {
    return unsafeAtomicAdd(p, v);   // hardware global_atomic_add_f32
}

__device__ __forceinline__ uint32_t bf16r(float x) {   // round-to-nearest-even bf16
    uint32_t u = __float_as_uint(x);
    return (u + 0x7fffu + ((u >> 16) & 1u)) >> 16;
}
__device__ __forceinline__ uint32_t pack2(float lo, float hi) {
    return (bf16r(hi) << 16) | bf16r(lo);
}

// =============== tiled linear: o = x @ W^T + b, single LDS buffer ============
__global__ __launch_bounds__(256) void k_tile_linear(
    const float* __restrict__ x, int R,
    const float* __restrict__ w0, const float* __restrict__ b0, float* __restrict__ o0,
    const float* __restrict__ w1, const float* __restrict__ b1, float* __restrict__ o1,
    const float* __restrict__ w2, const float* __restrict__ b2, float* __restrict__ o2,
    const float* __restrict__ w3, const float* __restrict__ b3, float* __restrict__ o3,
    const float* __restrict__ w4, const float* __restrict__ b4, float* __restrict__ o4)
{
    const float* w; const float* b; float* o;
    switch (blockIdx.y) {
        case 0:  w = w0; b = b0; o = o0; break;
        case 1:  w = w1; b = b1; o = o1; break;
        case 2:  w = w2; b = b2; o = o2; break;
        case 3:  w = w3; b = b3; o = o3; break;
        default: w = w4; b = b4; o = o4; break;
    }
    __shared__ float ldsE[TILE * LSTR];
    int tid  = threadIdx.x;
    int lane = tid & 63;
    int base = blockIdx.x * TILE;
    int rem  = R - base; if (rem > TILE) rem = TILE;
    int qu   = __builtin_amdgcn_readfirstlane(tid >> 6);   // wave id 0..3, SGPR

    const float4* x4 = reinterpret_cast<const float4*>(x + (size_t)base * DD);
    #pragma unroll
    for (int j = 0; j < 4; ++j) {
        int f4 = j * 256 + tid;          // float4 index in tile
        int r  = f4 >> 4, c = f4 & 15;
        if (r < rem) {
            float4 v = x4[f4];
            ldsE[r * LSTR + c * 4 + 0] = v.x;
            ldsE[r * LSTR + c * 4 + 1] = v.y;
            ldsE[r * LSTR + c * 4 + 2] = v.z;
            ldsE[r * LSTR + c * 4 + 3] = v.w;
        }
    }
    __syncthreads();

    float acc[16];
    #pragma unroll
    for (int i = 0; i < 16; ++i) acc[i] = b[qu * 16 + i];
    #pragma unroll 4
    for (int k = 0; k < 64; ++k) {
        float ev = ldsE[lane * LSTR + k];
        const float* wq = w + (size_t)(qu * 16) * DD + k;
        #pragma unroll
        for (int i = 0; i < 16; ++i)
            acc[i] = fmaf(ev, wq[(size_t)i * DD], acc[i]);
    }
    __syncthreads();   // all reads of ldsE done -> safe to overwrite
    #pragma unroll
    for (int i = 0; i < 16; ++i)
        ldsE[lane * LSTR + qu * 16 + i] = acc[i];
    __syncthreads();

    float4* outp4 = reinterpret_cast<float4*>(o + (size_t)base * DD);
    #pragma unroll
    for (int j = 0; j < 4; ++j) {
        int f4 = j * 256 + tid;
        int r  = f4 >> 4, c = f4 & 15;
        if (r < rem) {
            float4 v;
            v.x = ldsE[r * LSTR + c * 4 + 0];
            v.y = ldsE[r * LSTR + c * 4 + 1];
            v.z = ldsE[r * LSTR + c * 4 + 2];
            v.w = ldsE[r * LSTR + c * 4 + 3];
            outp4[f4] = v;
        }
    }
}

// =============== fused edge gate (MFMA GEMV) =================================
// g = B3 e + b3 + B1h[src] + B2h[dst]. The e@B3^T GEMV runs on the matrix pipe
// (16x16x32 bf16 MFMA); bf16-e and bf16-g0 live in LDS; phase 3 is pure adds.
__global__ __launch_bounds__(256) void k_edge_fused(
    const float* __restrict__ e,
    const int* __restrict__ src, const int* __restrict__ dst,
    const float* __restrict__ B1h, const float* __restrict__ B2h,
    const float* __restrict__ w, const float* __restrict__ b,
    uint32_t* __restrict__ packed, float4* ecopy, float* __restrict__ sums, int E)
{
    __shared__ __align__(16) uint16_t ldsEb[TILE * ESTR];  // bf16 e   (9216 B)
    __shared__ __align__(16) uint16_t ldsBG[TILE * ESTR];  // bf16 B3 -> bf16 g0
    __shared__ float red[256];
    uint32_t* eb32 = reinterpret_cast<uint32_t*>(ldsEb);
    int tid  = threadIdx.x;
    int lane = tid & 63;
    int base = blockIdx.x * TILE;
    int rem  = E - base; if (rem > TILE) rem = TILE;
    int qu   = __builtin_amdgcn_readfirstlane(tid >> 6);

    // phase 0a: read e tile into regs
    const float4* e4 = reinterpret_cast<const float4*>(e + (size_t)base * DD);
    float4 ev[4];
    #pragma unroll
    for (int j = 0; j < 4; ++j) {
        int f4 = j * 256 + tid;
        int r  = f4 >> 4;
        ev[j] = (r < rem) ? e4[f4] : float4{0.f, 0.f, 0.f, 0.f};
    }

    // phase 0b: issue this wave's 32 B-row loads (latency hides under MFMA+TLP)
    float b1r[16], b2r[16];
    #pragma unroll
    for (int it = 0; it < 16; ++it) {
        int el = qu * 16 + it;               // wave-uniform
        if (el < rem) {
            int ee = base + el;
            int s = src[ee], t = dst[ee];    // scalar loads (uniform address)
            b1r[it] = B1h[(size_t)s * DD + lane];
            b2r[it] = B2h[(size_t)t * DD + lane];
        } else { b1r[it] = 0.f; b2r[it] = 0.f; }
    }

    // phase 1: bf16 e -> ldsEb, bf16 B3 -> ldsBG, fp32 e passthrough
    #pragma unroll
    for (int j = 0; j < 4; ++j) {
        int f4 = j * 256 + tid;
        int r  = f4 >> 4, c = f4 & 15;
        if (r < rem) {
            eb32[r * (ESTR / 2) + 2 * c + 0] = pack2(ev[j].x, ev[j].y);
            eb32[r * (ESTR / 2) + 2 * c + 1] = pack2(ev[j].z, ev[j].w);
            if (ecopy) ecopy[(size_t)base * 16 + f4] = ev[j];
        }
    }
    #pragma unroll
    for (int i = 0; i < 16; ++i) {
        int idx = i * 256 + tid;             // 0..4095, coalesced (L2-hot 16KB)
        int r = idx >> 6, c = idx & 63;
        ldsBG[r * ESTR + c] = (uint16_t)bf16r(w[idx]);
    }
    __syncthreads();

    // phase 2: MFMA  g0[16qu..16qu+16) x d[0..64) = e-slice @ B3^T
    // A-frag: row = lane&15 (edge), k = 8*(lane>>4)+j   (contiguous-k mapping)
    // B-frag: col = lane&15 (d),    k = 8*(lane>>4)+j   (B3 row-major [d][k])
    int kg   = lane >> 4;
    int lrow = lane & 15;
    f32x4 acc[4] = {{0,0,0,0},{0,0,0,0},{0,0,0,0},{0,0,0,0}};
    bf16x8 a0 = __builtin_bit_cast(bf16x8,
        *(const u32x4*)&ldsEb[(qu * 16 + lrow) * ESTR + kg * 8]);        // k 0..31
    bf16x8 a1 = __builtin_bit_cast(bf16x8,
        *(const u32x4*)&ldsEb[(qu * 16 + lrow) * ESTR + 32 + kg * 8]);   // k 32..63
    #pragma unroll
    for (int t = 0; t < 4; ++t) {
        bf16x8 bb0 = __builtin_bit_cast(bf16x8,
            *(const u32x4*)&ldsBG[(t * 16 + lrow) * ESTR + kg * 8]);
        bf16x8 bb1 = __builtin_bit_cast(bf16x8,
            *(const u32x4*)&ldsBG[(t * 16 + lrow) * ESTR + 32 + kg * 8]);
        acc[t] = __builtin_amdgcn_mfma_f32_16x16x32_bf16(a0, bb0, acc[t], 0, 0, 0);
        acc[t] = __builtin_amdgcn_mfma_f32_16x16x32_bf16(a1, bb1, acc[t], 0, 0, 0);
    }
    __syncthreads();   // all waves done reading B3 -> ldsBG reusable for g0

    // D store (m89-verified C/D map: col = lane&15, row = (lane>>4)*4 + reg)
    #pragma unroll
    for (int t = 0; t < 4; ++t) {
        float bias = b[t * 16 + lrow];
        #pragma unroll
        for (int r = 0; r < 4; ++r) {
            ldsBG[(qu * 16 + kg * 4 + r) * ESTR + t * 16 + lrow] =
                (uint16_t)bf16r(acc[t][r] + bias);
        }
    }
    __syncthreads();

    // phase 3: v = g0 + B1row + B2row, stats, packed bf16 (g,e) write
    float ps = 0.f, pq = 0.f;
    #pragma unroll
    for (int it = 0; it < 16; ++it) {
        int el = qu * 16 + it;
        if (el < rem) {
            int ee = base + el;
            uint32_t ebits = ldsEb[el * ESTR + lane];
            uint32_t gbits = ldsBG[el * ESTR + lane];
            float gv = __uint_as_float(gbits << 16);
            float v  = gv + b1r[it] + b2r[it];
            packed[(size_t)ee * DD + lane] = (ebits << 16) | bf16r(v);
            ps += v; pq += v * v;
        }
    }
    float* srep = sums + (size_t)(blockIdx.x & (NREP - 1)) * 128;
    red[tid] = ps; __syncthreads();
    if (tid < 64) fatomic_add(&srep[tid],      red[tid] + red[tid+64] + red[tid+128] + red[tid+192]);
    __syncthreads();
    red[tid] = pq; __syncthreads();
    if (tid < 64) fatomic_add(&srep[64 + tid], red[tid] + red[tid+64] + red[tid+128] + red[tid+192]);
}

// ---------------- fold replicated stats into scale/shift ---------------------
__global__ void k_bn_final(const float* __restrict__ reps, float inv_cnt,
                           const float* __restrict__ gamma, const float* __restrict__ beta,
                           float* __restrict__ scale, float* __restrict__ shift)
{
    int d = threadIdx.x;
    if (d >= DD) return;
    float s = 0.f, q = 0.f;
    #pragma unroll 8
    for (int r = 0; r < NREP; ++r) {
        s += reps[r * 128 + d];
        q += reps[r * 128 + 64 + d];
    }
    float mean = s * inv_cnt;
    float var  = fmaxf(q * inv_cnt - mean * mean, 0.f);
    float rs   = rsqrtf(var + BN_EPS);
    float sc   = gamma[d] * rs;
    scale[d] = sc;
    shift[d] = beta[d] - mean * sc;
}

// ---------------- CSR build ---------------------------------------------------
__global__ __launch_bounds__(256) void k_count(
    const int* __restrict__ src, const int* __restrict__ dst,
    int* __restrict__ cnt2, int N, int E)
{
    int ee = blockIdx.x * 256 + threadIdx.x;
    if (ee >= E) return;
    atomicAdd(&cnt2[dst[ee]], 1);        // fwd counts at [0,N)
    atomicAdd(&cnt2[N + src[ee]], 1);    // bwd counts at [N,2N)
}

// hierarchical exclusive scan: block-local -> carry -> add
__global__ __launch_bounds__(1024) void k_scan_blk(
    const int* __restrict__ cnt, int* __restrict__ row, int* __restrict__ part, int n)
{
    __shared__ int tmp[1024];
    int tid = threadIdx.x;
    int i   = blockIdx.x * 1024 + tid;
    int v   = (i < n) ? cnt[i] : 0;
    tmp[tid] = v; __syncthreads();
    for (int off = 1; off < 1024; off <<= 1) {
        int t = (tid >= off) ? tmp[tid - off] : 0;
        __syncthreads();
        tmp[tid] += t;
        __syncthreads();
    }
    if (i < n) row[i] = tmp[tid] - v;            // local exclusive
    if (tid == 1023) part[blockIdx.x] = tmp[1023];  // block total
}

__global__ __launch_bounds__(1024) void k_scan_carry(int* part, int nb)
{
    __shared__ int tmp[1024];
    int tid = threadIdx.x;
    int carry = 0;
    for (int base = 0; base < nb; base += 1024) {
        int i = base + tid;
        int v = (i < nb) ? part[i] : 0;
        tmp[tid] = v; __syncthreads();
        for (int off = 1; off < 1024; off <<= 1) {
            int t = (tid >= off) ? tmp[tid - off] : 0;
            __syncthreads();
            tmp[tid] += t;
            __syncthreads();
        }
        if (i < nb) part[i] = carry + tmp[tid] - v;
        carry += tmp[1023];
        __syncthreads();
    }
}

__global__ __launch_bounds__(1024) void k_scan_add(
    int* __restrict__ row, int* __restrict__ cur, const int* __restrict__ part,
    int n, int total)
{
    int i = blockIdx.x * 1024 + threadIdx.x;
    if (i < n) {
        int r = row[i] + part[blockIdx.x];
        row[i] = r; cur[i] = r;
    }
    if (i == 0) row[n] = total;
}

// place packed (eid, other-node) pairs
__global__ __launch_bounds__(256) void k_place(
    const int* __restrict__ src, const int* __restrict__ dst,
    int* __restrict__ cur2, int2* __restrict__ pair2, int N, int E)
{
    int ee = blockIdx.x * 256 + threadIdx.x;
    if (ee >= E) return;
    int s = src[ee], t = dst[ee];
    int pf = atomicAdd(&cur2[t], 1);
    pair2[pf] = make_int2(ee, s);
    int pb = atomicAdd(&cur2[N + s], 1);
    pair2[pb] = make_int2(ee, t);        // bwd slots live at [E, 2E)
}

// ---------------- merged gather, sigma recomputed from packed bf16 (g,e) -----
__global__ __launch_bounds__(256) void k_gather2(
    const uint32_t* __restrict__ packed,
    const int2* __restrict__ pair2, const int* __restrict__ row2,
    const float* __restrict__ A2h, const float* __restrict__ A3h,
    const float* __restrict__ e_scale, const float* __restrict__ e_shift,
    float* __restrict__ agg_f, float* __restrict__ agg_b, int N)
{
    int gw = (blockIdx.x * 256 + threadIdx.x) >> 6;
    if (gw >= 2 * N) return;
    int lane = threadIdx.x & 63;
    bool bwd = gw >= N;
    int wid  = bwd ? gw - N : gw;
    const float4* Ah4 = reinterpret_cast<const float4*>(bwd ? A3h : A2h);
    float* agg        = bwd ? agg_b : agg_f;
    int beg = row2[gw], end = row2[gw + 1];   // fwd rows [0,N), bwd rows [N,2N)
    int q  = lane >> 4;      // edge slot 0..3
    int dj = lane & 15;      // float4 column slot
    float4 sc = reinterpret_cast<const float4*>(e_scale)[dj];
    float4 sh = reinterpret_cast<const float4*>(e_shift)[dj];
    float4 num = {0.f, 0.f, 0.f, 0.f};
    float4 den = {0.f, 0.f, 0.f, 0.f};
    const uint4* p4 = reinterpret_cast<const uint4*>(packed);
    for (int k = beg + q; k < end; k += 8) {
        int  k2   = k + 4;
        bool hasb = k2 < end;
        int2 pa = pair2[k];
        int2 pb = hasb ? pair2[k2] : pa;
        uint4  wa = p4[(size_t)pa.x * 16 + dj];
        float4 aa = Ah4[(size_t)pa.y * 16 + dj];
        uint4  wb = p4[(size_t)pb.x * 16 + dj];
        float4 ab = Ah4[(size_t)pb.y * 16 + dj];
        float4 sa;
        {
            float gx = __uint_as_float(wa.x << 16), ex = __uint_as_float(wa.x & 0xffff0000u);
            float gy = __uint_as_float(wa.y << 16), ey = __uint_as_float(wa.y & 0xffff0000u);
            float gz = __uint_as_float(wa.z << 16), ez = __uint_as_float(wa.z & 0xffff0000u);
            float gw4 = __uint_as_float(wa.w << 16), ew = __uint_as_float(wa.w & 0xffff0000u);
            sa.x = 1.f / (1.f + __expf(-(fmaxf(gx * sc.x + sh.x, 0.f) + ex)));
            sa.y = 1.f / (1.f + __expf(-(fmaxf(gy * sc.y + sh.y, 0.f) + ey)));
            sa.z = 1.f / (1.f + __expf(-(fmaxf(gz * sc.z + sh.z, 0.f) + ez)));
            sa.w = 1.f / (1.f + __expf(-(fmaxf(gw4 * sc.w + sh.w, 0.f) + ew)));
        }
        num.x += sa.x * aa.x; num.y += sa.y * aa.y;
        num.z += sa.z * aa.z; num.w += sa.w * aa.w;
        den.x += sa.x; den.y += sa.y; den.z += sa.z; den.w += sa.w;
        if (hasb) {
            float4 sb;
            float gx = __uint_as_float(wb.x << 16), ex = __uint_as_float(wb.x & 0xffff0000u);
            float gy = __uint_as_float(wb.y << 16), ey = __uint_as_float(wb.y & 0xffff0000u);
            float gz = __uint_as_float(wb.z << 16), ez = __uint_as_float(wb.z & 0xffff0000u);
            float gw4 = __uint_as_float(wb.w << 16), ew = __uint_as_float(wb.w & 0xffff0000u);
            sb.x = 1.f / (1.f + __expf(-(fmaxf(gx * sc.x + sh.x, 0.f) + ex)));
            sb.y = 1.f / (1.f + __expf(-(fmaxf(gy * sc.y + sh.y, 0.f) + ey)));
            sb.z = 1.f / (1.f + __expf(-(fmaxf(gz * sc.z + sh.z, 0.f) + ez)));
            sb.w = 1.f / (1.f + __expf(-(fmaxf(gw4 * sc.w + sh.w, 0.f) + ew)));
            num.x += sb.x * ab.x; num.y += sb.y * ab.y;
            num.z += sb.z * ab.z; num.w += sb.w * ab.w;
            den.x += sb.x; den.y += sb.y; den.z += sb.z; den.w += sb.w;
        }
    }
    #pragma unroll
    for (int off = 16; off <= 32; off <<= 1) {
        num.x += __shfl_xor(num.x, off); num.y += __shfl_xor(num.y, off);
        num.z += __shfl_xor(num.z, off); num.w += __shfl_xor(num.w, off);
        den.x += __shfl_xor(den.x, off); den.y += __shfl_xor(den.y, off);
        den.z += __shfl_xor(den.z, off); den.w += __shfl_xor(den.w, off);
    }
    if (q == 0) {
        float4 res;
        res.x = num.x / (den.x + DEG_EPS);
        res.y = num.y / (den.y + DEG_EPS);
        res.z = num.z / (den.z + DEG_EPS);
        res.w = num.w / (den.w + DEG_EPS);
        reinterpret_cast<float4*>(agg)[(size_t)wid * 16 + dj] = res;
    }
}

// ---------------- h_pre = A1h + agg_f + agg_b, + replicated column stats -----
__global__ __launch_bounds__(256) void k_node_pre(
    const float* __restrict__ A1h,
    const float* __restrict__ agg_f, const float* __restrict__ agg_b,
    float* __restrict__ hpre, float* __restrict__ sums, long long total)
{
    int tid = threadIdx.x;
    long long idx = (long long)blockIdx.x * 256 + tid;
    long long stride = (long long)gridDim.x * 256;
    float ps = 0.f, pq = 0.f;
    for (; idx < total; idx += stride) {
        float v = A1h[idx] + agg_f[idx] + agg_b[idx];
        hpre[idx] = v;
        ps += v; pq += v * v;
    }
    float* srep = sums + (size_t)(blockIdx.x & (NREP - 1)) * 128;
    __shared__ float red[256];
    red[tid] = ps; __syncthreads();
    if (tid < 64) fatomic_add(&srep[tid],      red[tid] + red[tid+64] + red[tid+128] + red[tid+192]);
    __syncthreads();
    red[tid] = pq; __syncthreads();
    if (tid < 64) fatomic_add(&srep[64 + tid], red[tid] + red[tid+64] + red[tid+128] + red[tid+192]);
}

// ---------------- finish h: BN affine + relu + residual (in place) -----------
__global__ __launch_bounds__(256) void k_node_out(
    const float* __restrict__ h,
    const float* __restrict__ scale, const float* __restrict__ shift,
    float* __restrict__ out, long long total)
{
    long long idx = (long long)blockIdx.x * 256 + threadIdx.x;
    long long stride = (long long)gridDim.x * 256;
    for (; idx < total; idx += stride) {
        int d = (int)(idx & (DD - 1));
        float v = out[idx] * scale[d] + shift[d];
        out[idx] = fmaxf(v, 0.f) + h[idx];
    }
}

extern "C" void kernel_launch(void* const* d_in, const int* in_sizes, int n_in,
                              void* d_out, int out_size, void* d_ws, size_t ws_size,
                              hipStream_t stream)
{
    const float* h    = (const float*)d_in[0];
    const float* e    = (const float*)d_in[1];
    const int*   src  = (const int*)d_in[2];
    const int*   dst  = (const int*)d_in[3];
    const float* A1w  = (const float*)d_in[4];
    const float* A1b  = (const float*)d_in[5];
    const float* A2w  = (const float*)d_in[6];
    const float* A2b  = (const float*)d_in[7];
    const float* A3w  = (const float*)d_in[8];
    const float* A3b  = (const float*)d_in[9];
    const float* B1w  = (const float*)d_in[10];
    const float* B1b  = (const float*)d_in[11];
    const float* B2w  = (const float*)d_in[12];
    const float* B2b  = (const float*)d_in[13];
    const float* B3w  = (const float*)d_in[14];
    const float* B3b  = (const float*)d_in[15];
    const float* bnhg = (const float*)d_in[16];
    const float* bnhb = (const float*)d_in[17];
    const float* bneg = (const float*)d_in[18];
    const float* bneb = (const float*)d_in[19];

    const int N = in_sizes[0] / DD;
    const int E = in_sizes[1] / DD;
    const size_t ND = (size_t)N * DD;
    const size_t ED = (size_t)E * DD;

    float* ws    = (float*)d_ws;
    float* A1h   = ws + 0 * ND;
    float* A2h   = ws + 1 * ND;
    float* A3h   = ws + 2 * ND;
    float* B1h   = ws + 3 * ND;
    float* B2h   = ws + 4 * ND;
    float* agg_f = ws + 5 * ND;
    float* agg_b = ws + 6 * ND;
    float* stats = ws + 7 * ND;
    const size_t STATS_F = 16640;
    float* e_rep   = stats;
    float* h_rep   = stats + 8192;
    float* e_scale = stats + 16384;
    float* e_shift = stats + 16448;
    float* h_scale = stats + 16512;
    float* h_shift = stats + 16576;

    const int nscan   = 2 * N;
    const int nb_scan = (nscan + 1023) / 1024;
    const size_t int_count = (size_t)(4 * N + 1 + nb_scan) + 4 * (size_t)E + 2;
    const size_t need_big  = (7 * ND + STATS_F + ED) * sizeof(float) + int_count * sizeof(int);
    const bool   ws_big    = ws_size >= need_big;

    uint32_t* pk_ws = (uint32_t*)(stats + STATS_F);     // ED uint32 (only if ws_big)
    int*      ibase = (int*)(ws_big ? (float*)(pk_ws + ED) : (stats + STATS_F));
    int*  cur2   = ibase;                     // 2N (counts -> cursors)
    int*  row2   = ibase + 2 * N;             // 2N+1
    int*  part   = ibase + 4 * N + 1;         // nb_scan
    int2* pair2  = (int2*)(((uintptr_t)(part + nb_scan) + 7) & ~(uintptr_t)7); // 2E pairs

    float* out  = (float*)d_out;
    float* gbuf = out + ND;   // out e-region

    hipMemsetAsync(stats, 0, STATS_F * sizeof(float), stream);
    hipMemsetAsync(cur2, 0, 2 * (size_t)N * sizeof(int), stream);

    dim3 blk(256);
    int nb_e  = (E + 255) / 256;
    int nt_n  = (N + TILE - 1) / TILE;
    int nt_e  = (E + TILE - 1) / TILE;

    k_tile_linear<<<dim3(nt_n, 5), blk, 0, stream>>>(h, N,
        A1w, A1b, A1h,  A2w, A2b, A2h,  A3w, A3b, A3h,
        B1w, B1b, B1h,  B2w, B2b, B2h);

    // CSR build (fwd+bwd merged), hierarchical scan
    k_count<<<nb_e, blk, 0, stream>>>(src, dst, cur2, N, E);
    k_scan_blk<<<nb_scan, 1024, 0, stream>>>(cur2, row2, part, nscan);
    k_scan_carry<<<1, 1024, 0, stream>>>(part, nb_scan);
    k_scan_add<<<nb_scan, 1024, 0, stream>>>(row2, cur2, part, nscan, 2 * E);
    k_place<<<nb_e, blk, 0, stream>>>(src, dst, cur2, pair2, N, E);

    // fused edge gate + BN-e stats + packed (g,e) + e passthrough
    uint32_t* pkmem = ws_big ? pk_ws : (uint32_t*)gbuf;
    k_edge_fused<<<nt_e, blk, 0, stream>>>(e, src, dst, B1h, B2h, B3w, B3b,
                                           pkmem, ws_big ? (float4*)gbuf : nullptr,
                                           e_rep, E);
    k_bn_final<<<1, 64, 0, stream>>>(e_rep, 1.0f / (float)E, bneg, bneb,
                                     e_scale, e_shift);

    // merged gather with inline sigma recompute from packed rows
    int nb_g2 = (int)(((size_t)2 * N * 64 + 255) / 256);
    k_gather2<<<nb_g2, blk, 0, stream>>>(pkmem, pair2, row2, A2h, A3h,
                                         e_scale, e_shift, agg_f, agg_b, N);

    k_node_pre<<<1024, blk, 0, stream>>>(A1h, agg_f, agg_b,
        out, h_rep, (long long)ND);
    k_bn_final<<<1, 64, 0, stream>>>(h_rep, 1.0f / (float)N, bnhg, bnhb,
                                     h_scale, h_shift);
    k_node_out<<<1024, blk, 0, stream>>>(h, h_scale, h_shift,
                                         out, (long long)ND);

    if (!ws_big) {
        hipMemcpyAsync(gbuf, e, ED * sizeof(float), hipMemcpyDeviceToDevice, stream);
    }
}